// Round 14
// baseline (1949.635 us; speedup 1.0000x reference)
//
#include <hip/hip_runtime.h>
#include <hip/hip_bf16.h>

#define HIDDEN   1024
#define XDIM     130
#define CONDDIM  44
#define INDIM    174      // XDIM + CONDDIM
#define NSTEP    16
#define BP       4096     // effective batch (64*64)
#define K0P      1088     // 1024 (h0) + 44 (y) + 20 pad ; i8: 17 tiles of 64
#define K1P      2048     // 1024 (h0') + 1024 (h1)      ; i8: 32 tiles of 64
#define GN       4096     // 4*HIDDEN gate dim
#define LGN      256      // padded logits cols (130 -> 256)

typedef float f32x4 __attribute__((ext_vector_type(4)));
typedef int   i32x4 __attribute__((ext_vector_type(4)));

// fused gate column order: n in [0,4096) -> q=(n>>4)&3 (gate), j=((n>>6)<<4)|(n&15)
__device__ __forceinline__ int fused_row(int n) {
  const int q = (n >> 4) & 3;
  const int j = ((n >> 6) << 4) | (n & 15);
  return q * HIDDEN + j;
}

__device__ __forceinline__ void g2lds16(const void* g, void* l) {
  __builtin_amdgcn_global_load_lds(
      (const __attribute__((address_space(1))) void*)g,
      (__attribute__((address_space(3))) void*)l, 16, 0, 0);
}

__device__ __forceinline__ float sigm(float x)  { return 1.f / (1.f + __expf(-x)); }
__device__ __forceinline__ float tanhfast(float x) { return 2.f / (1.f + __expf(-2.f * x)) - 1.f; }

__device__ __forceinline__ signed char qscale(float v, float inv127s) {
  int q = __float2int_rn(v * inv127s);
  q = q > 127 ? 127 : (q < -127 ? -127 : q);
  return (signed char)q;
}

// ================================================================ int8 gate GEMM + fused LSTM cell
// R13 analysis: dispatch time == hbm_bytes/1TB/s, K-independent -> tail-traffic
// bound. R14: (1) c state fp32->fp16 (halves the largest byte item);
// (2) c prefetched into REGISTERS at tile NT-4 (after last staging issues),
// remaining counted waits bumped +32 (vmcnt 40/36/32) so staging never blocks
// on c and c-load latency hides under the last tiles' MFMA. Epilogue reads regs.
template<bool FB>
__global__ __launch_bounds__(512, 2)
void gemm_i8_cell_k(const signed char* __restrict__ A,
                    const signed char* __restrict__ W, int K,
                    const float* __restrict__ bcomb,
                    const float* __restrict__ SC,
                    const float* __restrict__ sA,        // per-row A scale (or null)
                    const float* __restrict__ W0T,
                    const int*   __restrict__ idx,
                    _Float16* __restrict__ c,            // fp16 cell state
                    signed char* __restrict__ d1, int ld1,
                    const float* __restrict__ sD1,       // d1 quant scale (or null)
                    signed char* __restrict__ d2, int ld2)
{
  __shared__ __align__(16) signed char lds[4 * 32768];   // 4 buf x (A 16KB + B 16KB)

  const int tid  = threadIdx.x;
  const int w    = tid >> 6;
  const int lane = tid & 63;
  const int bid  = blockIdx.x;
  const int swz  = ((bid & 7) << 5) | (bid >> 3);   // XCD-chunked (256 % 8 == 0)
  const int m0   = (swz >> 4) * 256;
  const int n0   = (swz & 15) * 256;
  const int wm   = w >> 2;
  const int wn   = w & 3;
  const int fr   = lane & 15;
  const int kqs  = (((lane >> 4) ^ ((fr >> 1) & 3)) * 16);   // byte chunk, swizzled
  const int sr   = lane >> 2;
  const int sc   = (((lane & 3) ^ ((sr >> 1) & 3)) * 16);    // source chunk, pre-XORed
  const int NT   = K >> 6;          // K-tiles of 64 int8 (64 B rows)

  // epilogue coordinates (hoisted: needed by the c-prefetch)
  const int fq = lane >> 4;
  const int cb = n0 + wn * 64;
  const int j  = ((cb >> 6) << 4) | fr;

  i32x4 acc[8][4] = {};
  float cpre[8][4] = {};

  #define STAGE_A(t, d, i)                                                          \
    g2lds16(A + (size_t)(m0 + w * 32 + (i) * 16 + sr) * K + ((t) * 64 + sc),        \
            (void*)(lds + (d) * 32768 + (w * 32 + (i) * 16) * 64))
  #define STAGE_B(t, d, i)                                                          \
    g2lds16(W + (size_t)(n0 + w * 32 + (i) * 16 + sr) * K + ((t) * 64 + sc),        \
            (void*)(lds + (d) * 32768 + 16384 + (w * 32 + (i) * 16) * 64))

  const int npro = (NT < 3) ? NT : 3;
  for (int t = 0; t < npro; ++t) {
    STAGE_A(t, t, 0); STAGE_B(t, t, 0);
    STAGE_A(t, t, 1); STAGE_B(t, t, 1);
  }
  if (NT >= 3)      asm volatile("s_waitcnt vmcnt(8)" ::: "memory");
  else if (NT == 2) asm volatile("s_waitcnt vmcnt(4)" ::: "memory");
  else              asm volatile("s_waitcnt vmcnt(0)" ::: "memory");
  __builtin_amdgcn_s_barrier();

  for (int t = 0; t < NT; ++t) {
    const int d  = t & 3;
    const signed char* As = lds + d * 32768;
    const signed char* Bs = As + 16384;
    const int tp = t + 3;
    const int dp = tp & 3;
    const bool pf = tp < NT;

    i32x4 bfr[4];
    #pragma unroll
    for (int nf = 0; nf < 4; ++nf)
      bfr[nf] = *reinterpret_cast<const i32x4*>(&Bs[(wn * 64 + nf * 16 + fr) * 64 + kqs]);

    #pragma unroll
    for (int half = 0; half < 2; ++half) {
      if (pf) {
        if (half == 0) { STAGE_A(tp, dp, 0); STAGE_A(tp, dp, 1); }
        else           { STAGE_B(tp, dp, 0); STAGE_B(tp, dp, 1); }
      }
      i32x4 afr[4];
      #pragma unroll
      for (int q = 0; q < 4; ++q)
        afr[q] = *reinterpret_cast<const i32x4*>(&As[(wm * 128 + (half * 4 + q) * 16 + fr) * 64 + kqs]);
      __builtin_amdgcn_s_setprio(1);
      #pragma unroll
      for (int q = 0; q < 4; ++q)
        #pragma unroll
        for (int nf = 0; nf < 4; ++nf)
          acc[half * 4 + q][nf] =
              __builtin_amdgcn_mfma_i32_16x16x64_i8(afr[q], bfr[nf], acc[half * 4 + q][nf], 0, 0, 0);
      __builtin_amdgcn_s_setprio(0);
    }

    // bottom-of-tile waits. From t==NT-4 on, 32 c-prefetch loads are also in
    // flight (issued below), so the staging-wait counts are bumped by +32.
    if (t + 4 == NT) {
      // issue the 32 per-lane c loads (values land during the last 3 tiles)
      #pragma unroll
      for (int mf = 0; mf < 8; ++mf)
        #pragma unroll
        for (int r = 0; r < 4; ++r) {
          const int b = m0 + wm * 128 + mf * 16 + fq * 4 + r;
          cpre[mf][r] = (float)c[(size_t)b * HIDDEN + j];
        }
      asm volatile("s_waitcnt vmcnt(40)" ::: "memory");   // 8 staging + 32 c
      __builtin_amdgcn_s_barrier();
    } else if (t + 3 < NT) {
      asm volatile("s_waitcnt vmcnt(8)" ::: "memory");
      __builtin_amdgcn_s_barrier();
    } else if (t + 3 == NT) {
      asm volatile("s_waitcnt vmcnt(36)" ::: "memory");   // 4 staging + 32 c
      __builtin_amdgcn_s_barrier();
    } else if (t + 2 == NT) {
      asm volatile("s_waitcnt vmcnt(32)" ::: "memory");   // 0 staging + 32 c
      __builtin_amdgcn_s_barrier();
    }
    // t == NT-1: fall through to epilogue
  }
  #undef STAGE_A
  #undef STAGE_B

  const float bs0 = bcomb[cb + fr],      sc0 = SC[cb + fr];
  const float bs1 = bcomb[cb + 16 + fr], sc1 = SC[cb + 16 + fr];
  const float bs2 = bcomb[cb + 32 + fr], sc2 = SC[cb + 32 + fr];
  const float bs3 = bcomb[cb + 48 + fr], sc3 = SC[cb + 48 + fr];

  #pragma unroll
  for (int mf = 0; mf < 8; ++mf) {
    #pragma unroll
    for (int r = 0; r < 4; ++r) {
      const int b = m0 + wm * 128 + mf * 16 + fq * 4 + r;
      const float sa = sA ? sA[b] : 1.f;
      float gi = (float)acc[mf][0][r] * (sc0 * sa) + bs0;
      float gf = (float)acc[mf][1][r] * (sc1 * sa) + bs1;
      float gg = (float)acc[mf][2][r] * (sc2 * sa) + bs2;
      float go = (float)acc[mf][3][r] * (sc3 * sa) + bs3;
      if (FB) {
        const float* wr = W0T + (size_t)idx[b] * GN;
        gi += wr[cb + fr];
        gf += wr[cb + 16 + fr];
        gg += wr[cb + 32 + fr];
        go += wr[cb + 48 + fr];
      }
      const size_t ci = (size_t)b * HIDDEN + j;
      float cold = cpre[mf][r];
      if (NT < 4) cold = (float)c[ci];   // safety: never taken for NT=17/32
      const float cn = sigm(gf) * cold + sigm(gi) * tanhfast(gg);
      c[ci] = (_Float16)cn;
      const float hn = sigm(go) * tanhfast(cn);
      if (d1) {
        const float i127s = sD1 ? (127.f / sD1[b]) : 127.f;
        d1[(size_t)b * ld1 + j] = qscale(hn, i127s);
      }
      if (d2) d2[(size_t)b * ld2 + j] = qscale(hn, 127.f);
    }
  }
}

// ---------------------------------------------------------------- int8 logits GEMM (64x128 tile, 128 blocks)
__global__ __launch_bounds__(256, 4)
void logits_i8_k(const signed char* __restrict__ A, int lda,   // h1' rows (stride K1P)
                 const signed char* __restrict__ Wfi,          // [256][1024] int8
                 const float* __restrict__ SCf,                // RMf/127^2
                 float* __restrict__ C, int ldc)
{
  __shared__ __align__(16) signed char As[64 * 64];    // 4 KB
  __shared__ __align__(16) signed char Bs[128 * 64];   // 8 KB

  const int tid  = threadIdx.x;
  const int w    = tid >> 6;
  const int lane = tid & 63;
  const int m0 = blockIdx.y * 64;
  const int n0 = blockIdx.x * 128;
  const int wm = w >> 1;
  const int wn = w & 1;
  const int fr = lane & 15;
  const int kqs = (((lane >> 4) ^ ((fr >> 1) & 3)) * 16);
  const int sr  = lane >> 2;
  const int sc  = (((lane & 3) ^ ((sr >> 1) & 3)) * 16);

  i32x4 acc[2][4] = {};

  for (int k0 = 0; k0 < HIDDEN; k0 += 64) {
    __syncthreads();
    g2lds16(A + (size_t)(m0 + w * 16 + sr) * lda + (k0 + sc), (void*)(As + (w * 16) * 64));
    g2lds16(Wfi + (size_t)(n0 + w * 16 + sr) * HIDDEN + (k0 + sc), (void*)(Bs + (w * 16) * 64));
    g2lds16(Wfi + (size_t)(n0 + 64 + w * 16 + sr) * HIDDEN + (k0 + sc), (void*)(Bs + (64 + w * 16) * 64));
    __syncthreads();

    i32x4 af[2], bw[4];
    #pragma unroll
    for (int i = 0; i < 2; ++i)
      af[i] = *reinterpret_cast<const i32x4*>(&As[(wm * 32 + i * 16 + fr) * 64 + kqs]);
    #pragma unroll
    for (int j = 0; j < 4; ++j)
      bw[j] = *reinterpret_cast<const i32x4*>(&Bs[(wn * 64 + j * 16 + fr) * 64 + kqs]);
    #pragma unroll
    for (int i = 0; i < 2; ++i)
      #pragma unroll
      for (int j = 0; j < 4; ++j)
        acc[i][j] = __builtin_amdgcn_mfma_i32_16x16x64_i8(af[i], bw[j], acc[i][j], 0, 0, 0);
  }

  const int fq = lane >> 4;
  #pragma unroll
  for (int i = 0; i < 2; ++i)
    #pragma unroll
    for (int j = 0; j < 4; ++j) {
      const int col = n0 + wn * 64 + j * 16 + fr;
      const float scf = SCf[col];
      #pragma unroll
      for (int r = 0; r < 4; ++r) {
        const int row = m0 + wm * 32 + i * 16 + fq * 4 + r;
        C[(size_t)row * ldc + col] = (float)acc[i][j][r] * scf;
      }
    }
}

// ---------------------------------------------------------------- log_softmax + argmax + y staging (int8)
__global__ void smax_k(const float* __restrict__ LG,
                       const float* __restrict__ bfv,
                       float* __restrict__ out, int t,
                       const float* __restrict__ x,
                       signed char* __restrict__ A0next,   // y cols: q127(y/4)
                       int* __restrict__ idx)
{
  const int b    = blockIdx.x;
  const int lane = threadIdx.x;   // 64
  const float NINF = -__builtin_inff();
  const float* lg = LG + (size_t)b * LGN;

  const int c1 = lane + 64, c2 = lane + 128;
  float v0 = lg[lane] + bfv[lane];
  float v1 = lg[c1] + bfv[c1];
  float v2 = (c2 < XDIM) ? lg[c2] + bfv[c2] : NINF;

  float m = fmaxf(v0, fmaxf(v1, v2));
  #pragma unroll
  for (int o = 32; o > 0; o >>= 1) m = fmaxf(m, __shfl_xor(m, o, 64));

  int bi = 0x7fffffff;
  if (v0 == m) bi = lane;
  if (v1 == m) bi = min(bi, c1);
  if (v2 == m) bi = min(bi, c2);
  #pragma unroll
  for (int o = 32; o > 0; o >>= 1) bi = min(bi, __shfl_xor(bi, o, 64));

  float s = __expf(v0 - m) + __expf(v1 - m) + ((c2 < XDIM) ? __expf(v2 - m) : 0.f);
  #pragma unroll
  for (int o = 32; o > 0; o >>= 1) s += __shfl_xor(s, o, 64);
  const float lse = __logf(s);

  float* orow = out + ((size_t)b * NSTEP + t) * XDIM;
  orow[lane] = v0 - m - lse;
  orow[c1]   = v1 - m - lse;
  if (c2 < XDIM) orow[c2] = v2 - m - lse;
  if (lane == 0) idx[b] = bi;

  if (t + 1 < NSTEP) {
    const float yv = (lane < CONDDIM)
        ? x[((size_t)b * NSTEP + (t + 1)) * INDIM + XDIM + lane] : 0.f;
    A0next[(size_t)b * K0P + HIDDEN + lane] = qscale(yv * 0.25f, 127.f);
  }
}

// ---------------------------------------------------------------- init: per-row scales + quantize z
__global__ void initq_k(const float* __restrict__ z, const float* __restrict__ x,
                        _Float16* __restrict__ c0, _Float16* __restrict__ c1,
                        signed char* __restrict__ A0, signed char* __restrict__ A1,
                        float* __restrict__ S0, float* __restrict__ S1,
                        int* __restrict__ idx)
{
  const int b    = blockIdx.x;
  const int lane = threadIdx.x;   // 64
  const float* zr = z + (size_t)b * HIDDEN;

  float mz = 0.f;
  for (int k = lane; k < HIDDEN; k += 64) mz = fmaxf(mz, fabsf(zr[k]));
  #pragma unroll
  for (int o = 32; o > 0; o >>= 1) mz = fmaxf(mz, __shfl_xor(mz, o, 64));

  const float yv = (lane < CONDDIM) ? x[((size_t)b * NSTEP) * INDIM + XDIM + lane] : 0.f;
  float my = fabsf(yv) * 0.25f;
  #pragma unroll
  for (int o = 32; o > 0; o >>= 1) my = fmaxf(my, __shfl_xor(my, o, 64));

  const float s0 = fmaxf(fmaxf(mz, my), 1e-6f);
  const float s1 = fmaxf(mz, 1.f);
  const float i0 = 127.f / s0;
  const float i1 = 127.f / s1;

  for (int k = lane; k < HIDDEN; k += 64) {
    const float zv = zr[k];
    A0[(size_t)b * K0P + k]          = qscale(zv, i0);
    A1[(size_t)b * K1P + HIDDEN + k] = qscale(zv, i1);   // h1(-1) = z
    c0[(size_t)b * HIDDEN + k] = (_Float16)0.f;
    c1[(size_t)b * HIDDEN + k] = (_Float16)0.f;
  }
  A0[(size_t)b * K0P + HIDDEN + lane] = qscale(yv * 0.25f, i0);
  if (lane == 0) { S0[b] = s0; S1[b] = s1; idx[b] = 1; }
}

// ---------------------------------------------------------------- weight packing
__global__ void rowmax0_k(const float* __restrict__ Wih0, const float* __restrict__ Whh0,
                          float* __restrict__ RM, float* __restrict__ SC)
{
  const int n = blockIdx.x, lane = threadIdx.x;
  const int row = fused_row(n);
  float m = 1e-20f;
  for (int k = lane; k < HIDDEN; k += 64)  m = fmaxf(m, fabsf(Whh0[(size_t)row * HIDDEN + k]));
  for (int k = lane; k < CONDDIM; k += 64) m = fmaxf(m, 4.f * fabsf(Wih0[(size_t)row * INDIM + XDIM + k]));
  #pragma unroll
  for (int o = 32; o > 0; o >>= 1) m = fmaxf(m, __shfl_xor(m, o, 64));
  if (lane == 0) { RM[n] = m; SC[n] = m / 16129.f; }
}

__global__ void rowmax1_k(const float* __restrict__ Wih1, const float* __restrict__ Whh1,
                          float* __restrict__ RM, float* __restrict__ SC)
{
  const int n = blockIdx.x, lane = threadIdx.x;
  const int row = fused_row(n);
  float m = 1e-20f;
  for (int k = lane; k < HIDDEN; k += 64) {
    m = fmaxf(m, fabsf(Wih1[(size_t)row * HIDDEN + k]));
    m = fmaxf(m, fabsf(Whh1[(size_t)row * HIDDEN + k]));
  }
  #pragma unroll
  for (int o = 32; o > 0; o >>= 1) m = fmaxf(m, __shfl_xor(m, o, 64));
  if (lane == 0) { RM[n] = m; SC[n] = m / 16129.f; }
}

__global__ void packi0_k(const float* __restrict__ Wih0, const float* __restrict__ Whh0,
                         const float* __restrict__ RM, signed char* __restrict__ Bp)
{
  const int t = blockIdx.x * blockDim.x + threadIdx.x;
  if (t >= GN * K0P) return;
  const int n = t / K0P, k = t % K0P;
  const int row = fused_row(n);
  float v = 0.f;
  if (k < HIDDEN)                v = Whh0[(size_t)row * HIDDEN + k];
  else if (k < HIDDEN + CONDDIM) v = 4.f * Wih0[(size_t)row * INDIM + XDIM + (k - HIDDEN)];
  Bp[t] = qscale(v, 127.f / RM[n]);
}

__global__ void packi1_k(const float* __restrict__ Wih1, const float* __restrict__ Whh1,
                         const float* __restrict__ RM, signed char* __restrict__ Bp)
{
  const int t = blockIdx.x * blockDim.x + threadIdx.x;
  if (t >= GN * K1P) return;
  const int n = t >> 11, k = t & 2047;
  const int row = fused_row(n);
  const float v = (k < HIDDEN) ? Wih1[(size_t)row * HIDDEN + k]
                               : Whh1[(size_t)row * HIDDEN + (k - HIDDEN)];
  Bp[t] = qscale(v, 127.f / RM[n]);
}

__global__ void packbias_k(const float* __restrict__ bih, const float* __restrict__ bhh,
                           float* __restrict__ bc)
{
  const int n = blockIdx.x * blockDim.x + threadIdx.x;
  if (n >= GN) return;
  const int row = fused_row(n);
  bc[n] = bih[row] + bhh[row];
}

__global__ void rowmaxf_k(const float* __restrict__ Wf, float* __restrict__ RM,
                          float* __restrict__ SC)
{
  const int n = blockIdx.x, lane = threadIdx.x;
  float m = 1e-20f;
  if (n < XDIM)
    for (int k = lane; k < HIDDEN; k += 64) m = fmaxf(m, fabsf(Wf[(size_t)n * HIDDEN + k]));
  else m = 1.f;
  #pragma unroll
  for (int o = 32; o > 0; o >>= 1) m = fmaxf(m, __shfl_xor(m, o, 64));
  if (lane == 0) { RM[n] = m; SC[n] = m / 16129.f; }
}

__global__ void packfi_k(const float* __restrict__ Wf, const float* __restrict__ RM,
                         signed char* __restrict__ Wfi)
{
  const int t = blockIdx.x * blockDim.x + threadIdx.x;
  if (t >= LGN * HIDDEN) return;
  const int r = t >> 10, k = t & 1023;
  const float v = (r < XDIM) ? Wf[(size_t)r * HIDDEN + k] : 0.f;
  Wfi[t] = qscale(v, 127.f / RM[r]);
}

__global__ void packt_k(const float* __restrict__ Wih0, float* __restrict__ W0T)
{
  const int t = blockIdx.x * blockDim.x + threadIdx.x;
  if (t >= XDIM * GN) return;
  const int e = t >> 12, n = t & 4095;
  W0T[t] = Wih0[(size_t)fused_row(n) * INDIM + e];
}

// ---------------------------------------------------------------- launch
extern "C" void kernel_launch(void* const* d_in, const int* in_sizes, int n_in,
                              void* d_out, int out_size, void* d_ws, size_t ws_size,
                              hipStream_t stream)
{
  const float* z    = (const float*)d_in[0];
  const float* x    = (const float*)d_in[1];
  const float* Wih0 = (const float*)d_in[2];
  const float* Whh0 = (const float*)d_in[3];
  const float* bih0 = (const float*)d_in[4];
  const float* bhh0 = (const float*)d_in[5];
  const float* Wih1 = (const float*)d_in[6];
  const float* Whh1 = (const float*)d_in[7];
  const float* bih1 = (const float*)d_in[8];
  const float* bhh1 = (const float*)d_in[9];
  const float* Wf   = (const float*)d_in[10];
  const float* bfv  = (const float*)d_in[11];
  float* out = (float*)d_out;

  char* ws = (char*)d_ws;
  size_t off = 0;
  auto alloc = [&](size_t bytes) { void* p = ws + off; off += (bytes + 255) & ~(size_t)255; return p; };

  float*       LG    = (float*)      alloc((size_t)BP * LGN * 4);
  signed char* A0i8a = (signed char*)alloc((size_t)BP * K0P);
  signed char* A0i8b = (signed char*)alloc((size_t)BP * K0P);
  signed char* A1i8a = (signed char*)alloc((size_t)BP * K1P);
  signed char* A1i8b = (signed char*)alloc((size_t)BP * K1P);
  signed char* Bpi0  = (signed char*)alloc((size_t)GN * K0P);
  signed char* Bpi1  = (signed char*)alloc((size_t)GN * K1P);
  signed char* Wfi   = (signed char*)alloc((size_t)LGN * HIDDEN);
  float*       W0T   = (float*)      alloc((size_t)XDIM * GN * 4);
  float*       bc0   = (float*)      alloc((size_t)GN * 4);
  float*       bc1   = (float*)      alloc((size_t)GN * 4);
  float*       RM0   = (float*)      alloc((size_t)GN * 4);
  float*       SC0   = (float*)      alloc((size_t)GN * 4);
  float*       RM1   = (float*)      alloc((size_t)GN * 4);
  float*       SC1   = (float*)      alloc((size_t)GN * 4);
  float*       RMf   = (float*)      alloc((size_t)LGN * 4);
  float*       SCf   = (float*)      alloc((size_t)LGN * 4);
  float*       S0    = (float*)      alloc((size_t)BP * 4);
  float*       S1    = (float*)      alloc((size_t)BP * 4);
  _Float16*    c0    = (_Float16*)   alloc((size_t)BP * HIDDEN * 2);
  _Float16*    c1    = (_Float16*)   alloc((size_t)BP * HIDDEN * 2);
  int*         idx   = (int*)        alloc((size_t)BP * 4);
  (void)ws_size; (void)in_sizes; (void)n_in; (void)out_size;

  rowmax0_k<<<GN, 64, 0, stream>>>(Wih0, Whh0, RM0, SC0);
  rowmax1_k<<<GN, 64, 0, stream>>>(Wih1, Whh1, RM1, SC1);
  rowmaxf_k<<<LGN, 64, 0, stream>>>(Wf, RMf, SCf);
  packi0_k<<<(GN * K0P + 255) / 256, 256, 0, stream>>>(Wih0, Whh0, RM0, Bpi0);
  packi1_k<<<(GN * K1P + 255) / 256, 256, 0, stream>>>(Wih1, Whh1, RM1, Bpi1);
  packfi_k<<<(LGN * HIDDEN + 255) / 256, 256, 0, stream>>>(Wf, RMf, Wfi);
  packbias_k<<<(GN + 255) / 256, 256, 0, stream>>>(bih0, bhh0, bc0);
  packbias_k<<<(GN + 255) / 256, 256, 0, stream>>>(bih1, bhh1, bc1);
  packt_k<<<(XDIM * GN + 255) / 256, 256, 0, stream>>>(Wih0, W0T);
  initq_k<<<BP, 64, 0, stream>>>(z, x, c0, c1, A0i8a, A1i8a, S0, S1, idx);

  for (int t = 0; t < NSTEP; ++t) {
    signed char* A0c = (t & 1) ? A0i8b : A0i8a;
    signed char* A0n = (t & 1) ? A0i8a : A0i8b;
    signed char* A1c = (t & 1) ? A1i8b : A1i8a;
    signed char* A1n = (t & 1) ? A1i8a : A1i8b;
    const float* sA0 = (t == 0) ? S0 : nullptr;
    const float* sA1 = (t == 0) ? S1 : nullptr;
    const float* sD1 = (t == 0) ? S1 : nullptr;

    // layer 0: fused cell -> h0'
    gemm_i8_cell_k<true><<<256, 512, 0, stream>>>(
        A0c, Bpi0, K0P, bc0, SC0, sA0, W0T, idx, c0,
        A1c, K1P, sD1,           // h0' -> A1 (current) first half
        A0n, K0P);               // h0' -> A0 (next step), scale 1
    // layer 1: fused cell -> h1'
    gemm_i8_cell_k<false><<<256, 512, 0, stream>>>(
        A1c, Bpi1, K1P, bc1, SC1, sA1, nullptr, nullptr, c1,
        A1n + HIDDEN, K1P, nullptr,   // h1' -> A1 (next) second half, scale 1
        nullptr, 0);
    // logits from int8 h1' (scale 1/127)
    logits_i8_k<<<dim3(LGN / 128, BP / 64), dim3(256), 0, stream>>>(
        A1n + HIDDEN, K1P, Wfi, SCf, LG, LGN);
    smax_k<<<BP, 64, 0, stream>>>(LG, bfv, out, t, x, A0n, idx);
  }
}

// Round 15
// 1700.188 us; speedup vs baseline: 1.1467x; 1.1467x over previous
//
#include <hip/hip_runtime.h>
#include <hip/hip_bf16.h>

#define HIDDEN   1024
#define XDIM     130
#define CONDDIM  44
#define INDIM    174      // XDIM + CONDDIM
#define NSTEP    16
#define BP       4096     // effective batch (64*64)
#define K0P      1088     // 1024 (h) + 64 (y pad) ; i8: 17 tiles of 64
#define K1P      2048     // 1024 + 1024           ; i8: 32 tiles of 64
#define GN       4096     // 4*HIDDEN gate dim
#define LGN      256      // padded logits cols (130 -> 256)
#define SPLITK   16       // A-tiles < SPLITK from Alo (stride 1024), else Ahi

typedef float f32x4 __attribute__((ext_vector_type(4)));
typedef int   i32x4 __attribute__((ext_vector_type(4)));

// fused gate column order: n in [0,4096) -> q=(n>>4)&3 (gate), j=((n>>6)<<4)|(n&15)
__device__ __forceinline__ int fused_row(int n) {
  const int q = (n >> 4) & 3;
  const int j = ((n >> 6) << 4) | (n & 15);
  return q * HIDDEN + j;
}

__device__ __forceinline__ void g2lds16(const void* g, void* l) {
  __builtin_amdgcn_global_load_lds(
      (const __attribute__((address_space(1))) void*)g,
      (__attribute__((address_space(3))) void*)l, 16, 0, 0);
}

__device__ __forceinline__ float sigm(float x)  { return 1.f / (1.f + __expf(-x)); }
__device__ __forceinline__ float tanhfast(float x) { return 2.f / (1.f + __expf(-2.f * x)) - 1.f; }

__device__ __forceinline__ signed char qscale(float v, float inv127s) {
  int q = __float2int_rn(v * inv127s);
  q = q > 127 ? 127 : (q < -127 ? -127 : q);
  return (signed char)q;
}

// ================================================================ int8 gate GEMM + fused LSTM cell
// R13 diagnosis: gate dispatch time is a K-independent latency floor (1 block/CU,
// tail c/h traffic at ~1 TB/s). R15: 128x128 tile, 4 waves, 2 LDS buffers (32KB),
// launch_bounds(256,3) -> 3 blocks/CU; tiled c layout (block-contiguous 16KB);
// A staged from split bases (tiles<16: Alo stride 1024; else Ahi) so h is
// written ONCE per step. Math identical to R13 (fp32 c, same scales).
template<bool FB>
__global__ __launch_bounds__(256, 3)
void gemm_i8_cell_k(const signed char* __restrict__ Alo,   // stride 1024
                    const signed char* __restrict__ Ahi, int ahstr,
                    const signed char* __restrict__ W, int K,
                    const float* __restrict__ bcomb,
                    const float* __restrict__ SC,        // Rmax/127^2, fused order
                    const float* __restrict__ sA,        // per-row A scale (or null)
                    const float* __restrict__ W0T,       // 130 x 4096 fused (FB only)
                    const int*   __restrict__ idx,       // feedback index (FB only)
                    float* __restrict__ cT,              // tiled: [j>>5][b][j&31] fp32
                    signed char* __restrict__ d1,        // stride 1024, scale 1
                    signed char* __restrict__ d2,        // stride 1024, scale sD2 (or null)
                    const float* __restrict__ sD2)
{
  __shared__ __align__(16) signed char lds[2 * 16384];   // 2 buf x (A 8KB + B 8KB)

  const int tid  = threadIdx.x;
  const int w    = tid >> 6;        // wave 0..3
  const int lane = tid & 63;
  const int bid  = blockIdx.x;      // 1024 blocks
  const int swz  = ((bid & 7) << 7) | (bid >> 3);   // XCD-chunked (1024 % 8 == 0)
  const int m0   = (swz >> 5) * 128;
  const int n0   = (swz & 31) * 128;
  const int wm   = w >> 1;          // 0..1 : 64-row half
  const int wn   = w & 1;           // 0..1 : 64-col half
  const int fr   = lane & 15;
  const int kqs  = (((lane >> 4) ^ ((fr >> 1) & 3)) * 16);   // swizzled 16B chunk
  const int sr   = lane >> 2;
  const int sc   = (((lane & 3) ^ ((sr >> 1) & 3)) * 16);    // pre-XORed source chunk
  const int NT   = K >> 6;          // K-tiles of 64 int8 (64 B rows)

  const int fq = lane >> 4;
  const int cb = n0 + wn * 64;
  const int j  = ((cb >> 6) << 4) | fr;

  i32x4 acc[4][4] = {};

  auto stA = [&](int t, int buf) {
    const signed char* ab; size_t astr; int koff;
    if (t < SPLITK) { ab = Alo; astr = 1024;          koff = t * 64; }
    else            { ab = Ahi; astr = (size_t)ahstr; koff = (t - SPLITK) * 64; }
    #pragma unroll
    for (int i = 0; i < 2; ++i)
      g2lds16(ab + (size_t)(m0 + w * 32 + i * 16 + sr) * astr + (koff + sc),
              (void*)(lds + buf * 16384 + (w * 32 + i * 16) * 64));
  };
  auto stB = [&](int t, int buf) {
    #pragma unroll
    for (int i = 0; i < 2; ++i)
      g2lds16(W + (size_t)(n0 + w * 32 + i * 16 + sr) * K + (t * 64 + sc),
              (void*)(lds + buf * 16384 + 8192 + (w * 32 + i * 16) * 64));
  };

  // prologue: tiles 0,1 into bufs 0,1; wait tile 0 (tile 1 stays in flight)
  stA(0, 0); stB(0, 0);
  stA(1, 1); stB(1, 1);
  asm volatile("s_waitcnt vmcnt(4)" ::: "memory");
  __builtin_amdgcn_s_barrier();

  for (int t = 0; t < NT; ++t) {
    const int buf = t & 1;
    const signed char* As = lds + buf * 16384;
    const signed char* Bs = As + 8192;

    i32x4 afr[4], bfr[4];
    #pragma unroll
    for (int q = 0; q < 4; ++q)
      afr[q] = *reinterpret_cast<const i32x4*>(&As[(wm * 64 + q * 16 + fr) * 64 + kqs]);
    #pragma unroll
    for (int nf = 0; nf < 4; ++nf)
      bfr[nf] = *reinterpret_cast<const i32x4*>(&Bs[(wn * 64 + nf * 16 + fr) * 64 + kqs]);
    // all reads landed before any wave restages this buffer
    asm volatile("s_waitcnt lgkmcnt(0)" ::: "memory");
    __builtin_amdgcn_s_barrier();
    if (t + 2 < NT) { stA(t + 2, buf); stB(t + 2, buf); }

    __builtin_amdgcn_s_setprio(1);
    #pragma unroll
    for (int q = 0; q < 4; ++q)
      #pragma unroll
      for (int nf = 0; nf < 4; ++nf)
        acc[q][nf] = __builtin_amdgcn_mfma_i32_16x16x64_i8(afr[q], bfr[nf], acc[q][nf], 0, 0, 0);
    __builtin_amdgcn_s_setprio(0);

    if (t + 1 < NT) {
      if (t + 2 < NT) asm volatile("s_waitcnt vmcnt(4)" ::: "memory");  // t+1 landed
      else            asm volatile("s_waitcnt vmcnt(0)" ::: "memory");
      __builtin_amdgcn_s_barrier();
    }
  }

  // ---- fused LSTM cell epilogue ----
  const float bs0 = bcomb[cb + fr],      sc0 = SC[cb + fr];
  const float bs1 = bcomb[cb + 16 + fr], sc1 = SC[cb + 16 + fr];
  const float bs2 = bcomb[cb + 32 + fr], sc2 = SC[cb + 32 + fr];
  const float bs3 = bcomb[cb + 48 + fr], sc3 = SC[cb + 48 + fr];
  const size_t ctbase = (size_t)(j >> 5) * ((size_t)BP * 32) + (j & 31);

  #pragma unroll
  for (int mf = 0; mf < 4; ++mf) {
    #pragma unroll
    for (int r = 0; r < 4; ++r) {
      const int b = m0 + wm * 64 + mf * 16 + fq * 4 + r;
      const float sa = sA ? sA[b] : 1.f;
      float gi = (float)acc[mf][0][r] * (sc0 * sa) + bs0;
      float gf = (float)acc[mf][1][r] * (sc1 * sa) + bs1;
      float gg = (float)acc[mf][2][r] * (sc2 * sa) + bs2;
      float go = (float)acc[mf][3][r] * (sc3 * sa) + bs3;
      if (FB) {
        const float* wr = W0T + (size_t)idx[b] * GN;
        gi += wr[cb + fr];
        gf += wr[cb + 16 + fr];
        gg += wr[cb + 32 + fr];
        go += wr[cb + 48 + fr];
      }
      const size_t ci = ctbase + (size_t)b * 32;
      const float cn = sigm(gf) * cT[ci] + sigm(gi) * tanhfast(gg);
      cT[ci] = cn;
      const float hn = sigm(go) * tanhfast(cn);
      d1[(size_t)b * 1024 + j] = qscale(hn, 127.f);
      if (d2) d2[(size_t)b * 1024 + j] = qscale(hn, 127.f / sD2[b]);
    }
  }
}

// ---------------------------------------------------------------- int8 logits GEMM (64x128 tile, 128 blocks)
__global__ __launch_bounds__(256, 4)
void logits_i8_k(const signed char* __restrict__ A, int lda,   // h1' rows (stride 1024)
                 const signed char* __restrict__ Wfi,          // [256][1024] int8
                 const float* __restrict__ SCf,                // RMf/127^2
                 float* __restrict__ C, int ldc)
{
  __shared__ __align__(16) signed char As[64 * 64];    // 4 KB
  __shared__ __align__(16) signed char Bs[128 * 64];   // 8 KB

  const int tid  = threadIdx.x;
  const int w    = tid >> 6;
  const int lane = tid & 63;
  const int m0 = blockIdx.y * 64;
  const int n0 = blockIdx.x * 128;
  const int wm = w >> 1;
  const int wn = w & 1;
  const int fr = lane & 15;
  const int kqs = (((lane >> 4) ^ ((fr >> 1) & 3)) * 16);
  const int sr  = lane >> 2;
  const int sc  = (((lane & 3) ^ ((sr >> 1) & 3)) * 16);

  i32x4 acc[2][4] = {};

  for (int k0 = 0; k0 < HIDDEN; k0 += 64) {
    __syncthreads();
    g2lds16(A + (size_t)(m0 + w * 16 + sr) * lda + (k0 + sc), (void*)(As + (w * 16) * 64));
    g2lds16(Wfi + (size_t)(n0 + w * 16 + sr) * HIDDEN + (k0 + sc), (void*)(Bs + (w * 16) * 64));
    g2lds16(Wfi + (size_t)(n0 + 64 + w * 16 + sr) * HIDDEN + (k0 + sc), (void*)(Bs + (64 + w * 16) * 64));
    __syncthreads();

    i32x4 af[2], bw[4];
    #pragma unroll
    for (int i = 0; i < 2; ++i)
      af[i] = *reinterpret_cast<const i32x4*>(&As[(wm * 32 + i * 16 + fr) * 64 + kqs]);
    #pragma unroll
    for (int jn = 0; jn < 4; ++jn)
      bw[jn] = *reinterpret_cast<const i32x4*>(&Bs[(wn * 64 + jn * 16 + fr) * 64 + kqs]);
    #pragma unroll
    for (int i = 0; i < 2; ++i)
      #pragma unroll
      for (int jn = 0; jn < 4; ++jn)
        acc[i][jn] = __builtin_amdgcn_mfma_i32_16x16x64_i8(af[i], bw[jn], acc[i][jn], 0, 0, 0);
  }

  const int fq = lane >> 4;
  #pragma unroll
  for (int i = 0; i < 2; ++i)
    #pragma unroll
    for (int jn = 0; jn < 4; ++jn) {
      const int col = n0 + wn * 64 + jn * 16 + fr;
      const float scf = SCf[col];
      #pragma unroll
      for (int r = 0; r < 4; ++r) {
        const int row = m0 + wm * 32 + i * 16 + fq * 4 + r;
        C[(size_t)row * ldc + col] = (float)acc[i][jn][r] * scf;
      }
    }
}

// ---------------------------------------------------------------- log_softmax + argmax + y staging
__global__ void smax_k(const float* __restrict__ LG,
                       const float* __restrict__ bfv,
                       float* __restrict__ out, int t,
                       const float* __restrict__ x,
                       signed char* __restrict__ Y,      // [BP][64], y/4 at scale 1
                       int* __restrict__ idx)
{
  const int b    = blockIdx.x;
  const int lane = threadIdx.x;   // 64
  const float NINF = -__builtin_inff();
  const float* lg = LG + (size_t)b * LGN;

  const int c1 = lane + 64, c2 = lane + 128;
  float v0 = lg[lane] + bfv[lane];
  float v1 = lg[c1] + bfv[c1];
  float v2 = (c2 < XDIM) ? lg[c2] + bfv[c2] : NINF;

  float m = fmaxf(v0, fmaxf(v1, v2));
  #pragma unroll
  for (int o = 32; o > 0; o >>= 1) m = fmaxf(m, __shfl_xor(m, o, 64));

  int bi = 0x7fffffff;
  if (v0 == m) bi = lane;
  if (v1 == m) bi = min(bi, c1);
  if (v2 == m) bi = min(bi, c2);
  #pragma unroll
  for (int o = 32; o > 0; o >>= 1) bi = min(bi, __shfl_xor(bi, o, 64));

  float s = __expf(v0 - m) + __expf(v1 - m) + ((c2 < XDIM) ? __expf(v2 - m) : 0.f);
  #pragma unroll
  for (int o = 32; o > 0; o >>= 1) s += __shfl_xor(s, o, 64);
  const float lse = __logf(s);

  float* orow = out + ((size_t)b * NSTEP + t) * XDIM;
  orow[lane] = v0 - m - lse;
  orow[c1]   = v1 - m - lse;
  if (c2 < XDIM) orow[c2] = v2 - m - lse;
  if (lane == 0) idx[b] = bi;

  if (t + 1 < NSTEP) {
    const float yv = (lane < CONDDIM)
        ? x[((size_t)b * NSTEP + (t + 1)) * INDIM + XDIM + lane] : 0.f;
    Y[(size_t)b * 64 + lane] = qscale(yv * 0.25f, 127.f);
  }
}

// ---------------------------------------------------------------- init: per-row scales + quantized z + zero c
__global__ void initq_k(const float* __restrict__ z, const float* __restrict__ x,
                        float* __restrict__ c0T, float* __restrict__ c1T,
                        signed char* __restrict__ Hz0,   // z @ s0, stride 1024
                        signed char* __restrict__ Hz1,   // z @ s1, stride 1024
                        signed char* __restrict__ Y,
                        float* __restrict__ S0, float* __restrict__ S1,
                        int* __restrict__ idx)
{
  const int b    = blockIdx.x;
  const int lane = threadIdx.x;   // 64
  const float* zr = z + (size_t)b * HIDDEN;

  float mz = 0.f;
  for (int k = lane; k < HIDDEN; k += 64) mz = fmaxf(mz, fabsf(zr[k]));
  #pragma unroll
  for (int o = 32; o > 0; o >>= 1) mz = fmaxf(mz, __shfl_xor(mz, o, 64));

  const float yv = (lane < CONDDIM) ? x[((size_t)b * NSTEP) * INDIM + XDIM + lane] : 0.f;
  float my = fabsf(yv) * 0.25f;
  #pragma unroll
  for (int o = 32; o > 0; o >>= 1) my = fmaxf(my, __shfl_xor(my, o, 64));

  const float s0 = fmaxf(fmaxf(mz, my), 1e-6f);
  const float s1 = fmaxf(mz, 1.f);
  const float i0 = 127.f / s0;
  const float i1 = 127.f / s1;

  for (int k = lane; k < HIDDEN; k += 64) {
    const float zv = zr[k];
    Hz0[(size_t)b * 1024 + k] = qscale(zv, i0);
    Hz1[(size_t)b * 1024 + k] = qscale(zv, i1);
    // zero c in tiled layout: ci = (k>>5)*(BP*32) + b*32 + (k&31)
    const size_t ci = (size_t)(k >> 5) * ((size_t)BP * 32) + (size_t)b * 32 + (k & 31);
    c0T[ci] = 0.f;
    c1T[ci] = 0.f;
  }
  Y[(size_t)b * 64 + lane] = qscale(yv * 0.25f, i0);   // y_0 @ s0 (+ zero pad)
  if (lane == 0) { S0[b] = s0; S1[b] = s1; idx[b] = 1; }
}

// ---------------------------------------------------------------- weight packing
__global__ void rowmax0_k(const float* __restrict__ Wih0, const float* __restrict__ Whh0,
                          float* __restrict__ RM, float* __restrict__ SC)
{
  const int n = blockIdx.x, lane = threadIdx.x;
  const int row = fused_row(n);
  float m = 1e-20f;
  for (int k = lane; k < HIDDEN; k += 64)  m = fmaxf(m, fabsf(Whh0[(size_t)row * HIDDEN + k]));
  for (int k = lane; k < CONDDIM; k += 64) m = fmaxf(m, 4.f * fabsf(Wih0[(size_t)row * INDIM + XDIM + k]));
  #pragma unroll
  for (int o = 32; o > 0; o >>= 1) m = fmaxf(m, __shfl_xor(m, o, 64));
  if (lane == 0) { RM[n] = m; SC[n] = m / 16129.f; }
}

__global__ void rowmax1_k(const float* __restrict__ Wih1, const float* __restrict__ Whh1,
                          float* __restrict__ RM, float* __restrict__ SC)
{
  const int n = blockIdx.x, lane = threadIdx.x;
  const int row = fused_row(n);
  float m = 1e-20f;
  for (int k = lane; k < HIDDEN; k += 64) {
    m = fmaxf(m, fabsf(Wih1[(size_t)row * HIDDEN + k]));
    m = fmaxf(m, fabsf(Whh1[(size_t)row * HIDDEN + k]));
  }
  #pragma unroll
  for (int o = 32; o > 0; o >>= 1) m = fmaxf(m, __shfl_xor(m, o, 64));
  if (lane == 0) { RM[n] = m; SC[n] = m / 16129.f; }
}

__global__ void packi0_k(const float* __restrict__ Wih0, const float* __restrict__ Whh0,
                         const float* __restrict__ RM, signed char* __restrict__ Bp)
{
  const int t = blockIdx.x * blockDim.x + threadIdx.x;
  if (t >= GN * K0P) return;
  const int n = t / K0P, k = t % K0P;
  const int row = fused_row(n);
  float v = 0.f;
  if (k < HIDDEN)                v = Whh0[(size_t)row * HIDDEN + k];
  else if (k < HIDDEN + CONDDIM) v = 4.f * Wih0[(size_t)row * INDIM + XDIM + (k - HIDDEN)];
  Bp[t] = qscale(v, 127.f / RM[n]);
}

__global__ void packi1_k(const float* __restrict__ Wih1, const float* __restrict__ Whh1,
                         const float* __restrict__ RM, signed char* __restrict__ Bp)
{
  const int t = blockIdx.x * blockDim.x + threadIdx.x;
  if (t >= GN * K1P) return;
  const int n = t >> 11, k = t & 2047;
  const int row = fused_row(n);
  const float v = (k < HIDDEN) ? Wih1[(size_t)row * HIDDEN + k]
                               : Whh1[(size_t)row * HIDDEN + (k - HIDDEN)];
  Bp[t] = qscale(v, 127.f / RM[n]);
}

__global__ void packbias_k(const float* __restrict__ bih, const float* __restrict__ bhh,
                           float* __restrict__ bc)
{
  const int n = blockIdx.x * blockDim.x + threadIdx.x;
  if (n >= GN) return;
  const int row = fused_row(n);
  bc[n] = bih[row] + bhh[row];
}

__global__ void rowmaxf_k(const float* __restrict__ Wf, float* __restrict__ RM,
                          float* __restrict__ SC)
{
  const int n = blockIdx.x, lane = threadIdx.x;
  float m = 1e-20f;
  if (n < XDIM)
    for (int k = lane; k < HIDDEN; k += 64) m = fmaxf(m, fabsf(Wf[(size_t)n * HIDDEN + k]));
  else m = 1.f;
  #pragma unroll
  for (int o = 32; o > 0; o >>= 1) m = fmaxf(m, __shfl_xor(m, o, 64));
  if (lane == 0) { RM[n] = m; SC[n] = m / 16129.f; }
}

__global__ void packfi_k(const float* __restrict__ Wf, const float* __restrict__ RM,
                         signed char* __restrict__ Wfi)
{
  const int t = blockIdx.x * blockDim.x + threadIdx.x;
  if (t >= LGN * HIDDEN) return;
  const int r = t >> 10, k = t & 1023;
  const float v = (r < XDIM) ? Wf[(size_t)r * HIDDEN + k] : 0.f;
  Wfi[t] = qscale(v, 127.f / RM[r]);
}

__global__ void packt_k(const float* __restrict__ Wih0, float* __restrict__ W0T)
{
  const int t = blockIdx.x * blockDim.x + threadIdx.x;
  if (t >= XDIM * GN) return;
  const int e = t >> 12, n = t & 4095;
  W0T[t] = Wih0[(size_t)fused_row(n) * INDIM + e];
}

// ---------------------------------------------------------------- launch
extern "C" void kernel_launch(void* const* d_in, const int* in_sizes, int n_in,
                              void* d_out, int out_size, void* d_ws, size_t ws_size,
                              hipStream_t stream)
{
  const float* z    = (const float*)d_in[0];
  const float* x    = (const float*)d_in[1];
  const float* Wih0 = (const float*)d_in[2];
  const float* Whh0 = (const float*)d_in[3];
  const float* bih0 = (const float*)d_in[4];
  const float* bhh0 = (const float*)d_in[5];
  const float* Wih1 = (const float*)d_in[6];
  const float* Whh1 = (const float*)d_in[7];
  const float* bih1 = (const float*)d_in[8];
  const float* bhh1 = (const float*)d_in[9];
  const float* Wf   = (const float*)d_in[10];
  const float* bfv  = (const float*)d_in[11];
  float* out = (float*)d_out;

  char* ws = (char*)d_ws;
  size_t off = 0;
  auto alloc = [&](size_t bytes) { void* p = ws + off; off += (bytes + 255) & ~(size_t)255; return p; };

  float*       LG   = (float*)      alloc((size_t)BP * LGN * 4);
  signed char* H0a  = (signed char*)alloc((size_t)BP * 1024);
  signed char* H0b  = (signed char*)alloc((size_t)BP * 1024);
  signed char* H0s1 = (signed char*)alloc((size_t)BP * 1024);   // h0'_0 @ s1 (t=0 only)
  signed char* H1a  = (signed char*)alloc((size_t)BP * 1024);
  signed char* H1b  = (signed char*)alloc((size_t)BP * 1024);
  signed char* Y    = (signed char*)alloc((size_t)BP * 64);
  signed char* Bpi0 = (signed char*)alloc((size_t)GN * K0P);
  signed char* Bpi1 = (signed char*)alloc((size_t)GN * K1P);
  signed char* Wfi  = (signed char*)alloc((size_t)LGN * HIDDEN);
  float*       W0T  = (float*)      alloc((size_t)XDIM * GN * 4);
  float*       bc0  = (float*)      alloc((size_t)GN * 4);
  float*       bc1  = (float*)      alloc((size_t)GN * 4);
  float*       RM0  = (float*)      alloc((size_t)GN * 4);
  float*       SC0  = (float*)      alloc((size_t)GN * 4);
  float*       RM1  = (float*)      alloc((size_t)GN * 4);
  float*       SC1  = (float*)      alloc((size_t)GN * 4);
  float*       RMf  = (float*)      alloc((size_t)LGN * 4);
  float*       SCf  = (float*)      alloc((size_t)LGN * 4);
  float*       S0   = (float*)      alloc((size_t)BP * 4);
  float*       S1   = (float*)      alloc((size_t)BP * 4);
  float*       c0T  = (float*)      alloc((size_t)BP * HIDDEN * 4);
  float*       c1T  = (float*)      alloc((size_t)BP * HIDDEN * 4);
  int*         idx  = (int*)        alloc((size_t)BP * 4);
  (void)ws_size; (void)in_sizes; (void)n_in; (void)out_size;

  rowmax0_k<<<GN, 64, 0, stream>>>(Wih0, Whh0, RM0, SC0);
  rowmax1_k<<<GN, 64, 0, stream>>>(Wih1, Whh1, RM1, SC1);
  rowmaxf_k<<<LGN, 64, 0, stream>>>(Wf, RMf, SCf);
  packi0_k<<<(GN * K0P + 255) / 256, 256, 0, stream>>>(Wih0, Whh0, RM0, Bpi0);
  packi1_k<<<(GN * K1P + 255) / 256, 256, 0, stream>>>(Wih1, Whh1, RM1, Bpi1);
  packfi_k<<<(LGN * HIDDEN + 255) / 256, 256, 0, stream>>>(Wf, RMf, Wfi);
  packbias_k<<<(GN + 255) / 256, 256, 0, stream>>>(bih0, bhh0, bc0);
  packbias_k<<<(GN + 255) / 256, 256, 0, stream>>>(bih1, bhh1, bc1);
  packt_k<<<(XDIM * GN + 255) / 256, 256, 0, stream>>>(Wih0, W0T);
  // initq: z@s0 -> H0b (= H0prev at t=0), z@s1 -> H1b (= H1prev at t=0)
  initq_k<<<BP, 64, 0, stream>>>(z, x, c0T, c1T, H0b, H1b, Y, S0, S1, idx);

  for (int t = 0; t < NSTEP; ++t) {
    signed char* H0cur  = (t & 1) ? H0b : H0a;
    signed char* H0prev = (t & 1) ? H0a : H0b;
    signed char* H1cur  = (t & 1) ? H1b : H1a;
    signed char* H1prev = (t & 1) ? H1a : H1b;

    // layer 0: A = [h0_{t-1} | y_t], fused cell -> h0' (written once, scale 1)
    gemm_i8_cell_k<true><<<1024, 256, 0, stream>>>(
        H0prev, Y, 64, Bpi0, K0P, bc0, SC0,
        (t == 0) ? S0 : nullptr, W0T, idx, c0T,
        H0cur,
        (t == 0) ? H0s1 : nullptr, S1);     // extra s1-scaled copy at t=0 only
    // layer 1: A = [h0'_t | h1_{t-1}], fused cell -> h1'
    gemm_i8_cell_k<false><<<1024, 256, 0, stream>>>(
        (t == 0) ? H0s1 : H0cur, H1prev, 1024, Bpi1, K1P, bc1, SC1,
        (t == 0) ? S1 : nullptr, nullptr, nullptr, c1T,
        H1cur, nullptr, nullptr);
    // logits from int8 h1' (scale 1/127)
    logits_i8_k<<<dim3(LGN / 128, BP / 64), dim3(256), 0, stream>>>(
        H1cur, 1024, Wfi, SCf, LG, LGN);
    smax_k<<<BP, 64, 0, stream>>>(LG, bfv, out, t, x, Y, idx);
  }
}

// Round 16
// 1693.875 us; speedup vs baseline: 1.1510x; 1.0037x over previous
//
#include <hip/hip_runtime.h>
#include <hip/hip_bf16.h>

#define HIDDEN   1024
#define XDIM     130
#define CONDDIM  44
#define INDIM    174      // XDIM + CONDDIM
#define NSTEP    16
#define BP       4096     // effective batch (64*64)
#define K0P      1088     // 1024 (h) + 64 (y pad) ; i8: 17 tiles of 64
#define K1P      2048     // 1024 + 1024           ; i8: 32 tiles of 64
#define GN       4096     // 4*HIDDEN gate dim
#define LGN      256      // padded logits cols (130 -> 256)
#define SPLITK   16       // A-tiles < SPLITK from Alo (stride 1024), else Ahi

typedef float f32x4 __attribute__((ext_vector_type(4)));
typedef int   i32x4 __attribute__((ext_vector_type(4)));

// fused gate column order: n in [0,4096) -> q=(n>>4)&3 (gate), j=((n>>6)<<4)|(n&15)
__device__ __forceinline__ int fused_row(int n) {
  const int q = (n >> 4) & 3;
  const int j = ((n >> 6) << 4) | (n & 15);
  return q * HIDDEN + j;
}

__device__ __forceinline__ void g2lds16(const void* g, void* l) {
  __builtin_amdgcn_global_load_lds(
      (const __attribute__((address_space(1))) void*)g,
      (__attribute__((address_space(3))) void*)l, 16, 0, 0);
}

__device__ __forceinline__ float sigm(float x)  { return 1.f / (1.f + __expf(-x)); }
__device__ __forceinline__ float tanhfast(float x) { return 2.f / (1.f + __expf(-2.f * x)) - 1.f; }

__device__ __forceinline__ signed char qscale(float v, float inv127s) {
  int q = __float2int_rn(v * inv127s);
  q = q > 127 ? 127 : (q < -127 ? -127 : q);
  return (signed char)q;
}

// ================================================================ int8 gate GEMM + fused LSTM cell
// R16 = R13 bytes + R15 concurrency: 256x256 tile (16x panel re-reads, minimal
// FETCH) with only 2 LDS buffers (64 KB) -> launch_bounds(512,2) = 2 blocks/CU.
// Rectangular XCD swizzle: 16x16 tile grid as 4x2 super-tiles of (4m x 8n) per
// XCD, m-major inside so the B panel (512 KB) stays L2-resident.
// Tiled c layout (block-contiguous), single-write h via split-A staging.
template<bool FB>
__global__ __launch_bounds__(512, 2)
void gemm_i8_cell_k(const signed char* __restrict__ Alo,   // stride 1024
                    const signed char* __restrict__ Ahi, int ahstr,
                    const signed char* __restrict__ W, int K,
                    const float* __restrict__ bcomb,
                    const float* __restrict__ SC,        // Rmax/127^2, fused order
                    const float* __restrict__ sA,        // per-row A scale (or null)
                    const float* __restrict__ W0T,       // 130 x 4096 fused (FB only)
                    const int*   __restrict__ idx,       // feedback index (FB only)
                    float* __restrict__ cT,              // tiled: [j>>5][b][j&31] fp32
                    signed char* __restrict__ d1,        // stride 1024, scale 1
                    signed char* __restrict__ d2,        // stride 1024, scale sD2 (or null)
                    const float* __restrict__ sD2)
{
  __shared__ __align__(16) signed char lds[2 * 32768];   // 2 buf x (A 16KB + B 16KB)

  const int tid  = threadIdx.x;
  const int w    = tid >> 6;        // wave 0..7
  const int lane = tid & 63;
  const int bid  = blockIdx.x;      // 256 blocks
  // rectangular XCD swizzle: xcd (bid&7) owns a 4m x 8n tile rectangle; m-major inside
  const int xcd  = bid & 7;
  const int rr   = bid >> 3;        // 0..31
  const int mt   = (xcd >> 1) * 4 + (rr & 3);
  const int nt   = (xcd & 1) * 8 + (rr >> 2);
  const int m0   = mt * 256;
  const int n0   = nt * 256;
  const int wm   = w >> 2;          // 0..1 : 128-row half
  const int wn   = w & 3;           // 0..3 : 64-col quarter
  const int fr   = lane & 15;
  const int kqs  = (((lane >> 4) ^ ((fr >> 1) & 3)) * 16);   // swizzled 16B chunk
  const int sr   = lane >> 2;
  const int sc   = (((lane & 3) ^ ((sr >> 1) & 3)) * 16);    // pre-XORed source chunk
  const int NT   = K >> 6;          // K-tiles of 64 int8 (64 B rows)

  const int fq = lane >> 4;
  const int cb = n0 + wn * 64;
  const int j  = ((cb >> 6) << 4) | fr;

  i32x4 acc[8][4] = {};

  auto stA = [&](int t, int buf) {
    const signed char* ab; size_t astr; int koff;
    if (t < SPLITK) { ab = Alo; astr = 1024;          koff = t * 64; }
    else            { ab = Ahi; astr = (size_t)ahstr; koff = (t - SPLITK) * 64; }
    #pragma unroll
    for (int i = 0; i < 2; ++i)
      g2lds16(ab + (size_t)(m0 + w * 32 + i * 16 + sr) * astr + (koff + sc),
              (void*)(lds + buf * 32768 + (w * 32 + i * 16) * 64));
  };
  auto stB = [&](int t, int buf) {
    #pragma unroll
    for (int i = 0; i < 2; ++i)
      g2lds16(W + (size_t)(n0 + w * 32 + i * 16 + sr) * K + (t * 64 + sc),
              (void*)(lds + buf * 32768 + 16384 + (w * 32 + i * 16) * 64));
  };

  // prologue: tiles 0,1 into bufs 0,1; wait tile 0 (tile 1 stays in flight)
  stA(0, 0); stB(0, 0);
  stA(1, 1); stB(1, 1);
  asm volatile("s_waitcnt vmcnt(4)" ::: "memory");
  __builtin_amdgcn_s_barrier();

  for (int t = 0; t < NT; ++t) {
    const int buf = t & 1;
    const signed char* As = lds + buf * 32768;
    const signed char* Bs = As + 16384;

    i32x4 afr[8], bfr[4];
    #pragma unroll
    for (int q = 0; q < 8; ++q)
      afr[q] = *reinterpret_cast<const i32x4*>(&As[(wm * 128 + q * 16 + fr) * 64 + kqs]);
    #pragma unroll
    for (int nf = 0; nf < 4; ++nf)
      bfr[nf] = *reinterpret_cast<const i32x4*>(&Bs[(wn * 64 + nf * 16 + fr) * 64 + kqs]);
    // all reads landed before any wave restages this buffer
    asm volatile("s_waitcnt lgkmcnt(0)" ::: "memory");
    __builtin_amdgcn_s_barrier();
    if (t + 2 < NT) { stA(t + 2, buf); stB(t + 2, buf); }

    __builtin_amdgcn_s_setprio(1);
    #pragma unroll
    for (int q = 0; q < 8; ++q)
      #pragma unroll
      for (int nf = 0; nf < 4; ++nf)
        acc[q][nf] = __builtin_amdgcn_mfma_i32_16x16x64_i8(afr[q], bfr[nf], acc[q][nf], 0, 0, 0);
    __builtin_amdgcn_s_setprio(0);

    if (t + 1 < NT) {
      if (t + 2 < NT) asm volatile("s_waitcnt vmcnt(4)" ::: "memory");  // t+1 landed
      else            asm volatile("s_waitcnt vmcnt(0)" ::: "memory");
      __builtin_amdgcn_s_barrier();
    }
  }

  // ---- fused LSTM cell epilogue ----
  const float bs0 = bcomb[cb + fr],      sc0 = SC[cb + fr];
  const float bs1 = bcomb[cb + 16 + fr], sc1 = SC[cb + 16 + fr];
  const float bs2 = bcomb[cb + 32 + fr], sc2 = SC[cb + 32 + fr];
  const float bs3 = bcomb[cb + 48 + fr], sc3 = SC[cb + 48 + fr];
  const size_t ctbase = (size_t)(j >> 5) * ((size_t)BP * 32) + (j & 31);

  #pragma unroll
  for (int mf = 0; mf < 8; ++mf) {
    #pragma unroll
    for (int r = 0; r < 4; ++r) {
      const int b = m0 + wm * 128 + mf * 16 + fq * 4 + r;
      const float sa = sA ? sA[b] : 1.f;
      float gi = (float)acc[mf][0][r] * (sc0 * sa) + bs0;
      float gf = (float)acc[mf][1][r] * (sc1 * sa) + bs1;
      float gg = (float)acc[mf][2][r] * (sc2 * sa) + bs2;
      float go = (float)acc[mf][3][r] * (sc3 * sa) + bs3;
      if (FB) {
        const float* wr = W0T + (size_t)idx[b] * GN;
        gi += wr[cb + fr];
        gf += wr[cb + 16 + fr];
        gg += wr[cb + 32 + fr];
        go += wr[cb + 48 + fr];
      }
      const size_t ci = ctbase + (size_t)b * 32;
      const float cn = sigm(gf) * cT[ci] + sigm(gi) * tanhfast(gg);
      cT[ci] = cn;
      const float hn = sigm(go) * tanhfast(cn);
      d1[(size_t)b * 1024 + j] = qscale(hn, 127.f);
      if (d2) d2[(size_t)b * 1024 + j] = qscale(hn, 127.f / sD2[b]);
    }
  }
}

// ---------------------------------------------------------------- int8 logits GEMM (64x128 tile, 128 blocks)
__global__ __launch_bounds__(256, 4)
void logits_i8_k(const signed char* __restrict__ A, int lda,   // h1' rows (stride 1024)
                 const signed char* __restrict__ Wfi,          // [256][1024] int8
                 const float* __restrict__ SCf,                // RMf/127^2
                 float* __restrict__ C, int ldc)
{
  __shared__ __align__(16) signed char As[64 * 64];    // 4 KB
  __shared__ __align__(16) signed char Bs[128 * 64];   // 8 KB

  const int tid  = threadIdx.x;
  const int w    = tid >> 6;
  const int lane = tid & 63;
  const int m0 = blockIdx.y * 64;
  const int n0 = blockIdx.x * 128;
  const int wm = w >> 1;
  const int wn = w & 1;
  const int fr = lane & 15;
  const int kqs = (((lane >> 4) ^ ((fr >> 1) & 3)) * 16);
  const int sr  = lane >> 2;
  const int sc  = (((lane & 3) ^ ((sr >> 1) & 3)) * 16);

  i32x4 acc[2][4] = {};

  for (int k0 = 0; k0 < HIDDEN; k0 += 64) {
    __syncthreads();
    g2lds16(A + (size_t)(m0 + w * 16 + sr) * lda + (k0 + sc), (void*)(As + (w * 16) * 64));
    g2lds16(Wfi + (size_t)(n0 + w * 16 + sr) * HIDDEN + (k0 + sc), (void*)(Bs + (w * 16) * 64));
    g2lds16(Wfi + (size_t)(n0 + 64 + w * 16 + sr) * HIDDEN + (k0 + sc), (void*)(Bs + (64 + w * 16) * 64));
    __syncthreads();

    i32x4 af[2], bw[4];
    #pragma unroll
    for (int i = 0; i < 2; ++i)
      af[i] = *reinterpret_cast<const i32x4*>(&As[(wm * 32 + i * 16 + fr) * 64 + kqs]);
    #pragma unroll
    for (int jn = 0; jn < 4; ++jn)
      bw[jn] = *reinterpret_cast<const i32x4*>(&Bs[(wn * 64 + jn * 16 + fr) * 64 + kqs]);
    #pragma unroll
    for (int i = 0; i < 2; ++i)
      #pragma unroll
      for (int jn = 0; jn < 4; ++jn)
        acc[i][jn] = __builtin_amdgcn_mfma_i32_16x16x64_i8(af[i], bw[jn], acc[i][jn], 0, 0, 0);
  }

  const int fq = lane >> 4;
  #pragma unroll
  for (int i = 0; i < 2; ++i)
    #pragma unroll
    for (int jn = 0; jn < 4; ++jn) {
      const int col = n0 + wn * 64 + jn * 16 + fr;
      const float scf = SCf[col];
      #pragma unroll
      for (int r = 0; r < 4; ++r) {
        const int row = m0 + wm * 32 + i * 16 + fq * 4 + r;
        C[(size_t)row * ldc + col] = (float)acc[i][jn][r] * scf;
      }
    }
}

// ---------------------------------------------------------------- log_softmax + argmax + y staging
__global__ void smax_k(const float* __restrict__ LG,
                       const float* __restrict__ bfv,
                       float* __restrict__ out, int t,
                       const float* __restrict__ x,
                       signed char* __restrict__ Y,      // [BP][64], y/4 at scale 1
                       int* __restrict__ idx)
{
  const int b    = blockIdx.x;
  const int lane = threadIdx.x;   // 64
  const float NINF = -__builtin_inff();
  const float* lg = LG + (size_t)b * LGN;

  const int c1 = lane + 64, c2 = lane + 128;
  float v0 = lg[lane] + bfv[lane];
  float v1 = lg[c1] + bfv[c1];
  float v2 = (c2 < XDIM) ? lg[c2] + bfv[c2] : NINF;

  float m = fmaxf(v0, fmaxf(v1, v2));
  #pragma unroll
  for (int o = 32; o > 0; o >>= 1) m = fmaxf(m, __shfl_xor(m, o, 64));

  int bi = 0x7fffffff;
  if (v0 == m) bi = lane;
  if (v1 == m) bi = min(bi, c1);
  if (v2 == m) bi = min(bi, c2);
  #pragma unroll
  for (int o = 32; o > 0; o >>= 1) bi = min(bi, __shfl_xor(bi, o, 64));

  float s = __expf(v0 - m) + __expf(v1 - m) + ((c2 < XDIM) ? __expf(v2 - m) : 0.f);
  #pragma unroll
  for (int o = 32; o > 0; o >>= 1) s += __shfl_xor(s, o, 64);
  const float lse = __logf(s);

  float* orow = out + ((size_t)b * NSTEP + t) * XDIM;
  orow[lane] = v0 - m - lse;
  orow[c1]   = v1 - m - lse;
  if (c2 < XDIM) orow[c2] = v2 - m - lse;
  if (lane == 0) idx[b] = bi;

  if (t + 1 < NSTEP) {
    const float yv = (lane < CONDDIM)
        ? x[((size_t)b * NSTEP + (t + 1)) * INDIM + XDIM + lane] : 0.f;
    Y[(size_t)b * 64 + lane] = qscale(yv * 0.25f, 127.f);
  }
}

// ---------------------------------------------------------------- init: per-row scales + quantized z + zero c
__global__ void initq_k(const float* __restrict__ z, const float* __restrict__ x,
                        float* __restrict__ c0T, float* __restrict__ c1T,
                        signed char* __restrict__ Hz0,   // z @ s0, stride 1024
                        signed char* __restrict__ Hz1,   // z @ s1, stride 1024
                        signed char* __restrict__ Y,
                        float* __restrict__ S0, float* __restrict__ S1,
                        int* __restrict__ idx)
{
  const int b    = blockIdx.x;
  const int lane = threadIdx.x;   // 64
  const float* zr = z + (size_t)b * HIDDEN;

  float mz = 0.f;
  for (int k = lane; k < HIDDEN; k += 64) mz = fmaxf(mz, fabsf(zr[k]));
  #pragma unroll
  for (int o = 32; o > 0; o >>= 1) mz = fmaxf(mz, __shfl_xor(mz, o, 64));

  const float yv = (lane < CONDDIM) ? x[((size_t)b * NSTEP) * INDIM + XDIM + lane] : 0.f;
  float my = fabsf(yv) * 0.25f;
  #pragma unroll
  for (int o = 32; o > 0; o >>= 1) my = fmaxf(my, __shfl_xor(my, o, 64));

  const float s0 = fmaxf(fmaxf(mz, my), 1e-6f);
  const float s1 = fmaxf(mz, 1.f);
  const float i0 = 127.f / s0;
  const float i1 = 127.f / s1;

  for (int k = lane; k < HIDDEN; k += 64) {
    const float zv = zr[k];
    Hz0[(size_t)b * 1024 + k] = qscale(zv, i0);
    Hz1[(size_t)b * 1024 + k] = qscale(zv, i1);
    const size_t ci = (size_t)(k >> 5) * ((size_t)BP * 32) + (size_t)b * 32 + (k & 31);
    c0T[ci] = 0.f;
    c1T[ci] = 0.f;
  }
  Y[(size_t)b * 64 + lane] = qscale(yv * 0.25f, i0);   // y_0 @ s0 (+ zero pad)
  if (lane == 0) { S0[b] = s0; S1[b] = s1; idx[b] = 1; }
}

// ---------------------------------------------------------------- weight packing
__global__ void rowmax0_k(const float* __restrict__ Wih0, const float* __restrict__ Whh0,
                          float* __restrict__ RM, float* __restrict__ SC)
{
  const int n = blockIdx.x, lane = threadIdx.x;
  const int row = fused_row(n);
  float m = 1e-20f;
  for (int k = lane; k < HIDDEN; k += 64)  m = fmaxf(m, fabsf(Whh0[(size_t)row * HIDDEN + k]));
  for (int k = lane; k < CONDDIM; k += 64) m = fmaxf(m, 4.f * fabsf(Wih0[(size_t)row * INDIM + XDIM + k]));
  #pragma unroll
  for (int o = 32; o > 0; o >>= 1) m = fmaxf(m, __shfl_xor(m, o, 64));
  if (lane == 0) { RM[n] = m; SC[n] = m / 16129.f; }
}

__global__ void rowmax1_k(const float* __restrict__ Wih1, const float* __restrict__ Whh1,
                          float* __restrict__ RM, float* __restrict__ SC)
{
  const int n = blockIdx.x, lane = threadIdx.x;
  const int row = fused_row(n);
  float m = 1e-20f;
  for (int k = lane; k < HIDDEN; k += 64) {
    m = fmaxf(m, fabsf(Wih1[(size_t)row * HIDDEN + k]));
    m = fmaxf(m, fabsf(Whh1[(size_t)row * HIDDEN + k]));
  }
  #pragma unroll
  for (int o = 32; o > 0; o >>= 1) m = fmaxf(m, __shfl_xor(m, o, 64));
  if (lane == 0) { RM[n] = m; SC[n] = m / 16129.f; }
}

__global__ void packi0_k(const float* __restrict__ Wih0, const float* __restrict__ Whh0,
                         const float* __restrict__ RM, signed char* __restrict__ Bp)
{
  const int t = blockIdx.x * blockDim.x + threadIdx.x;
  if (t >= GN * K0P) return;
  const int n = t / K0P, k = t % K0P;
  const int row = fused_row(n);
  float v = 0.f;
  if (k < HIDDEN)                v = Whh0[(size_t)row * HIDDEN + k];
  else if (k < HIDDEN + CONDDIM) v = 4.f * Wih0[(size_t)row * INDIM + XDIM + (k - HIDDEN)];
  Bp[t] = qscale(v, 127.f / RM[n]);
}

__global__ void packi1_k(const float* __restrict__ Wih1, const float* __restrict__ Whh1,
                         const float* __restrict__ RM, signed char* __restrict__ Bp)
{
  const int t = blockIdx.x * blockDim.x + threadIdx.x;
  if (t >= GN * K1P) return;
  const int n = t >> 11, k = t & 2047;
  const int row = fused_row(n);
  const float v = (k < HIDDEN) ? Wih1[(size_t)row * HIDDEN + k]
                               : Whh1[(size_t)row * HIDDEN + (k - HIDDEN)];
  Bp[t] = qscale(v, 127.f / RM[n]);
}

__global__ void packbias_k(const float* __restrict__ bih, const float* __restrict__ bhh,
                           float* __restrict__ bc)
{
  const int n = blockIdx.x * blockDim.x + threadIdx.x;
  if (n >= GN) return;
  const int row = fused_row(n);
  bc[n] = bih[row] + bhh[row];
}

__global__ void rowmaxf_k(const float* __restrict__ Wf, float* __restrict__ RM,
                          float* __restrict__ SC)
{
  const int n = blockIdx.x, lane = threadIdx.x;
  float m = 1e-20f;
  if (n < XDIM)
    for (int k = lane; k < HIDDEN; k += 64) m = fmaxf(m, fabsf(Wf[(size_t)n * HIDDEN + k]));
  else m = 1.f;
  #pragma unroll
  for (int o = 32; o > 0; o >>= 1) m = fmaxf(m, __shfl_xor(m, o, 64));
  if (lane == 0) { RM[n] = m; SC[n] = m / 16129.f; }
}

__global__ void packfi_k(const float* __restrict__ Wf, const float* __restrict__ RM,
                         signed char* __restrict__ Wfi)
{
  const int t = blockIdx.x * blockDim.x + threadIdx.x;
  if (t >= LGN * HIDDEN) return;
  const int r = t >> 10, k = t & 1023;
  const float v = (r < XDIM) ? Wf[(size_t)r * HIDDEN + k] : 0.f;
  Wfi[t] = qscale(v, 127.f / RM[r]);
}

__global__ void packt_k(const float* __restrict__ Wih0, float* __restrict__ W0T)
{
  const int t = blockIdx.x * blockDim.x + threadIdx.x;
  if (t >= XDIM * GN) return;
  const int e = t >> 12, n = t & 4095;
  W0T[t] = Wih0[(size_t)fused_row(n) * INDIM + e];
}

// ---------------------------------------------------------------- launch
extern "C" void kernel_launch(void* const* d_in, const int* in_sizes, int n_in,
                              void* d_out, int out_size, void* d_ws, size_t ws_size,
                              hipStream_t stream)
{
  const float* z    = (const float*)d_in[0];
  const float* x    = (const float*)d_in[1];
  const float* Wih0 = (const float*)d_in[2];
  const float* Whh0 = (const float*)d_in[3];
  const float* bih0 = (const float*)d_in[4];
  const float* bhh0 = (const float*)d_in[5];
  const float* Wih1 = (const float*)d_in[6];
  const float* Whh1 = (const float*)d_in[7];
  const float* bih1 = (const float*)d_in[8];
  const float* bhh1 = (const float*)d_in[9];
  const float* Wf   = (const float*)d_in[10];
  const float* bfv  = (const float*)d_in[11];
  float* out = (float*)d_out;

  char* ws = (char*)d_ws;
  size_t off = 0;
  auto alloc = [&](size_t bytes) { void* p = ws + off; off += (bytes + 255) & ~(size_t)255; return p; };

  float*       LG   = (float*)      alloc((size_t)BP * LGN * 4);
  signed char* H0a  = (signed char*)alloc((size_t)BP * 1024);
  signed char* H0b  = (signed char*)alloc((size_t)BP * 1024);
  signed char* H0s1 = (signed char*)alloc((size_t)BP * 1024);   // h0'_0 @ s1 (t=0 only)
  signed char* H1a  = (signed char*)alloc((size_t)BP * 1024);
  signed char* H1b  = (signed char*)alloc((size_t)BP * 1024);
  signed char* Y    = (signed char*)alloc((size_t)BP * 64);
  signed char* Bpi0 = (signed char*)alloc((size_t)GN * K0P);
  signed char* Bpi1 = (signed char*)alloc((size_t)GN * K1P);
  signed char* Wfi  = (signed char*)alloc((size_t)LGN * HIDDEN);
  float*       W0T  = (float*)      alloc((size_t)XDIM * GN * 4);
  float*       bc0  = (float*)      alloc((size_t)GN * 4);
  float*       bc1  = (float*)      alloc((size_t)GN * 4);
  float*       RM0  = (float*)      alloc((size_t)GN * 4);
  float*       SC0  = (float*)      alloc((size_t)GN * 4);
  float*       RM1  = (float*)      alloc((size_t)GN * 4);
  float*       SC1  = (float*)      alloc((size_t)GN * 4);
  float*       RMf  = (float*)      alloc((size_t)LGN * 4);
  float*       SCf  = (float*)      alloc((size_t)LGN * 4);
  float*       S0   = (float*)      alloc((size_t)BP * 4);
  float*       S1   = (float*)      alloc((size_t)BP * 4);
  float*       c0T  = (float*)      alloc((size_t)BP * HIDDEN * 4);
  float*       c1T  = (float*)      alloc((size_t)BP * HIDDEN * 4);
  int*         idx  = (int*)        alloc((size_t)BP * 4);
  (void)ws_size; (void)in_sizes; (void)n_in; (void)out_size;

  rowmax0_k<<<GN, 64, 0, stream>>>(Wih0, Whh0, RM0, SC0);
  rowmax1_k<<<GN, 64, 0, stream>>>(Wih1, Whh1, RM1, SC1);
  rowmaxf_k<<<LGN, 64, 0, stream>>>(Wf, RMf, SCf);
  packi0_k<<<(GN * K0P + 255) / 256, 256, 0, stream>>>(Wih0, Whh0, RM0, Bpi0);
  packi1_k<<<(GN * K1P + 255) / 256, 256, 0, stream>>>(Wih1, Whh1, RM1, Bpi1);
  packfi_k<<<(LGN * HIDDEN + 255) / 256, 256, 0, stream>>>(Wf, RMf, Wfi);
  packbias_k<<<(GN + 255) / 256, 256, 0, stream>>>(bih0, bhh0, bc0);
  packbias_k<<<(GN + 255) / 256, 256, 0, stream>>>(bih1, bhh1, bc1);
  packt_k<<<(XDIM * GN + 255) / 256, 256, 0, stream>>>(Wih0, W0T);
  // initq: z@s0 -> H0b (= H0prev at t=0), z@s1 -> H1b (= H1prev at t=0)
  initq_k<<<BP, 64, 0, stream>>>(z, x, c0T, c1T, H0b, H1b, Y, S0, S1, idx);

  for (int t = 0; t < NSTEP; ++t) {
    signed char* H0cur  = (t & 1) ? H0b : H0a;
    signed char* H0prev = (t & 1) ? H0a : H0b;
    signed char* H1cur  = (t & 1) ? H1b : H1a;
    signed char* H1prev = (t & 1) ? H1a : H1b;

    // layer 0: A = [h0_{t-1} | y_t], fused cell -> h0' (written once, scale 1)
    gemm_i8_cell_k<true><<<256, 512, 0, stream>>>(
        H0prev, Y, 64, Bpi0, K0P, bc0, SC0,
        (t == 0) ? S0 : nullptr, W0T, idx, c0T,
        H0cur,
        (t == 0) ? H0s1 : nullptr, S1);     // extra s1-scaled copy at t=0 only
    // layer 1: A = [h0'_t | h1_{t-1}], fused cell -> h1'
    gemm_i8_cell_k<false><<<256, 512, 0, stream>>>(
        (t == 0) ? H0s1 : H0cur, H1prev, 1024, Bpi1, K1P, bc1, SC1,
        (t == 0) ? S1 : nullptr, nullptr, nullptr, c1T,
        H1cur, nullptr, nullptr);
    // logits from int8 h1' (scale 1/127)
    logits_i8_k<<<dim3(LGN / 128, BP / 64), dim3(256), 0, stream>>>(
        H1cur, 1024, Wfi, SCf, LG, LGN);
    smax_k<<<BP, 64, 0, stream>>>(LG, bfv, out, t, x, Y, idx);
  }
}

// Round 17
// 1579.722 us; speedup vs baseline: 1.2342x; 1.0723x over previous
//
#include <hip/hip_runtime.h>
#include <hip/hip_bf16.h>

#define HIDDEN   1024
#define XDIM     130
#define CONDDIM  44
#define INDIM    174      // XDIM + CONDDIM
#define NSTEP    16
#define BP       4096     // effective batch (64*64)
#define K0P      1088     // 1024 (h) + 64 (y pad) ; i8: 17 tiles of 64
#define K1P      2048     // 1024 + 1024           ; i8: 32 tiles of 64
#define GN       4096     // 4*HIDDEN gate dim
#define LGN      256      // padded logits cols (130 -> 256)
#define SPLITK   16       // A-tiles < SPLITK from Alo (stride 1024), else Ahi

typedef float f32x4 __attribute__((ext_vector_type(4)));
typedef int   i32x4 __attribute__((ext_vector_type(4)));

// fused gate column order: n in [0,4096) -> q=(n>>4)&3 (gate), j=((n>>6)<<4)|(n&15)
__device__ __forceinline__ int fused_row(int n) {
  const int q = (n >> 4) & 3;
  const int j = ((n >> 6) << 4) | (n & 15);
  return q * HIDDEN + j;
}

__device__ __forceinline__ void g2lds16(const void* g, void* l) {
  __builtin_amdgcn_global_load_lds(
      (const __attribute__((address_space(1))) void*)g,
      (__attribute__((address_space(3))) void*)l, 16, 0, 0);
}

__device__ __forceinline__ float sigm(float x)  { return 1.f / (1.f + __expf(-x)); }
__device__ __forceinline__ float tanhfast(float x) { return 2.f / (1.f + __expf(-2.f * x)) - 1.f; }

__device__ __forceinline__ signed char qscale(float v, float inv127s) {
  int q = __float2int_rn(v * inv127s);
  q = q > 127 ? 127 : (q < -127 ? -127 : q);
  return (signed char)q;
}

// ================================================================ int8 gate GEMM + fused LSTM cell
// R17: gate dispatch = bytes / (concurrency-limited BW). R13/R16 had minimal
// bytes at 1 block/CU (1 TB/s); R15 had 2x bytes at 3 blocks/CU (2 TB/s).
// This round: 256m x 128n tile -> 512 blocks, launch_bounds(512,4) = 2 blocks/CU
// (the 2nd arg is waves/SIMD: 512-thread blocks need 4 for 2 blocks/CU).
// 8 waves = 4m x 2n, per-wave 64x64 (one full gate quad per wave -> in-register
// cell kept). LDS 2 x (A 16KB + B 8KB) = 48 KB. Staging 3 gloads/wave/tile,
// counted vmcnt(3) 1-ahead pipeline. XCD swizzle: 8m x 8n rectangle, m-major.
template<bool FB>
__global__ __launch_bounds__(512, 4)
void gemm_i8_cell_k(const signed char* __restrict__ Alo,   // stride 1024
                    const signed char* __restrict__ Ahi, int ahstr,
                    const signed char* __restrict__ W, int K,
                    const float* __restrict__ bcomb,
                    const float* __restrict__ SC,        // Rmax/127^2, fused order
                    const float* __restrict__ sA,        // per-row A scale (or null)
                    const float* __restrict__ W0T,       // 130 x 4096 fused (FB only)
                    const int*   __restrict__ idx,       // feedback index (FB only)
                    float* __restrict__ cT,              // tiled: [j>>5][b][j&31] fp32
                    signed char* __restrict__ d1,        // stride 1024, scale 1
                    signed char* __restrict__ d2,        // stride 1024, scale sD2 (or null)
                    const float* __restrict__ sD2)
{
  __shared__ __align__(16) signed char lds[2 * 24576];   // 2 buf x (A 16KB + B 8KB)

  const int tid  = threadIdx.x;
  const int w    = tid >> 6;        // wave 0..7
  const int lane = tid & 63;
  const int bid  = blockIdx.x;      // 512 blocks (16 m-tiles x 32 n-tiles)
  // XCD swizzle: each XCD owns an 8m x 8n rectangle, m-major inside
  const int xcd  = bid & 7;
  const int rr   = bid >> 3;        // 0..63
  const int mt   = (xcd & 1) * 8 + (rr & 7);
  const int nt   = (xcd >> 1) * 8 + (rr >> 3);
  const int m0   = mt * 256;
  const int n0   = nt * 128;
  const int wm   = w >> 1;          // 0..3 : 64-row quarter
  const int wn   = w & 1;           // 0..1 : 64-col half
  const int fr   = lane & 15;
  const int kqs  = (((lane >> 4) ^ ((fr >> 1) & 3)) * 16);   // swizzled 16B chunk
  const int sr   = lane >> 2;
  const int sc   = (((lane & 3) ^ ((sr >> 1) & 3)) * 16);    // pre-XORed source chunk
  const int NT   = K >> 6;          // K-tiles of 64 int8 (64 B rows)

  const int fq = lane >> 4;
  const int cb = n0 + wn * 64;
  const int j  = ((cb >> 6) << 4) | fr;

  i32x4 acc[4][4] = {};

  auto stA = [&](int t, int buf) {          // 2 issues: rows w*32 + {0,16} + sr
    const signed char* ab; size_t astr; int koff;
    if (t < SPLITK) { ab = Alo; astr = 1024;          koff = t * 64; }
    else            { ab = Ahi; astr = (size_t)ahstr; koff = (t - SPLITK) * 64; }
    #pragma unroll
    for (int i = 0; i < 2; ++i)
      g2lds16(ab + (size_t)(m0 + w * 32 + i * 16 + sr) * astr + (koff + sc),
              (void*)(lds + buf * 24576 + (w * 32 + i * 16) * 64));
  };
  auto stB = [&](int t, int buf) {          // 1 issue: rows w*16 + sr (128 rows)
    g2lds16(W + (size_t)(n0 + w * 16 + sr) * K + (t * 64 + sc),
            (void*)(lds + buf * 24576 + 16384 + (w * 16) * 64));
  };

  // prologue: tiles 0,1 into bufs 0,1; wait tile 0 (tile 1's 3 ops in flight)
  stA(0, 0); stB(0, 0);
  stA(1, 1); stB(1, 1);
  asm volatile("s_waitcnt vmcnt(3)" ::: "memory");
  __builtin_amdgcn_s_barrier();

  for (int t = 0; t < NT; ++t) {
    const int buf = t & 1;
    const signed char* As = lds + buf * 24576;
    const signed char* Bs = As + 16384;

    i32x4 afr[4], bfr[4];
    #pragma unroll
    for (int q = 0; q < 4; ++q)
      afr[q] = *reinterpret_cast<const i32x4*>(&As[(wm * 64 + q * 16 + fr) * 64 + kqs]);
    #pragma unroll
    for (int nf = 0; nf < 4; ++nf)
      bfr[nf] = *reinterpret_cast<const i32x4*>(&Bs[(wn * 64 + nf * 16 + fr) * 64 + kqs]);
    // all reads landed before any wave restages this buffer
    asm volatile("s_waitcnt lgkmcnt(0)" ::: "memory");
    __builtin_amdgcn_s_barrier();
    if (t + 2 < NT) { stA(t + 2, buf); stB(t + 2, buf); }

    __builtin_amdgcn_s_setprio(1);
    #pragma unroll
    for (int q = 0; q < 4; ++q)
      #pragma unroll
      for (int nf = 0; nf < 4; ++nf)
        acc[q][nf] = __builtin_amdgcn_mfma_i32_16x16x64_i8(afr[q], bfr[nf], acc[q][nf], 0, 0, 0);
    __builtin_amdgcn_s_setprio(0);

    if (t + 1 < NT) {
      if (t + 2 < NT) asm volatile("s_waitcnt vmcnt(3)" ::: "memory");  // t+1 landed
      else            asm volatile("s_waitcnt vmcnt(0)" ::: "memory");
      __builtin_amdgcn_s_barrier();
    }
  }

  // ---- fused LSTM cell epilogue ----
  const float bs0 = bcomb[cb + fr],      sc0 = SC[cb + fr];
  const float bs1 = bcomb[cb + 16 + fr], sc1 = SC[cb + 16 + fr];
  const float bs2 = bcomb[cb + 32 + fr], sc2 = SC[cb + 32 + fr];
  const float bs3 = bcomb[cb + 48 + fr], sc3 = SC[cb + 48 + fr];
  const size_t ctbase = (size_t)(j >> 5) * ((size_t)BP * 32) + (j & 31);

  #pragma unroll
  for (int mf = 0; mf < 4; ++mf) {
    #pragma unroll
    for (int r = 0; r < 4; ++r) {
      const int b = m0 + wm * 64 + mf * 16 + fq * 4 + r;
      const float sa = sA ? sA[b] : 1.f;
      float gi = (float)acc[mf][0][r] * (sc0 * sa) + bs0;
      float gf = (float)acc[mf][1][r] * (sc1 * sa) + bs1;
      float gg = (float)acc[mf][2][r] * (sc2 * sa) + bs2;
      float go = (float)acc[mf][3][r] * (sc3 * sa) + bs3;
      if (FB) {
        const float* wr = W0T + (size_t)idx[b] * GN;
        gi += wr[cb + fr];
        gf += wr[cb + 16 + fr];
        gg += wr[cb + 32 + fr];
        go += wr[cb + 48 + fr];
      }
      const size_t ci = ctbase + (size_t)b * 32;
      const float cn = sigm(gf) * cT[ci] + sigm(gi) * tanhfast(gg);
      cT[ci] = cn;
      const float hn = sigm(go) * tanhfast(cn);
      d1[(size_t)b * 1024 + j] = qscale(hn, 127.f);
      if (d2) d2[(size_t)b * 1024 + j] = qscale(hn, 127.f / sD2[b]);
    }
  }
}

// ---------------------------------------------------------------- int8 logits GEMM (64x128 tile, 128 blocks)
__global__ __launch_bounds__(256, 4)
void logits_i8_k(const signed char* __restrict__ A, int lda,   // h1' rows (stride 1024)
                 const signed char* __restrict__ Wfi,          // [256][1024] int8
                 const float* __restrict__ SCf,                // RMf/127^2
                 float* __restrict__ C, int ldc)
{
  __shared__ __align__(16) signed char As[64 * 64];    // 4 KB
  __shared__ __align__(16) signed char Bs[128 * 64];   // 8 KB

  const int tid  = threadIdx.x;
  const int w    = tid >> 6;
  const int lane = tid & 63;
  const int m0 = blockIdx.y * 64;
  const int n0 = blockIdx.x * 128;
  const int wm = w >> 1;
  const int wn = w & 1;
  const int fr = lane & 15;
  const int kqs = (((lane >> 4) ^ ((fr >> 1) & 3)) * 16);
  const int sr  = lane >> 2;
  const int sc  = (((lane & 3) ^ ((sr >> 1) & 3)) * 16);

  i32x4 acc[2][4] = {};

  for (int k0 = 0; k0 < HIDDEN; k0 += 64) {
    __syncthreads();
    g2lds16(A + (size_t)(m0 + w * 16 + sr) * lda + (k0 + sc), (void*)(As + (w * 16) * 64));
    g2lds16(Wfi + (size_t)(n0 + w * 16 + sr) * HIDDEN + (k0 + sc), (void*)(Bs + (w * 16) * 64));
    g2lds16(Wfi + (size_t)(n0 + 64 + w * 16 + sr) * HIDDEN + (k0 + sc), (void*)(Bs + (64 + w * 16) * 64));
    __syncthreads();

    i32x4 af[2], bw[4];
    #pragma unroll
    for (int i = 0; i < 2; ++i)
      af[i] = *reinterpret_cast<const i32x4*>(&As[(wm * 32 + i * 16 + fr) * 64 + kqs]);
    #pragma unroll
    for (int jn = 0; jn < 4; ++jn)
      bw[jn] = *reinterpret_cast<const i32x4*>(&Bs[(wn * 64 + jn * 16 + fr) * 64 + kqs]);
    #pragma unroll
    for (int i = 0; i < 2; ++i)
      #pragma unroll
      for (int jn = 0; jn < 4; ++jn)
        acc[i][jn] = __builtin_amdgcn_mfma_i32_16x16x64_i8(af[i], bw[jn], acc[i][jn], 0, 0, 0);
  }

  const int fq = lane >> 4;
  #pragma unroll
  for (int i = 0; i < 2; ++i)
    #pragma unroll
    for (int jn = 0; jn < 4; ++jn) {
      const int col = n0 + wn * 64 + jn * 16 + fr;
      const float scf = SCf[col];
      #pragma unroll
      for (int r = 0; r < 4; ++r) {
        const int row = m0 + wm * 32 + i * 16 + fq * 4 + r;
        C[(size_t)row * ldc + col] = (float)acc[i][jn][r] * scf;
      }
    }
}

// ---------------------------------------------------------------- log_softmax + argmax + y staging
__global__ void smax_k(const float* __restrict__ LG,
                       const float* __restrict__ bfv,
                       float* __restrict__ out, int t,
                       const float* __restrict__ x,
                       signed char* __restrict__ Y,      // [BP][64], y/4 at scale 1
                       int* __restrict__ idx)
{
  const int b    = blockIdx.x;
  const int lane = threadIdx.x;   // 64
  const float NINF = -__builtin_inff();
  const float* lg = LG + (size_t)b * LGN;

  const int c1 = lane + 64, c2 = lane + 128;
  float v0 = lg[lane] + bfv[lane];
  float v1 = lg[c1] + bfv[c1];
  float v2 = (c2 < XDIM) ? lg[c2] + bfv[c2] : NINF;

  float m = fmaxf(v0, fmaxf(v1, v2));
  #pragma unroll
  for (int o = 32; o > 0; o >>= 1) m = fmaxf(m, __shfl_xor(m, o, 64));

  int bi = 0x7fffffff;
  if (v0 == m) bi = lane;
  if (v1 == m) bi = min(bi, c1);
  if (v2 == m) bi = min(bi, c2);
  #pragma unroll
  for (int o = 32; o > 0; o >>= 1) bi = min(bi, __shfl_xor(bi, o, 64));

  float s = __expf(v0 - m) + __expf(v1 - m) + ((c2 < XDIM) ? __expf(v2 - m) : 0.f);
  #pragma unroll
  for (int o = 32; o > 0; o >>= 1) s += __shfl_xor(s, o, 64);
  const float lse = __logf(s);

  float* orow = out + ((size_t)b * NSTEP + t) * XDIM;
  orow[lane] = v0 - m - lse;
  orow[c1]   = v1 - m - lse;
  if (c2 < XDIM) orow[c2] = v2 - m - lse;
  if (lane == 0) idx[b] = bi;

  if (t + 1 < NSTEP) {
    const float yv = (lane < CONDDIM)
        ? x[((size_t)b * NSTEP + (t + 1)) * INDIM + XDIM + lane] : 0.f;
    Y[(size_t)b * 64 + lane] = qscale(yv * 0.25f, 127.f);
  }
}

// ---------------------------------------------------------------- init: per-row scales + quantized z + zero c
__global__ void initq_k(const float* __restrict__ z, const float* __restrict__ x,
                        float* __restrict__ c0T, float* __restrict__ c1T,
                        signed char* __restrict__ Hz0,   // z @ s0, stride 1024
                        signed char* __restrict__ Hz1,   // z @ s1, stride 1024
                        signed char* __restrict__ Y,
                        float* __restrict__ S0, float* __restrict__ S1,
                        int* __restrict__ idx)
{
  const int b    = blockIdx.x;
  const int lane = threadIdx.x;   // 64
  const float* zr = z + (size_t)b * HIDDEN;

  float mz = 0.f;
  for (int k = lane; k < HIDDEN; k += 64) mz = fmaxf(mz, fabsf(zr[k]));
  #pragma unroll
  for (int o = 32; o > 0; o >>= 1) mz = fmaxf(mz, __shfl_xor(mz, o, 64));

  const float yv = (lane < CONDDIM) ? x[((size_t)b * NSTEP) * INDIM + XDIM + lane] : 0.f;
  float my = fabsf(yv) * 0.25f;
  #pragma unroll
  for (int o = 32; o > 0; o >>= 1) my = fmaxf(my, __shfl_xor(my, o, 64));

  const float s0 = fmaxf(fmaxf(mz, my), 1e-6f);
  const float s1 = fmaxf(mz, 1.f);
  const float i0 = 127.f / s0;
  const float i1 = 127.f / s1;

  for (int k = lane; k < HIDDEN; k += 64) {
    const float zv = zr[k];
    Hz0[(size_t)b * 1024 + k] = qscale(zv, i0);
    Hz1[(size_t)b * 1024 + k] = qscale(zv, i1);
    const size_t ci = (size_t)(k >> 5) * ((size_t)BP * 32) + (size_t)b * 32 + (k & 31);
    c0T[ci] = 0.f;
    c1T[ci] = 0.f;
  }
  Y[(size_t)b * 64 + lane] = qscale(yv * 0.25f, i0);   // y_0 @ s0 (+ zero pad)
  if (lane == 0) { S0[b] = s0; S1[b] = s1; idx[b] = 1; }
}

// ---------------------------------------------------------------- weight packing
__global__ void rowmax0_k(const float* __restrict__ Wih0, const float* __restrict__ Whh0,
                          float* __restrict__ RM, float* __restrict__ SC)
{
  const int n = blockIdx.x, lane = threadIdx.x;
  const int row = fused_row(n);
  float m = 1e-20f;
  for (int k = lane; k < HIDDEN; k += 64)  m = fmaxf(m, fabsf(Whh0[(size_t)row * HIDDEN + k]));
  for (int k = lane; k < CONDDIM; k += 64) m = fmaxf(m, 4.f * fabsf(Wih0[(size_t)row * INDIM + XDIM + k]));
  #pragma unroll
  for (int o = 32; o > 0; o >>= 1) m = fmaxf(m, __shfl_xor(m, o, 64));
  if (lane == 0) { RM[n] = m; SC[n] = m / 16129.f; }
}

__global__ void rowmax1_k(const float* __restrict__ Wih1, const float* __restrict__ Whh1,
                          float* __restrict__ RM, float* __restrict__ SC)
{
  const int n = blockIdx.x, lane = threadIdx.x;
  const int row = fused_row(n);
  float m = 1e-20f;
  for (int k = lane; k < HIDDEN; k += 64) {
    m = fmaxf(m, fabsf(Wih1[(size_t)row * HIDDEN + k]));
    m = fmaxf(m, fabsf(Whh1[(size_t)row * HIDDEN + k]));
  }
  #pragma unroll
  for (int o = 32; o > 0; o >>= 1) m = fmaxf(m, __shfl_xor(m, o, 64));
  if (lane == 0) { RM[n] = m; SC[n] = m / 16129.f; }
}

__global__ void packi0_k(const float* __restrict__ Wih0, const float* __restrict__ Whh0,
                         const float* __restrict__ RM, signed char* __restrict__ Bp)
{
  const int t = blockIdx.x * blockDim.x + threadIdx.x;
  if (t >= GN * K0P) return;
  const int n = t / K0P, k = t % K0P;
  const int row = fused_row(n);
  float v = 0.f;
  if (k < HIDDEN)                v = Whh0[(size_t)row * HIDDEN + k];
  else if (k < HIDDEN + CONDDIM) v = 4.f * Wih0[(size_t)row * INDIM + XDIM + (k - HIDDEN)];
  Bp[t] = qscale(v, 127.f / RM[n]);
}

__global__ void packi1_k(const float* __restrict__ Wih1, const float* __restrict__ Whh1,
                         const float* __restrict__ RM, signed char* __restrict__ Bp)
{
  const int t = blockIdx.x * blockDim.x + threadIdx.x;
  if (t >= GN * K1P) return;
  const int n = t >> 11, k = t & 2047;
  const int row = fused_row(n);
  const float v = (k < HIDDEN) ? Wih1[(size_t)row * HIDDEN + k]
                               : Whh1[(size_t)row * HIDDEN + (k - HIDDEN)];
  Bp[t] = qscale(v, 127.f / RM[n]);
}

__global__ void packbias_k(const float* __restrict__ bih, const float* __restrict__ bhh,
                           float* __restrict__ bc)
{
  const int n = blockIdx.x * blockDim.x + threadIdx.x;
  if (n >= GN) return;
  const int row = fused_row(n);
  bc[n] = bih[row] + bhh[row];
}

__global__ void rowmaxf_k(const float* __restrict__ Wf, float* __restrict__ RM,
                          float* __restrict__ SC)
{
  const int n = blockIdx.x, lane = threadIdx.x;
  float m = 1e-20f;
  if (n < XDIM)
    for (int k = lane; k < HIDDEN; k += 64) m = fmaxf(m, fabsf(Wf[(size_t)n * HIDDEN + k]));
  else m = 1.f;
  #pragma unroll
  for (int o = 32; o > 0; o >>= 1) m = fmaxf(m, __shfl_xor(m, o, 64));
  if (lane == 0) { RM[n] = m; SC[n] = m / 16129.f; }
}

__global__ void packfi_k(const float* __restrict__ Wf, const float* __restrict__ RM,
                         signed char* __restrict__ Wfi)
{
  const int t = blockIdx.x * blockDim.x + threadIdx.x;
  if (t >= LGN * HIDDEN) return;
  const int r = t >> 10, k = t & 1023;
  const float v = (r < XDIM) ? Wf[(size_t)r * HIDDEN + k] : 0.f;
  Wfi[t] = qscale(v, 127.f / RM[r]);
}

__global__ void packt_k(const float* __restrict__ Wih0, float* __restrict__ W0T)
{
  const int t = blockIdx.x * blockDim.x + threadIdx.x;
  if (t >= XDIM * GN) return;
  const int e = t >> 12, n = t & 4095;
  W0T[t] = Wih0[(size_t)fused_row(n) * INDIM + e];
}

// ---------------------------------------------------------------- launch
extern "C" void kernel_launch(void* const* d_in, const int* in_sizes, int n_in,
                              void* d_out, int out_size, void* d_ws, size_t ws_size,
                              hipStream_t stream)
{
  const float* z    = (const float*)d_in[0];
  const float* x    = (const float*)d_in[1];
  const float* Wih0 = (const float*)d_in[2];
  const float* Whh0 = (const float*)d_in[3];
  const float* bih0 = (const float*)d_in[4];
  const float* bhh0 = (const float*)d_in[5];
  const float* Wih1 = (const float*)d_in[6];
  const float* Whh1 = (const float*)d_in[7];
  const float* bih1 = (const float*)d_in[8];
  const float* bhh1 = (const float*)d_in[9];
  const float* Wf   = (const float*)d_in[10];
  const float* bfv  = (const float*)d_in[11];
  float* out = (float*)d_out;

  char* ws = (char*)d_ws;
  size_t off = 0;
  auto alloc = [&](size_t bytes) { void* p = ws + off; off += (bytes + 255) & ~(size_t)255; return p; };

  float*       LG   = (float*)      alloc((size_t)BP * LGN * 4);
  signed char* H0a  = (signed char*)alloc((size_t)BP * 1024);
  signed char* H0b  = (signed char*)alloc((size_t)BP * 1024);
  signed char* H0s1 = (signed char*)alloc((size_t)BP * 1024);   // h0'_0 @ s1 (t=0 only)
  signed char* H1a  = (signed char*)alloc((size_t)BP * 1024);
  signed char* H1b  = (signed char*)alloc((size_t)BP * 1024);
  signed char* Y    = (signed char*)alloc((size_t)BP * 64);
  signed char* Bpi0 = (signed char*)alloc((size_t)GN * K0P);
  signed char* Bpi1 = (signed char*)alloc((size_t)GN * K1P);
  signed char* Wfi  = (signed char*)alloc((size_t)LGN * HIDDEN);
  float*       W0T  = (float*)      alloc((size_t)XDIM * GN * 4);
  float*       bc0  = (float*)      alloc((size_t)GN * 4);
  float*       bc1  = (float*)      alloc((size_t)GN * 4);
  float*       RM0  = (float*)      alloc((size_t)GN * 4);
  float*       SC0  = (float*)      alloc((size_t)GN * 4);
  float*       RM1  = (float*)      alloc((size_t)GN * 4);
  float*       SC1  = (float*)      alloc((size_t)GN * 4);
  float*       RMf  = (float*)      alloc((size_t)LGN * 4);
  float*       SCf  = (float*)      alloc((size_t)LGN * 4);
  float*       S0   = (float*)      alloc((size_t)BP * 4);
  float*       S1   = (float*)      alloc((size_t)BP * 4);
  float*       c0T  = (float*)      alloc((size_t)BP * HIDDEN * 4);
  float*       c1T  = (float*)      alloc((size_t)BP * HIDDEN * 4);
  int*         idx  = (int*)        alloc((size_t)BP * 4);
  (void)ws_size; (void)in_sizes; (void)n_in; (void)out_size;

  rowmax0_k<<<GN, 64, 0, stream>>>(Wih0, Whh0, RM0, SC0);
  rowmax1_k<<<GN, 64, 0, stream>>>(Wih1, Whh1, RM1, SC1);
  rowmaxf_k<<<LGN, 64, 0, stream>>>(Wf, RMf, SCf);
  packi0_k<<<(GN * K0P + 255) / 256, 256, 0, stream>>>(Wih0, Whh0, RM0, Bpi0);
  packi1_k<<<(GN * K1P + 255) / 256, 256, 0, stream>>>(Wih1, Whh1, RM1, Bpi1);
  packfi_k<<<(LGN * HIDDEN + 255) / 256, 256, 0, stream>>>(Wf, RMf, Wfi);
  packbias_k<<<(GN + 255) / 256, 256, 0, stream>>>(bih0, bhh0, bc0);
  packbias_k<<<(GN + 255) / 256, 256, 0, stream>>>(bih1, bhh1, bc1);
  packt_k<<<(XDIM * GN + 255) / 256, 256, 0, stream>>>(Wih0, W0T);
  // initq: z@s0 -> H0b (= H0prev at t=0), z@s1 -> H1b (= H1prev at t=0)
  initq_k<<<BP, 64, 0, stream>>>(z, x, c0T, c1T, H0b, H1b, Y, S0, S1, idx);

  for (int t = 0; t < NSTEP; ++t) {
    signed char* H0cur  = (t & 1) ? H0b : H0a;
    signed char* H0prev = (t & 1) ? H0a : H0b;
    signed char* H1cur  = (t & 1) ? H1b : H1a;
    signed char* H1prev = (t & 1) ? H1a : H1b;

    // layer 0: A = [h0_{t-1} | y_t], fused cell -> h0' (written once, scale 1)
    gemm_i8_cell_k<true><<<512, 512, 0, stream>>>(
        H0prev, Y, 64, Bpi0, K0P, bc0, SC0,
        (t == 0) ? S0 : nullptr, W0T, idx, c0T,
        H0cur,
        (t == 0) ? H0s1 : nullptr, S1);     // extra s1-scaled copy at t=0 only
    // layer 1: A = [h0'_t | h1_{t-1}], fused cell -> h1'
    gemm_i8_cell_k<false><<<512, 512, 0, stream>>>(
        (t == 0) ? H0s1 : H0cur, H1prev, 1024, Bpi1, K1P, bc1, SC1,
        (t == 0) ? S1 : nullptr, nullptr, nullptr, c1T,
        H1cur, nullptr, nullptr);
    // logits from int8 h1' (scale 1/127)
    logits_i8_k<<<dim3(LGN / 128, BP / 64), dim3(256), 0, stream>>>(
        H1cur, 1024, Wfi, SCf, LG, LGN);
    smax_k<<<BP, 64, 0, stream>>>(LG, bfv, out, t, x, Y, idx);
  }
}

// Round 18
// 1564.568 us; speedup vs baseline: 1.2461x; 1.0097x over previous
//
#include <hip/hip_runtime.h>
#include <hip/hip_bf16.h>

#define HIDDEN   1024
#define XDIM     130
#define CONDDIM  44
#define INDIM    174      // XDIM + CONDDIM
#define NSTEP    16
#define BP       4096     // effective batch (64*64)
#define K0P      1088     // 1024 (h) + 64 (y pad) ; i8: 17 tiles of 64
#define K1P      2048     // 1024 + 1024           ; i8: 32 tiles of 64
#define GN       4096     // 4*HIDDEN gate dim
#define LGN      256      // padded logits cols (130 -> 256)
#define SPLITK   16       // A-tiles < SPLITK from Alo (stride 1024), else Ahi

typedef float f32x4 __attribute__((ext_vector_type(4)));
typedef int   i32x4 __attribute__((ext_vector_type(4)));

// fused gate column order: n in [0,4096) -> q=(n>>4)&3 (gate), j=((n>>6)<<4)|(n&15)
__device__ __forceinline__ int fused_row(int n) {
  const int q = (n >> 4) & 3;
  const int j = ((n >> 6) << 4) | (n & 15);
  return q * HIDDEN + j;
}

__device__ __forceinline__ void g2lds16(const void* g, void* l) {
  __builtin_amdgcn_global_load_lds(
      (const __attribute__((address_space(1))) void*)g,
      (__attribute__((address_space(3))) void*)l, 16, 0, 0);
}

__device__ __forceinline__ float sigm(float x)  { return 1.f / (1.f + __expf(-x)); }
__device__ __forceinline__ float tanhfast(float x) { return 2.f / (1.f + __expf(-2.f * x)) - 1.f; }

__device__ __forceinline__ signed char qscale(float v, float inv127s) {
  int q = __float2int_rn(v * inv127s);
  q = q > 127 ? 127 : (q < -127 ? -127 : q);
  return (signed char)q;
}

// ================================================================ int8 gate GEMM + fused LSTM cell
// R18: K-loop pipe-overlap surgery. R17 PMC showed per-tile ~3750 cyc vs
// ~1500 floor, with VALUBusy 40% (per-tile address recompute) and a mid-tile
// lgkmcnt(0)+barrier serializing LDS/VALU/MFMA pipes.
//  (1) staging source bases hoisted; per tile just base + t*64.
//  (2) 3 LDS buffers (72 KB), 2-ahead prefetch, ONE barrier per tile:
//      stage(t+2) targets buf (t-1)%3 whose readers drained before the
//      end-of-(t-1) barrier (their MFMAs consumed the ds_reads first), so the
//      lgkmcnt(0)+barrier pair is deleted; compiler emits fine-grained lgkm
//      waits for ds_read->MFMA. vmcnt(3) at tile bottom = stage(t+2) in flight.
// Geometry unchanged from R17: 256m x 128n, 8 waves (4m x 2n), 2 blocks/CU.
template<bool FB>
__global__ __launch_bounds__(512, 4)
void gemm_i8_cell_k(const signed char* __restrict__ Alo,   // stride 1024
                    const signed char* __restrict__ Ahi, int ahstr,
                    const signed char* __restrict__ W, int K,
                    const float* __restrict__ bcomb,
                    const float* __restrict__ SC,        // Rmax/127^2, fused order
                    const float* __restrict__ sA,        // per-row A scale (or null)
                    const float* __restrict__ W0T,       // 130 x 4096 fused (FB only)
                    const int*   __restrict__ idx,       // feedback index (FB only)
                    float* __restrict__ cT,              // tiled: [j>>5][b][j&31] fp32
                    signed char* __restrict__ d1,        // stride 1024, scale 1
                    signed char* __restrict__ d2,        // stride 1024, scale sD2 (or null)
                    const float* __restrict__ sD2)
{
  __shared__ __align__(16) signed char lds[3 * 24576];   // 3 buf x (A 16KB + B 8KB)

  const int tid  = threadIdx.x;
  const int w    = tid >> 6;        // wave 0..7
  const int lane = tid & 63;
  const int bid  = blockIdx.x;      // 512 blocks (16 m-tiles x 32 n-tiles)
  // XCD swizzle: each XCD owns an 8m x 8n rectangle, m-major inside
  const int xcd  = bid & 7;
  const int rr   = bid >> 3;        // 0..63
  const int mt   = (xcd & 1) * 8 + (rr & 7);
  const int nt   = (xcd >> 1) * 8 + (rr >> 3);
  const int m0   = mt * 256;
  const int n0   = nt * 128;
  const int wm   = w >> 1;          // 0..3 : 64-row quarter
  const int wn   = w & 1;           // 0..1 : 64-col half
  const int fr   = lane & 15;
  const int kqs  = (((lane >> 4) ^ ((fr >> 1) & 3)) * 16);   // swizzled 16B chunk
  const int sr   = lane >> 2;
  const int sc   = (((lane & 3) ^ ((sr >> 1) & 3)) * 16);    // pre-XORed source chunk
  const int NT   = K >> 6;          // K-tiles of 64 int8 (64 B rows)

  const int fq = lane >> 4;
  const int cb = n0 + wn * 64;
  const int j  = ((cb >> 6) << 4) | fr;

  i32x4 acc[4][4] = {};

  // hoisted staging source bases (per-lane pre-swizzled chunk folded in)
  const signed char* aLo0 = Alo + (size_t)(m0 + w * 32 +      sr) * 1024  + sc;
  const signed char* aLo1 = Alo + (size_t)(m0 + w * 32 + 16 + sr) * 1024  + sc;
  const signed char* aHi0 = Ahi + (size_t)(m0 + w * 32 +      sr) * ahstr + sc;
  const signed char* aHi1 = Ahi + (size_t)(m0 + w * 32 + 16 + sr) * ahstr + sc;
  const signed char* bB   = W   + (size_t)(n0 + w * 16 +      sr) * K     + sc;

  auto stage = [&](int t, int buf) {
    signed char* dA = lds + buf * 24576 + (w * 32) * 64;
    signed char* dB = lds + buf * 24576 + 16384 + (w * 16) * 64;
    const bool lo = t < SPLITK;
    const signed char* s0 = lo ? aLo0 : aHi0;
    const signed char* s1 = lo ? aLo1 : aHi1;
    const int ko = (lo ? t : t - SPLITK) * 64;
    g2lds16(s0 + ko, dA);
    g2lds16(s1 + ko, dA + 1024);
    g2lds16(bB + t * 64, dB);
  };

  // prologue: tiles 0,1 into bufs 0,1; wait tile 0 (tile 1's 3 ops in flight)
  stage(0, 0);
  stage(1, 1);
  asm volatile("s_waitcnt vmcnt(3)" ::: "memory");
  __builtin_amdgcn_s_barrier();

  int bcur = 0, bnx2 = 2;
  for (int t = 0; t < NT; ++t) {
    const signed char* As = lds + bcur * 24576;
    const signed char* Bs = As + 16384;

    if (t + 2 < NT) stage(t + 2, bnx2);   // issue early; buf (t-1)%3 is drained

    i32x4 afr[4], bfr[4];
    #pragma unroll
    for (int q = 0; q < 4; ++q)
      afr[q] = *reinterpret_cast<const i32x4*>(&As[(wm * 64 + q * 16 + fr) * 64 + kqs]);
    #pragma unroll
    for (int nf = 0; nf < 4; ++nf)
      bfr[nf] = *reinterpret_cast<const i32x4*>(&Bs[(wn * 64 + nf * 16 + fr) * 64 + kqs]);

    __builtin_amdgcn_s_setprio(1);
    #pragma unroll
    for (int q = 0; q < 4; ++q)
      #pragma unroll
      for (int nf = 0; nf < 4; ++nf)
        acc[q][nf] = __builtin_amdgcn_mfma_i32_16x16x64_i8(afr[q], bfr[nf], acc[q][nf], 0, 0, 0);
    __builtin_amdgcn_s_setprio(0);

    if (t + 1 < NT) {
      if (t + 2 < NT) asm volatile("s_waitcnt vmcnt(3)" ::: "memory");  // t+1 landed
      else            asm volatile("s_waitcnt vmcnt(0)" ::: "memory");
      __builtin_amdgcn_s_barrier();
    }
    bcur = (bcur == 2) ? 0 : bcur + 1;
    bnx2 = (bnx2 == 2) ? 0 : bnx2 + 1;
  }

  // ---- fused LSTM cell epilogue ----
  const float bs0 = bcomb[cb + fr],      sc0 = SC[cb + fr];
  const float bs1 = bcomb[cb + 16 + fr], sc1 = SC[cb + 16 + fr];
  const float bs2 = bcomb[cb + 32 + fr], sc2 = SC[cb + 32 + fr];
  const float bs3 = bcomb[cb + 48 + fr], sc3 = SC[cb + 48 + fr];
  const size_t ctbase = (size_t)(j >> 5) * ((size_t)BP * 32) + (j & 31);

  #pragma unroll
  for (int mf = 0; mf < 4; ++mf) {
    #pragma unroll
    for (int r = 0; r < 4; ++r) {
      const int b = m0 + wm * 64 + mf * 16 + fq * 4 + r;
      const float sa = sA ? sA[b] : 1.f;
      float gi = (float)acc[mf][0][r] * (sc0 * sa) + bs0;
      float gf = (float)acc[mf][1][r] * (sc1 * sa) + bs1;
      float gg = (float)acc[mf][2][r] * (sc2 * sa) + bs2;
      float go = (float)acc[mf][3][r] * (sc3 * sa) + bs3;
      if (FB) {
        const float* wr = W0T + (size_t)idx[b] * GN;
        gi += wr[cb + fr];
        gf += wr[cb + 16 + fr];
        gg += wr[cb + 32 + fr];
        go += wr[cb + 48 + fr];
      }
      const size_t ci = ctbase + (size_t)b * 32;
      const float cn = sigm(gf) * cT[ci] + sigm(gi) * tanhfast(gg);
      cT[ci] = cn;
      const float hn = sigm(go) * tanhfast(cn);
      d1[(size_t)b * 1024 + j] = qscale(hn, 127.f);
      if (d2) d2[(size_t)b * 1024 + j] = qscale(hn, 127.f / sD2[b]);
    }
  }
}

// ---------------------------------------------------------------- int8 logits GEMM (64x128 tile, 128 blocks)
__global__ __launch_bounds__(256, 4)
void logits_i8_k(const signed char* __restrict__ A, int lda,   // h1' rows (stride 1024)
                 const signed char* __restrict__ Wfi,          // [256][1024] int8
                 const float* __restrict__ SCf,                // RMf/127^2
                 float* __restrict__ C, int ldc)
{
  __shared__ __align__(16) signed char As[64 * 64];    // 4 KB
  __shared__ __align__(16) signed char Bs[128 * 64];   // 8 KB

  const int tid  = threadIdx.x;
  const int w    = tid >> 6;
  const int lane = tid & 63;
  const int m0 = blockIdx.y * 64;
  const int n0 = blockIdx.x * 128;
  const int wm = w >> 1;
  const int wn = w & 1;
  const int fr = lane & 15;
  const int kqs = (((lane >> 4) ^ ((fr >> 1) & 3)) * 16);
  const int sr  = lane >> 2;
  const int sc  = (((lane & 3) ^ ((sr >> 1) & 3)) * 16);

  i32x4 acc[2][4] = {};

  for (int k0 = 0; k0 < HIDDEN; k0 += 64) {
    __syncthreads();
    g2lds16(A + (size_t)(m0 + w * 16 + sr) * lda + (k0 + sc), (void*)(As + (w * 16) * 64));
    g2lds16(Wfi + (size_t)(n0 + w * 16 + sr) * HIDDEN + (k0 + sc), (void*)(Bs + (w * 16) * 64));
    g2lds16(Wfi + (size_t)(n0 + 64 + w * 16 + sr) * HIDDEN + (k0 + sc), (void*)(Bs + (64 + w * 16) * 64));
    __syncthreads();

    i32x4 af[2], bw[4];
    #pragma unroll
    for (int i = 0; i < 2; ++i)
      af[i] = *reinterpret_cast<const i32x4*>(&As[(wm * 32 + i * 16 + fr) * 64 + kqs]);
    #pragma unroll
    for (int jn = 0; jn < 4; ++jn)
      bw[jn] = *reinterpret_cast<const i32x4*>(&Bs[(wn * 64 + jn * 16 + fr) * 64 + kqs]);
    #pragma unroll
    for (int i = 0; i < 2; ++i)
      #pragma unroll
      for (int jn = 0; jn < 4; ++jn)
        acc[i][jn] = __builtin_amdgcn_mfma_i32_16x16x64_i8(af[i], bw[jn], acc[i][jn], 0, 0, 0);
  }

  const int fq = lane >> 4;
  #pragma unroll
  for (int i = 0; i < 2; ++i)
    #pragma unroll
    for (int jn = 0; jn < 4; ++jn) {
      const int col = n0 + wn * 64 + jn * 16 + fr;
      const float scf = SCf[col];
      #pragma unroll
      for (int r = 0; r < 4; ++r) {
        const int row = m0 + wm * 32 + i * 16 + fq * 4 + r;
        C[(size_t)row * ldc + col] = (float)acc[i][jn][r] * scf;
      }
    }
}

// ---------------------------------------------------------------- log_softmax + argmax + y staging
__global__ void smax_k(const float* __restrict__ LG,
                       const float* __restrict__ bfv,
                       float* __restrict__ out, int t,
                       const float* __restrict__ x,
                       signed char* __restrict__ Y,      // [BP][64], y/4 at scale 1
                       int* __restrict__ idx)
{
  const int b    = blockIdx.x;
  const int lane = threadIdx.x;   // 64
  const float NINF = -__builtin_inff();
  const float* lg = LG + (size_t)b * LGN;

  const int c1 = lane + 64, c2 = lane + 128;
  float v0 = lg[lane] + bfv[lane];
  float v1 = lg[c1] + bfv[c1];
  float v2 = (c2 < XDIM) ? lg[c2] + bfv[c2] : NINF;

  float m = fmaxf(v0, fmaxf(v1, v2));
  #pragma unroll
  for (int o = 32; o > 0; o >>= 1) m = fmaxf(m, __shfl_xor(m, o, 64));

  int bi = 0x7fffffff;
  if (v0 == m) bi = lane;
  if (v1 == m) bi = min(bi, c1);
  if (v2 == m) bi = min(bi, c2);
  #pragma unroll
  for (int o = 32; o > 0; o >>= 1) bi = min(bi, __shfl_xor(bi, o, 64));

  float s = __expf(v0 - m) + __expf(v1 - m) + ((c2 < XDIM) ? __expf(v2 - m) : 0.f);
  #pragma unroll
  for (int o = 32; o > 0; o >>= 1) s += __shfl_xor(s, o, 64);
  const float lse = __logf(s);

  float* orow = out + ((size_t)b * NSTEP + t) * XDIM;
  orow[lane] = v0 - m - lse;
  orow[c1]   = v1 - m - lse;
  if (c2 < XDIM) orow[c2] = v2 - m - lse;
  if (lane == 0) idx[b] = bi;

  if (t + 1 < NSTEP) {
    const float yv = (lane < CONDDIM)
        ? x[((size_t)b * NSTEP + (t + 1)) * INDIM + XDIM + lane] : 0.f;
    Y[(size_t)b * 64 + lane] = qscale(yv * 0.25f, 127.f);
  }
}

// ---------------------------------------------------------------- init: per-row scales + quantized z + zero c
__global__ void initq_k(const float* __restrict__ z, const float* __restrict__ x,
                        float* __restrict__ c0T, float* __restrict__ c1T,
                        signed char* __restrict__ Hz0,   // z @ s0, stride 1024
                        signed char* __restrict__ Hz1,   // z @ s1, stride 1024
                        signed char* __restrict__ Y,
                        float* __restrict__ S0, float* __restrict__ S1,
                        int* __restrict__ idx)
{
  const int b    = blockIdx.x;
  const int lane = threadIdx.x;   // 64
  const float* zr = z + (size_t)b * HIDDEN;

  float mz = 0.f;
  for (int k = lane; k < HIDDEN; k += 64) mz = fmaxf(mz, fabsf(zr[k]));
  #pragma unroll
  for (int o = 32; o > 0; o >>= 1) mz = fmaxf(mz, __shfl_xor(mz, o, 64));

  const float yv = (lane < CONDDIM) ? x[((size_t)b * NSTEP) * INDIM + XDIM + lane] : 0.f;
  float my = fabsf(yv) * 0.25f;
  #pragma unroll
  for (int o = 32; o > 0; o >>= 1) my = fmaxf(my, __shfl_xor(my, o, 64));

  const float s0 = fmaxf(fmaxf(mz, my), 1e-6f);
  const float s1 = fmaxf(mz, 1.f);
  const float i0 = 127.f / s0;
  const float i1 = 127.f / s1;

  for (int k = lane; k < HIDDEN; k += 64) {
    const float zv = zr[k];
    Hz0[(size_t)b * 1024 + k] = qscale(zv, i0);
    Hz1[(size_t)b * 1024 + k] = qscale(zv, i1);
    const size_t ci = (size_t)(k >> 5) * ((size_t)BP * 32) + (size_t)b * 32 + (k & 31);
    c0T[ci] = 0.f;
    c1T[ci] = 0.f;
  }
  Y[(size_t)b * 64 + lane] = qscale(yv * 0.25f, i0);   // y_0 @ s0 (+ zero pad)
  if (lane == 0) { S0[b] = s0; S1[b] = s1; idx[b] = 1; }
}

// ---------------------------------------------------------------- weight packing
__global__ void rowmax0_k(const float* __restrict__ Wih0, const float* __restrict__ Whh0,
                          float* __restrict__ RM, float* __restrict__ SC)
{
  const int n = blockIdx.x, lane = threadIdx.x;
  const int row = fused_row(n);
  float m = 1e-20f;
  for (int k = lane; k < HIDDEN; k += 64)  m = fmaxf(m, fabsf(Whh0[(size_t)row * HIDDEN + k]));
  for (int k = lane; k < CONDDIM; k += 64) m = fmaxf(m, 4.f * fabsf(Wih0[(size_t)row * INDIM + XDIM + k]));
  #pragma unroll
  for (int o = 32; o > 0; o >>= 1) m = fmaxf(m, __shfl_xor(m, o, 64));
  if (lane == 0) { RM[n] = m; SC[n] = m / 16129.f; }
}

__global__ void rowmax1_k(const float* __restrict__ Wih1, const float* __restrict__ Whh1,
                          float* __restrict__ RM, float* __restrict__ SC)
{
  const int n = blockIdx.x, lane = threadIdx.x;
  const int row = fused_row(n);
  float m = 1e-20f;
  for (int k = lane; k < HIDDEN; k += 64) {
    m = fmaxf(m, fabsf(Wih1[(size_t)row * HIDDEN + k]));
    m = fmaxf(m, fabsf(Whh1[(size_t)row * HIDDEN + k]));
  }
  #pragma unroll
  for (int o = 32; o > 0; o >>= 1) m = fmaxf(m, __shfl_xor(m, o, 64));
  if (lane == 0) { RM[n] = m; SC[n] = m / 16129.f; }
}

__global__ void packi0_k(const float* __restrict__ Wih0, const float* __restrict__ Whh0,
                         const float* __restrict__ RM, signed char* __restrict__ Bp)
{
  const int t = blockIdx.x * blockDim.x + threadIdx.x;
  if (t >= GN * K0P) return;
  const int n = t / K0P, k = t % K0P;
  const int row = fused_row(n);
  float v = 0.f;
  if (k < HIDDEN)                v = Whh0[(size_t)row * HIDDEN + k];
  else if (k < HIDDEN + CONDDIM) v = 4.f * Wih0[(size_t)row * INDIM + XDIM + (k - HIDDEN)];
  Bp[t] = qscale(v, 127.f / RM[n]);
}

__global__ void packi1_k(const float* __restrict__ Wih1, const float* __restrict__ Whh1,
                         const float* __restrict__ RM, signed char* __restrict__ Bp)
{
  const int t = blockIdx.x * blockDim.x + threadIdx.x;
  if (t >= GN * K1P) return;
  const int n = t >> 11, k = t & 2047;
  const int row = fused_row(n);
  const float v = (k < HIDDEN) ? Wih1[(size_t)row * HIDDEN + k]
                               : Whh1[(size_t)row * HIDDEN + (k - HIDDEN)];
  Bp[t] = qscale(v, 127.f / RM[n]);
}

__global__ void packbias_k(const float* __restrict__ bih, const float* __restrict__ bhh,
                           float* __restrict__ bc)
{
  const int n = blockIdx.x * blockDim.x + threadIdx.x;
  if (n >= GN) return;
  const int row = fused_row(n);
  bc[n] = bih[row] + bhh[row];
}

__global__ void rowmaxf_k(const float* __restrict__ Wf, float* __restrict__ RM,
                          float* __restrict__ SC)
{
  const int n = blockIdx.x, lane = threadIdx.x;
  float m = 1e-20f;
  if (n < XDIM)
    for (int k = lane; k < HIDDEN; k += 64) m = fmaxf(m, fabsf(Wf[(size_t)n * HIDDEN + k]));
  else m = 1.f;
  #pragma unroll
  for (int o = 32; o > 0; o >>= 1) m = fmaxf(m, __shfl_xor(m, o, 64));
  if (lane == 0) { RM[n] = m; SC[n] = m / 16129.f; }
}

__global__ void packfi_k(const float* __restrict__ Wf, const float* __restrict__ RM,
                         signed char* __restrict__ Wfi)
{
  const int t = blockIdx.x * blockDim.x + threadIdx.x;
  if (t >= LGN * HIDDEN) return;
  const int r = t >> 10, k = t & 1023;
  const float v = (r < XDIM) ? Wf[(size_t)r * HIDDEN + k] : 0.f;
  Wfi[t] = qscale(v, 127.f / RM[r]);
}

__global__ void packt_k(const float* __restrict__ Wih0, float* __restrict__ W0T)
{
  const int t = blockIdx.x * blockDim.x + threadIdx.x;
  if (t >= XDIM * GN) return;
  const int e = t >> 12, n = t & 4095;
  W0T[t] = Wih0[(size_t)fused_row(n) * INDIM + e];
}

// ---------------------------------------------------------------- launch
extern "C" void kernel_launch(void* const* d_in, const int* in_sizes, int n_in,
                              void* d_out, int out_size, void* d_ws, size_t ws_size,
                              hipStream_t stream)
{
  const float* z    = (const float*)d_in[0];
  const float* x    = (const float*)d_in[1];
  const float* Wih0 = (const float*)d_in[2];
  const float* Whh0 = (const float*)d_in[3];
  const float* bih0 = (const float*)d_in[4];
  const float* bhh0 = (const float*)d_in[5];
  const float* Wih1 = (const float*)d_in[6];
  const float* Whh1 = (const float*)d_in[7];
  const float* bih1 = (const float*)d_in[8];
  const float* bhh1 = (const float*)d_in[9];
  const float* Wf   = (const float*)d_in[10];
  const float* bfv  = (const float*)d_in[11];
  float* out = (float*)d_out;

  char* ws = (char*)d_ws;
  size_t off = 0;
  auto alloc = [&](size_t bytes) { void* p = ws + off; off += (bytes + 255) & ~(size_t)255; return p; };

  float*       LG   = (float*)      alloc((size_t)BP * LGN * 4);
  signed char* H0a  = (signed char*)alloc((size_t)BP * 1024);
  signed char* H0b  = (signed char*)alloc((size_t)BP * 1024);
  signed char* H0s1 = (signed char*)alloc((size_t)BP * 1024);   // h0'_0 @ s1 (t=0 only)
  signed char* H1a  = (signed char*)alloc((size_t)BP * 1024);
  signed char* H1b  = (signed char*)alloc((size_t)BP * 1024);
  signed char* Y    = (signed char*)alloc((size_t)BP * 64);
  signed char* Bpi0 = (signed char*)alloc((size_t)GN * K0P);
  signed char* Bpi1 = (signed char*)alloc((size_t)GN * K1P);
  signed char* Wfi  = (signed char*)alloc((size_t)LGN * HIDDEN);
  float*       W0T  = (float*)      alloc((size_t)XDIM * GN * 4);
  float*       bc0  = (float*)      alloc((size_t)GN * 4);
  float*       bc1  = (float*)      alloc((size_t)GN * 4);
  float*       RM0  = (float*)      alloc((size_t)GN * 4);
  float*       SC0  = (float*)      alloc((size_t)GN * 4);
  float*       RM1  = (float*)      alloc((size_t)GN * 4);
  float*       SC1  = (float*)      alloc((size_t)GN * 4);
  float*       RMf  = (float*)      alloc((size_t)LGN * 4);
  float*       SCf  = (float*)      alloc((size_t)LGN * 4);
  float*       S0   = (float*)      alloc((size_t)BP * 4);
  float*       S1   = (float*)      alloc((size_t)BP * 4);
  float*       c0T  = (float*)      alloc((size_t)BP * HIDDEN * 4);
  float*       c1T  = (float*)      alloc((size_t)BP * HIDDEN * 4);
  int*         idx  = (int*)        alloc((size_t)BP * 4);
  (void)ws_size; (void)in_sizes; (void)n_in; (void)out_size;

  rowmax0_k<<<GN, 64, 0, stream>>>(Wih0, Whh0, RM0, SC0);
  rowmax1_k<<<GN, 64, 0, stream>>>(Wih1, Whh1, RM1, SC1);
  rowmaxf_k<<<LGN, 64, 0, stream>>>(Wf, RMf, SCf);
  packi0_k<<<(GN * K0P + 255) / 256, 256, 0, stream>>>(Wih0, Whh0, RM0, Bpi0);
  packi1_k<<<(GN * K1P + 255) / 256, 256, 0, stream>>>(Wih1, Whh1, RM1, Bpi1);
  packfi_k<<<(LGN * HIDDEN + 255) / 256, 256, 0, stream>>>(Wf, RMf, Wfi);
  packbias_k<<<(GN + 255) / 256, 256, 0, stream>>>(bih0, bhh0, bc0);
  packbias_k<<<(GN + 255) / 256, 256, 0, stream>>>(bih1, bhh1, bc1);
  packt_k<<<(XDIM * GN + 255) / 256, 256, 0, stream>>>(Wih0, W0T);
  // initq: z@s0 -> H0b (= H0prev at t=0), z@s1 -> H1b (= H1prev at t=0)
  initq_k<<<BP, 64, 0, stream>>>(z, x, c0T, c1T, H0b, H1b, Y, S0, S1, idx);

  for (int t = 0; t < NSTEP; ++t) {
    signed char* H0cur  = (t & 1) ? H0b : H0a;
    signed char* H0prev = (t & 1) ? H0a : H0b;
    signed char* H1cur  = (t & 1) ? H1b : H1a;
    signed char* H1prev = (t & 1) ? H1a : H1b;

    // layer 0: A = [h0_{t-1} | y_t], fused cell -> h0' (written once, scale 1)
    gemm_i8_cell_k<true><<<512, 512, 0, stream>>>(
        H0prev, Y, 64, Bpi0, K0P, bc0, SC0,
        (t == 0) ? S0 : nullptr, W0T, idx, c0T,
        H0cur,
        (t == 0) ? H0s1 : nullptr, S1);     // extra s1-scaled copy at t=0 only
    // layer 1: A = [h0'_t | h1_{t-1}], fused cell -> h1'
    gemm_i8_cell_k<false><<<512, 512, 0, stream>>>(
        (t == 0) ? H0s1 : H0cur, H1prev, 1024, Bpi1, K1P, bc1, SC1,
        (t == 0) ? S1 : nullptr, nullptr, nullptr, c1T,
        H1cur, nullptr, nullptr);
    // logits from int8 h1' (scale 1/127)
    logits_i8_k<<<dim3(LGN / 128, BP / 64), dim3(256), 0, stream>>>(
        H1cur, 1024, Wfi, SCf, LG, LGN);
    smax_k<<<BP, 64, 0, stream>>>(LG, bfv, out, t, x, Y, idx);
  }
}

// Round 19
// 1560.515 us; speedup vs baseline: 1.2494x; 1.0026x over previous
//
#include <hip/hip_runtime.h>
#include <hip/hip_bf16.h>

#define HIDDEN   1024
#define XDIM     130
#define CONDDIM  44
#define INDIM    174      // XDIM + CONDDIM
#define NSTEP    16
#define BP       4096     // effective batch (64*64)
#define K0P      1088     // 1024 (h) + 64 (y pad) ; i8: 17 tiles of 64
#define K1P      2048     // 1024 + 1024           ; i8: 32 tiles of 64
#define GN       4096     // 4*HIDDEN gate dim
#define LGN      256      // padded logits cols (130 -> 256)
#define SPLITK   16       // A-tiles < SPLITK from Alo (stride 1024), else Ahi

typedef float f32x4 __attribute__((ext_vector_type(4)));
typedef int   i32x4 __attribute__((ext_vector_type(4)));

// fused gate column order: n in [0,4096) -> q=(n>>4)&3 (gate), j=((n>>6)<<4)|(n&15)
__device__ __forceinline__ int fused_row(int n) {
  const int q = (n >> 4) & 3;
  const int j = ((n >> 6) << 4) | (n & 15);
  return q * HIDDEN + j;
}

__device__ __forceinline__ void g2lds16(const void* g, void* l) {
  __builtin_amdgcn_global_load_lds(
      (const __attribute__((address_space(1))) void*)g,
      (__attribute__((address_space(3))) void*)l, 16, 0, 0);
}

__device__ __forceinline__ float sigm(float x)  { return 1.f / (1.f + __expf(-x)); }
__device__ __forceinline__ float tanhfast(float x) { return 2.f / (1.f + __expf(-2.f * x)) - 1.f; }

__device__ __forceinline__ signed char qscale(float v, float inv127s) {
  int q = __float2int_rn(v * inv127s);
  q = q > 127 ? 127 : (q < -127 ? -127 : q);
  return (signed char)q;
}

// ================================================================ int8 gate GEMM + fused LSTM cell
// R18: K-loop pipe-overlap surgery. R17 PMC showed per-tile ~3750 cyc vs
// ~1500 floor, with VALUBusy 40% (per-tile address recompute) and a mid-tile
// lgkmcnt(0)+barrier serializing LDS/VALU/MFMA pipes.
//  (1) staging source bases hoisted; per tile just base + t*64.
//  (2) 3 LDS buffers (72 KB), 2-ahead prefetch, ONE barrier per tile:
//      stage(t+2) targets buf (t-1)%3 whose readers drained before the
//      end-of-(t-1) barrier (their MFMAs consumed the ds_reads first), so the
//      lgkmcnt(0)+barrier pair is deleted; compiler emits fine-grained lgkm
//      waits for ds_read->MFMA. vmcnt(3) at tile bottom = stage(t+2) in flight.
// Geometry unchanged from R17: 256m x 128n, 8 waves (4m x 2n), 2 blocks/CU.
template<bool FB>
__global__ __launch_bounds__(512, 4)
void gemm_i8_cell_k(const signed char* __restrict__ Alo,   // stride 1024
                    const signed char* __restrict__ Ahi, int ahstr,
                    const signed char* __restrict__ W, int K,
                    const float* __restrict__ bcomb,
                    const float* __restrict__ SC,        // Rmax/127^2, fused order
                    const float* __restrict__ sA,        // per-row A scale (or null)
                    const float* __restrict__ W0T,       // 130 x 4096 fused (FB only)
                    const int*   __restrict__ idx,       // feedback index (FB only)
                    float* __restrict__ cT,              // tiled: [j>>5][b][j&31] fp32
                    signed char* __restrict__ d1,        // stride 1024, scale 1
                    signed char* __restrict__ d2,        // stride 1024, scale sD2 (or null)
                    const float* __restrict__ sD2)
{
  __shared__ __align__(16) signed char lds[3 * 24576];   // 3 buf x (A 16KB + B 8KB)

  const int tid  = threadIdx.x;
  const int w    = tid >> 6;        // wave 0..7
  const int lane = tid & 63;
  const int bid  = blockIdx.x;      // 512 blocks (16 m-tiles x 32 n-tiles)
  // XCD swizzle: each XCD owns an 8m x 8n rectangle, m-major inside
  const int xcd  = bid & 7;
  const int rr   = bid >> 3;        // 0..63
  const int mt   = (xcd & 1) * 8 + (rr & 7);
  const int nt   = (xcd >> 1) * 8 + (rr >> 3);
  const int m0   = mt * 256;
  const int n0   = nt * 128;
  const int wm   = w >> 1;          // 0..3 : 64-row quarter
  const int wn   = w & 1;           // 0..1 : 64-col half
  const int fr   = lane & 15;
  const int kqs  = (((lane >> 4) ^ ((fr >> 1) & 3)) * 16);   // swizzled 16B chunk
  const int sr   = lane >> 2;
  const int sc   = (((lane & 3) ^ ((sr >> 1) & 3)) * 16);    // pre-XORed source chunk
  const int NT   = K >> 6;          // K-tiles of 64 int8 (64 B rows)

  const int fq = lane >> 4;
  const int cb = n0 + wn * 64;
  const int j  = ((cb >> 6) << 4) | fr;

  i32x4 acc[4][4] = {};

  // hoisted staging source bases (per-lane pre-swizzled chunk folded in)
  const signed char* aLo0 = Alo + (size_t)(m0 + w * 32 +      sr) * 1024  + sc;
  const signed char* aLo1 = Alo + (size_t)(m0 + w * 32 + 16 + sr) * 1024  + sc;
  const signed char* aHi0 = Ahi + (size_t)(m0 + w * 32 +      sr) * ahstr + sc;
  const signed char* aHi1 = Ahi + (size_t)(m0 + w * 32 + 16 + sr) * ahstr + sc;
  const signed char* bB   = W   + (size_t)(n0 + w * 16 +      sr) * K     + sc;

  auto stage = [&](int t, int buf) {
    signed char* dA = lds + buf * 24576 + (w * 32) * 64;
    signed char* dB = lds + buf * 24576 + 16384 + (w * 16) * 64;
    const bool lo = t < SPLITK;
    const signed char* s0 = lo ? aLo0 : aHi0;
    const signed char* s1 = lo ? aLo1 : aHi1;
    const int ko = (lo ? t : t - SPLITK) * 64;
    g2lds16(s0 + ko, dA);
    g2lds16(s1 + ko, dA + 1024);
    g2lds16(bB + t * 64, dB);
  };

  // prologue: tiles 0,1 into bufs 0,1; wait tile 0 (tile 1's 3 ops in flight)
  stage(0, 0);
  stage(1, 1);
  asm volatile("s_waitcnt vmcnt(3)" ::: "memory");
  __builtin_amdgcn_s_barrier();

  int bcur = 0, bnx2 = 2;
  for (int t = 0; t < NT; ++t) {
    const signed char* As = lds + bcur * 24576;
    const signed char* Bs = As + 16384;

    if (t + 2 < NT) stage(t + 2, bnx2);   // issue early; buf (t-1)%3 is drained

    i32x4 afr[4], bfr[4];
    #pragma unroll
    for (int q = 0; q < 4; ++q)
      afr[q] = *reinterpret_cast<const i32x4*>(&As[(wm * 64 + q * 16 + fr) * 64 + kqs]);
    #pragma unroll
    for (int nf = 0; nf < 4; ++nf)
      bfr[nf] = *reinterpret_cast<const i32x4*>(&Bs[(wn * 64 + nf * 16 + fr) * 64 + kqs]);

    __builtin_amdgcn_s_setprio(1);
    #pragma unroll
    for (int q = 0; q < 4; ++q)
      #pragma unroll
      for (int nf = 0; nf < 4; ++nf)
        acc[q][nf] = __builtin_amdgcn_mfma_i32_16x16x64_i8(afr[q], bfr[nf], acc[q][nf], 0, 0, 0);
    __builtin_amdgcn_s_setprio(0);

    if (t + 1 < NT) {
      if (t + 2 < NT) asm volatile("s_waitcnt vmcnt(3)" ::: "memory");  // t+1 landed
      else            asm volatile("s_waitcnt vmcnt(0)" ::: "memory");
      __builtin_amdgcn_s_barrier();
    }
    bcur = (bcur == 2) ? 0 : bcur + 1;
    bnx2 = (bnx2 == 2) ? 0 : bnx2 + 1;
  }

  // ---- fused LSTM cell epilogue ----
  const float bs0 = bcomb[cb + fr],      sc0 = SC[cb + fr];
  const float bs1 = bcomb[cb + 16 + fr], sc1 = SC[cb + 16 + fr];
  const float bs2 = bcomb[cb + 32 + fr], sc2 = SC[cb + 32 + fr];
  const float bs3 = bcomb[cb + 48 + fr], sc3 = SC[cb + 48 + fr];
  const size_t ctbase = (size_t)(j >> 5) * ((size_t)BP * 32) + (j & 31);

  #pragma unroll
  for (int mf = 0; mf < 4; ++mf) {
    #pragma unroll
    for (int r = 0; r < 4; ++r) {
      const int b = m0 + wm * 64 + mf * 16 + fq * 4 + r;
      const float sa = sA ? sA[b] : 1.f;
      float gi = (float)acc[mf][0][r] * (sc0 * sa) + bs0;
      float gf = (float)acc[mf][1][r] * (sc1 * sa) + bs1;
      float gg = (float)acc[mf][2][r] * (sc2 * sa) + bs2;
      float go = (float)acc[mf][3][r] * (sc3 * sa) + bs3;
      if (FB) {
        const float* wr = W0T + (size_t)idx[b] * GN;
        gi += wr[cb + fr];
        gf += wr[cb + 16 + fr];
        gg += wr[cb + 32 + fr];
        go += wr[cb + 48 + fr];
      }
      const size_t ci = ctbase + (size_t)b * 32;
      const float cn = sigm(gf) * cT[ci] + sigm(gi) * tanhfast(gg);
      cT[ci] = cn;
      const float hn = sigm(go) * tanhfast(cn);
      d1[(size_t)b * 1024 + j] = qscale(hn, 127.f);
      if (d2) d2[(size_t)b * 1024 + j] = qscale(hn, 127.f / sD2[b]);
    }
  }
}

// ---------------------------------------------------------------- int8 logits GEMM (64x128 tile, 128 blocks)
__global__ __launch_bounds__(256, 4)
void logits_i8_k(const signed char* __restrict__ A, int lda,   // h1' rows (stride 1024)
                 const signed char* __restrict__ Wfi,          // [256][1024] int8
                 const float* __restrict__ SCf,                // RMf/127^2
                 float* __restrict__ C, int ldc)
{
  __shared__ __align__(16) signed char As[64 * 64];    // 4 KB
  __shared__ __align__(16) signed char Bs[128 * 64];   // 8 KB

  const int tid  = threadIdx.x;
  const int w    = tid >> 6;
  const int lane = tid & 63;
  const int m0 = blockIdx.y * 64;
  const int n0 = blockIdx.x * 128;
  const int wm = w >> 1;
  const int wn = w & 1;
  const int fr = lane & 15;
  const int kqs = (((lane >> 4) ^ ((fr >> 1) & 3)) * 16);
  const int sr  = lane >> 2;
  const int sc  = (((lane & 3) ^ ((sr >> 1) & 3)) * 16);

  i32x4 acc[2][4] = {};

  for (int k0 = 0; k0 < HIDDEN; k0 += 64) {
    __syncthreads();
    g2lds16(A + (size_t)(m0 + w * 16 + sr) * lda + (k0 + sc), (void*)(As + (w * 16) * 64));
    g2lds16(Wfi + (size_t)(n0 + w * 16 + sr) * HIDDEN + (k0 + sc), (void*)(Bs + (w * 16) * 64));
    g2lds16(Wfi + (size_t)(n0 + 64 + w * 16 + sr) * HIDDEN + (k0 + sc), (void*)(Bs + (64 + w * 16) * 64));
    __syncthreads();

    i32x4 af[2], bw[4];
    #pragma unroll
    for (int i = 0; i < 2; ++i)
      af[i] = *reinterpret_cast<const i32x4*>(&As[(wm * 32 + i * 16 + fr) * 64 + kqs]);
    #pragma unroll
    for (int jn = 0; jn < 4; ++jn)
      bw[jn] = *reinterpret_cast<const i32x4*>(&Bs[(wn * 64 + jn * 16 + fr) * 64 + kqs]);
    #pragma unroll
    for (int i = 0; i < 2; ++i)
      #pragma unroll
      for (int jn = 0; jn < 4; ++jn)
        acc[i][jn] = __builtin_amdgcn_mfma_i32_16x16x64_i8(af[i], bw[jn], acc[i][jn], 0, 0, 0);
  }

  const int fq = lane >> 4;
  #pragma unroll
  for (int i = 0; i < 2; ++i)
    #pragma unroll
    for (int jn = 0; jn < 4; ++jn) {
      const int col = n0 + wn * 64 + jn * 16 + fr;
      const float scf = SCf[col];
      #pragma unroll
      for (int r = 0; r < 4; ++r) {
        const int row = m0 + wm * 32 + i * 16 + fq * 4 + r;
        C[(size_t)row * ldc + col] = (float)acc[i][jn][r] * scf;
      }
    }
}

// ---------------------------------------------------------------- log_softmax + argmax + y staging
__global__ void smax_k(const float* __restrict__ LG,
                       const float* __restrict__ bfv,
                       float* __restrict__ out, int t,
                       const float* __restrict__ x,
                       signed char* __restrict__ Y,      // [BP][64], y/4 at scale 1
                       int* __restrict__ idx)
{
  const int b    = blockIdx.x;
  const int lane = threadIdx.x;   // 64
  const float NINF = -__builtin_inff();
  const float* lg = LG + (size_t)b * LGN;

  const int c1 = lane + 64, c2 = lane + 128;
  float v0 = lg[lane] + bfv[lane];
  float v1 = lg[c1] + bfv[c1];
  float v2 = (c2 < XDIM) ? lg[c2] + bfv[c2] : NINF;

  float m = fmaxf(v0, fmaxf(v1, v2));
  #pragma unroll
  for (int o = 32; o > 0; o >>= 1) m = fmaxf(m, __shfl_xor(m, o, 64));

  int bi = 0x7fffffff;
  if (v0 == m) bi = lane;
  if (v1 == m) bi = min(bi, c1);
  if (v2 == m) bi = min(bi, c2);
  #pragma unroll
  for (int o = 32; o > 0; o >>= 1) bi = min(bi, __shfl_xor(bi, o, 64));

  float s = __expf(v0 - m) + __expf(v1 - m) + ((c2 < XDIM) ? __expf(v2 - m) : 0.f);
  #pragma unroll
  for (int o = 32; o > 0; o >>= 1) s += __shfl_xor(s, o, 64);
  const float lse = __logf(s);

  float* orow = out + ((size_t)b * NSTEP + t) * XDIM;
  orow[lane] = v0 - m - lse;
  orow[c1]   = v1 - m - lse;
  if (c2 < XDIM) orow[c2] = v2 - m - lse;
  if (lane == 0) idx[b] = bi;

  if (t + 1 < NSTEP) {
    const float yv = (lane < CONDDIM)
        ? x[((size_t)b * NSTEP + (t + 1)) * INDIM + XDIM + lane] : 0.f;
    Y[(size_t)b * 64 + lane] = qscale(yv * 0.25f, 127.f);
  }
}

// ---------------------------------------------------------------- init: per-row scales + quantized z + zero c
__global__ void initq_k(const float* __restrict__ z, const float* __restrict__ x,
                        float* __restrict__ c0T, float* __restrict__ c1T,
                        signed char* __restrict__ Hz0,   // z @ s0, stride 1024
                        signed char* __restrict__ Hz1,   // z @ s1, stride 1024
                        signed char* __restrict__ Y,
                        float* __restrict__ S0, float* __restrict__ S1,
                        int* __restrict__ idx)
{
  const int b    = blockIdx.x;
  const int lane = threadIdx.x;   // 64
  const float* zr = z + (size_t)b * HIDDEN;

  float mz = 0.f;
  for (int k = lane; k < HIDDEN; k += 64) mz = fmaxf(mz, fabsf(zr[k]));
  #pragma unroll
  for (int o = 32; o > 0; o >>= 1) mz = fmaxf(mz, __shfl_xor(mz, o, 64));

  const float yv = (lane < CONDDIM) ? x[((size_t)b * NSTEP) * INDIM + XDIM + lane] : 0.f;
  float my = fabsf(yv) * 0.25f;
  #pragma unroll
  for (int o = 32; o > 0; o >>= 1) my = fmaxf(my, __shfl_xor(my, o, 64));

  const float s0 = fmaxf(fmaxf(mz, my), 1e-6f);
  const float s1 = fmaxf(mz, 1.f);
  const float i0 = 127.f / s0;
  const float i1 = 127.f / s1;

  for (int k = lane; k < HIDDEN; k += 64) {
    const float zv = zr[k];
    Hz0[(size_t)b * 1024 + k] = qscale(zv, i0);
    Hz1[(size_t)b * 1024 + k] = qscale(zv, i1);
    const size_t ci = (size_t)(k >> 5) * ((size_t)BP * 32) + (size_t)b * 32 + (k & 31);
    c0T[ci] = 0.f;
    c1T[ci] = 0.f;
  }
  Y[(size_t)b * 64 + lane] = qscale(yv * 0.25f, i0);   // y_0 @ s0 (+ zero pad)
  if (lane == 0) { S0[b] = s0; S1[b] = s1; idx[b] = 1; }
}

// ---------------------------------------------------------------- weight packing
__global__ void rowmax0_k(const float* __restrict__ Wih0, const float* __restrict__ Whh0,
                          float* __restrict__ RM, float* __restrict__ SC)
{
  const int n = blockIdx.x, lane = threadIdx.x;
  const int row = fused_row(n);
  float m = 1e-20f;
  for (int k = lane; k < HIDDEN; k += 64)  m = fmaxf(m, fabsf(Whh0[(size_t)row * HIDDEN + k]));
  for (int k = lane; k < CONDDIM; k += 64) m = fmaxf(m, 4.f * fabsf(Wih0[(size_t)row * INDIM + XDIM + k]));
  #pragma unroll
  for (int o = 32; o > 0; o >>= 1) m = fmaxf(m, __shfl_xor(m, o, 64));
  if (lane == 0) { RM[n] = m; SC[n] = m / 16129.f; }
}

__global__ void rowmax1_k(const float* __restrict__ Wih1, const float* __restrict__ Whh1,
                          float* __restrict__ RM, float* __restrict__ SC)
{
  const int n = blockIdx.x, lane = threadIdx.x;
  const int row = fused_row(n);
  float m = 1e-20f;
  for (int k = lane; k < HIDDEN; k += 64) {
    m = fmaxf(m, fabsf(Wih1[(size_t)row * HIDDEN + k]));
    m = fmaxf(m, fabsf(Whh1[(size_t)row * HIDDEN + k]));
  }
  #pragma unroll
  for (int o = 32; o > 0; o >>= 1) m = fmaxf(m, __shfl_xor(m, o, 64));
  if (lane == 0) { RM[n] = m; SC[n] = m / 16129.f; }
}

__global__ void packi0_k(const float* __restrict__ Wih0, const float* __restrict__ Whh0,
                         const float* __restrict__ RM, signed char* __restrict__ Bp)
{
  const int t = blockIdx.x * blockDim.x + threadIdx.x;
  if (t >= GN * K0P) return;
  const int n = t / K0P, k = t % K0P;
  const int row = fused_row(n);
  float v = 0.f;
  if (k < HIDDEN)                v = Whh0[(size_t)row * HIDDEN + k];
  else if (k < HIDDEN + CONDDIM) v = 4.f * Wih0[(size_t)row * INDIM + XDIM + (k - HIDDEN)];
  Bp[t] = qscale(v, 127.f / RM[n]);
}

__global__ void packi1_k(const float* __restrict__ Wih1, const float* __restrict__ Whh1,
                         const float* __restrict__ RM, signed char* __restrict__ Bp)
{
  const int t = blockIdx.x * blockDim.x + threadIdx.x;
  if (t >= GN * K1P) return;
  const int n = t >> 11, k = t & 2047;
  const int row = fused_row(n);
  const float v = (k < HIDDEN) ? Wih1[(size_t)row * HIDDEN + k]
                               : Whh1[(size_t)row * HIDDEN + (k - HIDDEN)];
  Bp[t] = qscale(v, 127.f / RM[n]);
}

__global__ void packbias_k(const float* __restrict__ bih, const float* __restrict__ bhh,
                           float* __restrict__ bc)
{
  const int n = blockIdx.x * blockDim.x + threadIdx.x;
  if (n >= GN) return;
  const int row = fused_row(n);
  bc[n] = bih[row] + bhh[row];
}

__global__ void rowmaxf_k(const float* __restrict__ Wf, float* __restrict__ RM,
                          float* __restrict__ SC)
{
  const int n = blockIdx.x, lane = threadIdx.x;
  float m = 1e-20f;
  if (n < XDIM)
    for (int k = lane; k < HIDDEN; k += 64) m = fmaxf(m, fabsf(Wf[(size_t)n * HIDDEN + k]));
  else m = 1.f;
  #pragma unroll
  for (int o = 32; o > 0; o >>= 1) m = fmaxf(m, __shfl_xor(m, o, 64));
  if (lane == 0) { RM[n] = m; SC[n] = m / 16129.f; }
}

__global__ void packfi_k(const float* __restrict__ Wf, const float* __restrict__ RM,
                         signed char* __restrict__ Wfi)
{
  const int t = blockIdx.x * blockDim.x + threadIdx.x;
  if (t >= LGN * HIDDEN) return;
  const int r = t >> 10, k = t & 1023;
  const float v = (r < XDIM) ? Wf[(size_t)r * HIDDEN + k] : 0.f;
  Wfi[t] = qscale(v, 127.f / RM[r]);
}

__global__ void packt_k(const float* __restrict__ Wih0, float* __restrict__ W0T)
{
  const int t = blockIdx.x * blockDim.x + threadIdx.x;
  if (t >= XDIM * GN) return;
  const int e = t >> 12, n = t & 4095;
  W0T[t] = Wih0[(size_t)fused_row(n) * INDIM + e];
}

// ---------------------------------------------------------------- launch
extern "C" void kernel_launch(void* const* d_in, const int* in_sizes, int n_in,
                              void* d_out, int out_size, void* d_ws, size_t ws_size,
                              hipStream_t stream)
{
  const float* z    = (const float*)d_in[0];
  const float* x    = (const float*)d_in[1];
  const float* Wih0 = (const float*)d_in[2];
  const float* Whh0 = (const float*)d_in[3];
  const float* bih0 = (const float*)d_in[4];
  const float* bhh0 = (const float*)d_in[5];
  const float* Wih1 = (const float*)d_in[6];
  const float* Whh1 = (const float*)d_in[7];
  const float* bih1 = (const float*)d_in[8];
  const float* bhh1 = (const float*)d_in[9];
  const float* Wf   = (const float*)d_in[10];
  const float* bfv  = (const float*)d_in[11];
  float* out = (float*)d_out;

  char* ws = (char*)d_ws;
  size_t off = 0;
  auto alloc = [&](size_t bytes) { void* p = ws + off; off += (bytes + 255) & ~(size_t)255; return p; };

  float*       LG   = (float*)      alloc((size_t)BP * LGN * 4);
  signed char* H0a  = (signed char*)alloc((size_t)BP * 1024);
  signed char* H0b  = (signed char*)alloc((size_t)BP * 1024);
  signed char* H0s1 = (signed char*)alloc((size_t)BP * 1024);   // h0'_0 @ s1 (t=0 only)
  signed char* H1a  = (signed char*)alloc((size_t)BP * 1024);
  signed char* H1b  = (signed char*)alloc((size_t)BP * 1024);
  signed char* Y    = (signed char*)alloc((size_t)BP * 64);
  signed char* Bpi0 = (signed char*)alloc((size_t)GN * K0P);
  signed char* Bpi1 = (signed char*)alloc((size_t)GN * K1P);
  signed char* Wfi  = (signed char*)alloc((size_t)LGN * HIDDEN);
  float*       W0T  = (float*)      alloc((size_t)XDIM * GN * 4);
  float*       bc0  = (float*)      alloc((size_t)GN * 4);
  float*       bc1  = (float*)      alloc((size_t)GN * 4);
  float*       RM0  = (float*)      alloc((size_t)GN * 4);
  float*       SC0  = (float*)      alloc((size_t)GN * 4);
  float*       RM1  = (float*)      alloc((size_t)GN * 4);
  float*       SC1  = (float*)      alloc((size_t)GN * 4);
  float*       RMf  = (float*)      alloc((size_t)LGN * 4);
  float*       SCf  = (float*)      alloc((size_t)LGN * 4);
  float*       S0   = (float*)      alloc((size_t)BP * 4);
  float*       S1   = (float*)      alloc((size_t)BP * 4);
  float*       c0T  = (float*)      alloc((size_t)BP * HIDDEN * 4);
  float*       c1T  = (float*)      alloc((size_t)BP * HIDDEN * 4);
  int*         idx  = (int*)        alloc((size_t)BP * 4);
  (void)ws_size; (void)in_sizes; (void)n_in; (void)out_size;

  rowmax0_k<<<GN, 64, 0, stream>>>(Wih0, Whh0, RM0, SC0);
  rowmax1_k<<<GN, 64, 0, stream>>>(Wih1, Whh1, RM1, SC1);
  rowmaxf_k<<<LGN, 64, 0, stream>>>(Wf, RMf, SCf);
  packi0_k<<<(GN * K0P + 255) / 256, 256, 0, stream>>>(Wih0, Whh0, RM0, Bpi0);
  packi1_k<<<(GN * K1P + 255) / 256, 256, 0, stream>>>(Wih1, Whh1, RM1, Bpi1);
  packfi_k<<<(LGN * HIDDEN + 255) / 256, 256, 0, stream>>>(Wf, RMf, Wfi);
  packbias_k<<<(GN + 255) / 256, 256, 0, stream>>>(bih0, bhh0, bc0);
  packbias_k<<<(GN + 255) / 256, 256, 0, stream>>>(bih1, bhh1, bc1);
  packt_k<<<(XDIM * GN + 255) / 256, 256, 0, stream>>>(Wih0, W0T);
  // initq: z@s0 -> H0b (= H0prev at t=0), z@s1 -> H1b (= H1prev at t=0)
  initq_k<<<BP, 64, 0, stream>>>(z, x, c0T, c1T, H0b, H1b, Y, S0, S1, idx);

  for (int t = 0; t < NSTEP; ++t) {
    signed char* H0cur  = (t & 1) ? H0b : H0a;
    signed char* H0prev = (t & 1) ? H0a : H0b;
    signed char* H1cur  = (t & 1) ? H1b : H1a;
    signed char* H1prev = (t & 1) ? H1a : H1b;

    // layer 0: A = [h0_{t-1} | y_t], fused cell -> h0' (written once, scale 1)
    gemm_i8_cell_k<true><<<512, 512, 0, stream>>>(
        H0prev, Y, 64, Bpi0, K0P, bc0, SC0,
        (t == 0) ? S0 : nullptr, W0T, idx, c0T,
        H0cur,
        (t == 0) ? H0s1 : nullptr, S1);     // extra s1-scaled copy at t=0 only
    // layer 1: A = [h0'_t | h1_{t-1}], fused cell -> h1'
    gemm_i8_cell_k<false><<<512, 512, 0, stream>>>(
        (t == 0) ? H0s1 : H0cur, H1prev, 1024, Bpi1, K1P, bc1, SC1,
        (t == 0) ? S1 : nullptr, nullptr, nullptr, c1T,
        H1cur, nullptr, nullptr);
    // logits from int8 h1' (scale 1/127)
    logits_i8_k<<<dim3(LGN / 128, BP / 64), dim3(256), 0, stream>>>(
        H1cur, 1024, Wfi, SCf, LG, LGN);
    smax_k<<<BP, 64, 0, stream>>>(LG, bfv, out, t, x, Y, idx);
  }
}

// Round 20
// 1546.837 us; speedup vs baseline: 1.2604x; 1.0088x over previous
//
#include <hip/hip_runtime.h>
#include <hip/hip_bf16.h>

#define HIDDEN   1024
#define XDIM     130
#define CONDDIM  44
#define INDIM    174      // XDIM + CONDDIM
#define NSTEP    16
#define BP       4096     // effective batch (64*64)
#define K0P      1088     // 1024 (h) + 64 (y pad) ; i8: 17 tiles of 64
#define K1P      2048     // 1024 + 1024           ; i8: 32 tiles of 64
#define GN       4096     // 4*HIDDEN gate dim
#define LGN      256      // padded logits cols (130 -> 256)
#define SPLITK   16       // A-tiles < SPLITK from Alo (stride 1024), else Ahi

typedef float f32x4 __attribute__((ext_vector_type(4)));
typedef int   i32x4 __attribute__((ext_vector_type(4)));

// fused gate column order: n in [0,4096) -> q=(n>>4)&3 (gate), j=((n>>6)<<4)|(n&15)
__device__ __forceinline__ int fused_row(int n) {
  const int q = (n >> 4) & 3;
  const int j = ((n >> 6) << 4) | (n & 15);
  return q * HIDDEN + j;
}

__device__ __forceinline__ void g2lds16(const void* g, void* l) {
  __builtin_amdgcn_global_load_lds(
      (const __attribute__((address_space(1))) void*)g,
      (__attribute__((address_space(3))) void*)l, 16, 0, 0);
}

__device__ __forceinline__ float sigm(float x)  { return 1.f / (1.f + __expf(-x)); }
__device__ __forceinline__ float tanhfast(float x) { return 2.f / (1.f + __expf(-2.f * x)) - 1.f; }

__device__ __forceinline__ signed char qscale(float v, float inv127s) {
  int q = __float2int_rn(v * inv127s);
  q = q > 127 ? 127 : (q < -127 ? -127 : q);
  return (signed char)q;
}

// ================================================================ int8 gate GEMM + fused LSTM cell
// R20 = R19 + c state fp32 -> fp16 in the TILED layout. R19 byte budget for
// GEMM1: FETCH 33 MB = A 8 + B 8.4 + c-read 16; WRITE 20.5 = c-write 16 + h 4
// -> c is 58% of traffic. R14's fp16-c failure had two confounds now gone:
// scattered row-major 2B writes (tiled layout writes dense 32B chunks; the two
// n-half waves cover complementary halves of each 64B line) and a 32-VGPR
// prefetch (not used). Numerics: |c|~O(1), fp16 eps 2^-11 x 16 steps -> gate
// error ~0.002, absmax stays well under threshold.
template<bool FB>
__global__ __launch_bounds__(512, 4)
void gemm_i8_cell_k(const signed char* __restrict__ Alo,   // stride 1024
                    const signed char* __restrict__ Ahi, int ahstr,
                    const signed char* __restrict__ W, int K,
                    const float* __restrict__ bcomb,
                    const float* __restrict__ SC,        // Rmax/127^2, fused order
                    const float* __restrict__ sA,        // per-row A scale (or null)
                    const float* __restrict__ W0T,       // 130 x 4096 fused (FB only)
                    const int*   __restrict__ idx,       // feedback index (FB only)
                    _Float16* __restrict__ cT,           // tiled: [j>>5][b][j&31] fp16
                    signed char* __restrict__ d1,        // stride 1024, scale 1
                    signed char* __restrict__ d2,        // stride 1024, scale sD2 (or null)
                    const float* __restrict__ sD2)
{
  __shared__ __align__(16) signed char lds[3 * 24576];   // 3 buf x (A 16KB + B 8KB)

  const int tid  = threadIdx.x;
  const int w    = tid >> 6;        // wave 0..7
  const int lane = tid & 63;
  const int bid  = blockIdx.x;      // 512 blocks (16 m-tiles x 32 n-tiles)
  // XCD swizzle: each XCD owns an 8m x 8n rectangle, m-major inside
  const int xcd  = bid & 7;
  const int rr   = bid >> 3;        // 0..63
  const int mt   = (xcd & 1) * 8 + (rr & 7);
  const int nt   = (xcd >> 1) * 8 + (rr >> 3);
  const int m0   = mt * 256;
  const int n0   = nt * 128;
  const int wm   = w >> 1;          // 0..3 : 64-row quarter
  const int wn   = w & 1;           // 0..1 : 64-col half
  const int fr   = lane & 15;
  const int kqs  = (((lane >> 4) ^ ((fr >> 1) & 3)) * 16);   // swizzled 16B chunk
  const int sr   = lane >> 2;
  const int sc   = (((lane & 3) ^ ((sr >> 1) & 3)) * 16);    // pre-XORed source chunk
  const int NT   = K >> 6;          // K-tiles of 64 int8 (64 B rows)

  const int fq = lane >> 4;
  const int cb = n0 + wn * 64;
  const int j  = ((cb >> 6) << 4) | fr;

  i32x4 acc[4][4] = {};

  // hoisted staging source bases (per-lane pre-swizzled chunk folded in)
  const signed char* aLo0 = Alo + (size_t)(m0 + w * 32 +      sr) * 1024  + sc;
  const signed char* aLo1 = Alo + (size_t)(m0 + w * 32 + 16 + sr) * 1024  + sc;
  const signed char* aHi0 = Ahi + (size_t)(m0 + w * 32 +      sr) * ahstr + sc;
  const signed char* aHi1 = Ahi + (size_t)(m0 + w * 32 + 16 + sr) * ahstr + sc;
  const signed char* bB   = W   + (size_t)(n0 + w * 16 +      sr) * K     + sc;

  auto stage = [&](int t, int buf) {
    signed char* dA = lds + buf * 24576 + (w * 32) * 64;
    signed char* dB = lds + buf * 24576 + 16384 + (w * 16) * 64;
    const bool lo = t < SPLITK;
    const signed char* s0 = lo ? aLo0 : aHi0;
    const signed char* s1 = lo ? aLo1 : aHi1;
    const int ko = (lo ? t : t - SPLITK) * 64;
    g2lds16(s0 + ko, dA);
    g2lds16(s1 + ko, dA + 1024);
    g2lds16(bB + t * 64, dB);
  };

  // prologue: tiles 0,1 into bufs 0,1; wait tile 0 (tile 1's 3 ops in flight)
  stage(0, 0);
  stage(1, 1);
  asm volatile("s_waitcnt vmcnt(3)" ::: "memory");
  __builtin_amdgcn_s_barrier();

  int bcur = 0, bnx2 = 2;
  for (int t = 0; t < NT; ++t) {
    const signed char* As = lds + bcur * 24576;
    const signed char* Bs = As + 16384;

    if (t + 2 < NT) stage(t + 2, bnx2);   // issue early; buf (t-1)%3 is drained

    i32x4 afr[4], bfr[4];
    #pragma unroll
    for (int q = 0; q < 4; ++q)
      afr[q] = *reinterpret_cast<const i32x4*>(&As[(wm * 64 + q * 16 + fr) * 64 + kqs]);
    #pragma unroll
    for (int nf = 0; nf < 4; ++nf)
      bfr[nf] = *reinterpret_cast<const i32x4*>(&Bs[(wn * 64 + nf * 16 + fr) * 64 + kqs]);

    __builtin_amdgcn_s_setprio(1);
    #pragma unroll
    for (int q = 0; q < 4; ++q)
      #pragma unroll
      for (int nf = 0; nf < 4; ++nf)
        acc[q][nf] = __builtin_amdgcn_mfma_i32_16x16x64_i8(afr[q], bfr[nf], acc[q][nf], 0, 0, 0);
    __builtin_amdgcn_s_setprio(0);

    if (t + 1 < NT) {
      if (t + 2 < NT) asm volatile("s_waitcnt vmcnt(3)" ::: "memory");  // t+1 landed
      else            asm volatile("s_waitcnt vmcnt(0)" ::: "memory");
      __builtin_amdgcn_s_barrier();
    }
    bcur = (bcur == 2) ? 0 : bcur + 1;
    bnx2 = (bnx2 == 2) ? 0 : bnx2 + 1;
  }

  // ---- fused LSTM cell epilogue ----
  const float bs0 = bcomb[cb + fr],      sc0 = SC[cb + fr];
  const float bs1 = bcomb[cb + 16 + fr], sc1 = SC[cb + 16 + fr];
  const float bs2 = bcomb[cb + 32 + fr], sc2 = SC[cb + 32 + fr];
  const float bs3 = bcomb[cb + 48 + fr], sc3 = SC[cb + 48 + fr];
  const size_t ctbase = (size_t)(j >> 5) * ((size_t)BP * 32) + (j & 31);

  #pragma unroll
  for (int mf = 0; mf < 4; ++mf) {
    #pragma unroll
    for (int r = 0; r < 4; ++r) {
      const int b = m0 + wm * 64 + mf * 16 + fq * 4 + r;
      const float sa = sA ? sA[b] : 1.f;
      float gi = (float)acc[mf][0][r] * (sc0 * sa) + bs0;
      float gf = (float)acc[mf][1][r] * (sc1 * sa) + bs1;
      float gg = (float)acc[mf][2][r] * (sc2 * sa) + bs2;
      float go = (float)acc[mf][3][r] * (sc3 * sa) + bs3;
      if (FB) {
        const float* wr = W0T + (size_t)idx[b] * GN;
        gi += wr[cb + fr];
        gf += wr[cb + 16 + fr];
        gg += wr[cb + 32 + fr];
        go += wr[cb + 48 + fr];
      }
      const size_t ci = ctbase + (size_t)b * 32;
      const float cn = sigm(gf) * (float)cT[ci] + sigm(gi) * tanhfast(gg);
      cT[ci] = (_Float16)cn;
      const float hn = sigm(go) * tanhfast(cn);
      d1[(size_t)b * 1024 + j] = qscale(hn, 127.f);
      if (d2) d2[(size_t)b * 1024 + j] = qscale(hn, 127.f / sD2[b]);
    }
  }
}

// ---------------------------------------------------------------- int8 logits GEMM (64x128 tile, 128 blocks)
__global__ __launch_bounds__(256, 4)
void logits_i8_k(const signed char* __restrict__ A, int lda,   // h1' rows (stride 1024)
                 const signed char* __restrict__ Wfi,          // [256][1024] int8
                 const float* __restrict__ SCf,                // RMf/127^2
                 float* __restrict__ C, int ldc)
{
  __shared__ __align__(16) signed char As[64 * 64];    // 4 KB
  __shared__ __align__(16) signed char Bs[128 * 64];   // 8 KB

  const int tid  = threadIdx.x;
  const int w    = tid >> 6;
  const int lane = tid & 63;
  const int m0 = blockIdx.y * 64;
  const int n0 = blockIdx.x * 128;
  const int wm = w >> 1;
  const int wn = w & 1;
  const int fr = lane & 15;
  const int kqs = (((lane >> 4) ^ ((fr >> 1) & 3)) * 16);
  const int sr  = lane >> 2;
  const int sc  = (((lane & 3) ^ ((sr >> 1) & 3)) * 16);

  i32x4 acc[2][4] = {};

  for (int k0 = 0; k0 < HIDDEN; k0 += 64) {
    __syncthreads();
    g2lds16(A + (size_t)(m0 + w * 16 + sr) * lda + (k0 + sc), (void*)(As + (w * 16) * 64));
    g2lds16(Wfi + (size_t)(n0 + w * 16 + sr) * HIDDEN + (k0 + sc), (void*)(Bs + (w * 16) * 64));
    g2lds16(Wfi + (size_t)(n0 + 64 + w * 16 + sr) * HIDDEN + (k0 + sc), (void*)(Bs + (64 + w * 16) * 64));
    __syncthreads();

    i32x4 af[2], bw[4];
    #pragma unroll
    for (int i = 0; i < 2; ++i)
      af[i] = *reinterpret_cast<const i32x4*>(&As[(wm * 32 + i * 16 + fr) * 64 + kqs]);
    #pragma unroll
    for (int jn = 0; jn < 4; ++jn)
      bw[jn] = *reinterpret_cast<const i32x4*>(&Bs[(wn * 64 + jn * 16 + fr) * 64 + kqs]);
    #pragma unroll
    for (int i = 0; i < 2; ++i)
      #pragma unroll
      for (int jn = 0; jn < 4; ++jn)
        acc[i][jn] = __builtin_amdgcn_mfma_i32_16x16x64_i8(af[i], bw[jn], acc[i][jn], 0, 0, 0);
  }

  const int fq = lane >> 4;
  #pragma unroll
  for (int i = 0; i < 2; ++i)
    #pragma unroll
    for (int jn = 0; jn < 4; ++jn) {
      const int col = n0 + wn * 64 + jn * 16 + fr;
      const float scf = SCf[col];
      #pragma unroll
      for (int r = 0; r < 4; ++r) {
        const int row = m0 + wm * 32 + i * 16 + fq * 4 + r;
        C[(size_t)row * ldc + col] = (float)acc[i][jn][r] * scf;
      }
    }
}

// ---------------------------------------------------------------- log_softmax + argmax + y staging
__global__ void smax_k(const float* __restrict__ LG,
                       const float* __restrict__ bfv,
                       float* __restrict__ out, int t,
                       const float* __restrict__ x,
                       signed char* __restrict__ Y,      // [BP][64], y/4 at scale 1
                       int* __restrict__ idx)
{
  const int b    = blockIdx.x;
  const int lane = threadIdx.x;   // 64
  const float NINF = -__builtin_inff();
  const float* lg = LG + (size_t)b * LGN;

  const int c1 = lane + 64, c2 = lane + 128;
  float v0 = lg[lane] + bfv[lane];
  float v1 = lg[c1] + bfv[c1];
  float v2 = (c2 < XDIM) ? lg[c2] + bfv[c2] : NINF;

  float m = fmaxf(v0, fmaxf(v1, v2));
  #pragma unroll
  for (int o = 32; o > 0; o >>= 1) m = fmaxf(m, __shfl_xor(m, o, 64));

  int bi = 0x7fffffff;
  if (v0 == m) bi = lane;
  if (v1 == m) bi = min(bi, c1);
  if (v2 == m) bi = min(bi, c2);
  #pragma unroll
  for (int o = 32; o > 0; o >>= 1) bi = min(bi, __shfl_xor(bi, o, 64));

  float s = __expf(v0 - m) + __expf(v1 - m) + ((c2 < XDIM) ? __expf(v2 - m) : 0.f);
  #pragma unroll
  for (int o = 32; o > 0; o >>= 1) s += __shfl_xor(s, o, 64);
  const float lse = __logf(s);

  float* orow = out + ((size_t)b * NSTEP + t) * XDIM;
  orow[lane] = v0 - m - lse;
  orow[c1]   = v1 - m - lse;
  if (c2 < XDIM) orow[c2] = v2 - m - lse;
  if (lane == 0) idx[b] = bi;

  if (t + 1 < NSTEP) {
    const float yv = (lane < CONDDIM)
        ? x[((size_t)b * NSTEP + (t + 1)) * INDIM + XDIM + lane] : 0.f;
    Y[(size_t)b * 64 + lane] = qscale(yv * 0.25f, 127.f);
  }
}

// ---------------------------------------------------------------- init: per-row scales + quantized z + zero c
__global__ void initq_k(const float* __restrict__ z, const float* __restrict__ x,
                        _Float16* __restrict__ c0T, _Float16* __restrict__ c1T,
                        signed char* __restrict__ Hz0,   // z @ s0, stride 1024
                        signed char* __restrict__ Hz1,   // z @ s1, stride 1024
                        signed char* __restrict__ Y,
                        float* __restrict__ S0, float* __restrict__ S1,
                        int* __restrict__ idx)
{
  const int b    = blockIdx.x;
  const int lane = threadIdx.x;   // 64
  const float* zr = z + (size_t)b * HIDDEN;

  float mz = 0.f;
  for (int k = lane; k < HIDDEN; k += 64) mz = fmaxf(mz, fabsf(zr[k]));
  #pragma unroll
  for (int o = 32; o > 0; o >>= 1) mz = fmaxf(mz, __shfl_xor(mz, o, 64));

  const float yv = (lane < CONDDIM) ? x[((size_t)b * NSTEP) * INDIM + XDIM + lane] : 0.f;
  float my = fabsf(yv) * 0.25f;
  #pragma unroll
  for (int o = 32; o > 0; o >>= 1) my = fmaxf(my, __shfl_xor(my, o, 64));

  const float s0 = fmaxf(fmaxf(mz, my), 1e-6f);
  const float s1 = fmaxf(mz, 1.f);
  const float i0 = 127.f / s0;
  const float i1 = 127.f / s1;

  for (int k = lane; k < HIDDEN; k += 64) {
    const float zv = zr[k];
    Hz0[(size_t)b * 1024 + k] = qscale(zv, i0);
    Hz1[(size_t)b * 1024 + k] = qscale(zv, i1);
    const size_t ci = (size_t)(k >> 5) * ((size_t)BP * 32) + (size_t)b * 32 + (k & 31);
    c0T[ci] = (_Float16)0.f;
    c1T[ci] = (_Float16)0.f;
  }
  Y[(size_t)b * 64 + lane] = qscale(yv * 0.25f, i0);   // y_0 @ s0 (+ zero pad)
  if (lane == 0) { S0[b] = s0; S1[b] = s1; idx[b] = 1; }
}

// ---------------------------------------------------------------- weight packing
__global__ void rowmax0_k(const float* __restrict__ Wih0, const float* __restrict__ Whh0,
                          float* __restrict__ RM, float* __restrict__ SC)
{
  const int n = blockIdx.x, lane = threadIdx.x;
  const int row = fused_row(n);
  float m = 1e-20f;
  for (int k = lane; k < HIDDEN; k += 64)  m = fmaxf(m, fabsf(Whh0[(size_t)row * HIDDEN + k]));
  for (int k = lane; k < CONDDIM; k += 64) m = fmaxf(m, 4.f * fabsf(Wih0[(size_t)row * INDIM + XDIM + k]));
  #pragma unroll
  for (int o = 32; o > 0; o >>= 1) m = fmaxf(m, __shfl_xor(m, o, 64));
  if (lane == 0) { RM[n] = m; SC[n] = m / 16129.f; }
}

__global__ void rowmax1_k(const float* __restrict__ Wih1, const float* __restrict__ Whh1,
                          float* __restrict__ RM, float* __restrict__ SC)
{
  const int n = blockIdx.x, lane = threadIdx.x;
  const int row = fused_row(n);
  float m = 1e-20f;
  for (int k = lane; k < HIDDEN; k += 64) {
    m = fmaxf(m, fabsf(Wih1[(size_t)row * HIDDEN + k]));
    m = fmaxf(m, fabsf(Whh1[(size_t)row * HIDDEN + k]));
  }
  #pragma unroll
  for (int o = 32; o > 0; o >>= 1) m = fmaxf(m, __shfl_xor(m, o, 64));
  if (lane == 0) { RM[n] = m; SC[n] = m / 16129.f; }
}

__global__ void packi0_k(const float* __restrict__ Wih0, const float* __restrict__ Whh0,
                         const float* __restrict__ RM, signed char* __restrict__ Bp)
{
  const int t = blockIdx.x * blockDim.x + threadIdx.x;
  if (t >= GN * K0P) return;
  const int n = t / K0P, k = t % K0P;
  const int row = fused_row(n);
  float v = 0.f;
  if (k < HIDDEN)                v = Whh0[(size_t)row * HIDDEN + k];
  else if (k < HIDDEN + CONDDIM) v = 4.f * Wih0[(size_t)row * INDIM + XDIM + (k - HIDDEN)];
  Bp[t] = qscale(v, 127.f / RM[n]);
}

__global__ void packi1_k(const float* __restrict__ Wih1, const float* __restrict__ Whh1,
                         const float* __restrict__ RM, signed char* __restrict__ Bp)
{
  const int t = blockIdx.x * blockDim.x + threadIdx.x;
  if (t >= GN * K1P) return;
  const int n = t >> 11, k = t & 2047;
  const int row = fused_row(n);
  const float v = (k < HIDDEN) ? Wih1[(size_t)row * HIDDEN + k]
                               : Whh1[(size_t)row * HIDDEN + (k - HIDDEN)];
  Bp[t] = qscale(v, 127.f / RM[n]);
}

__global__ void packbias_k(const float* __restrict__ bih, const float* __restrict__ bhh,
                           float* __restrict__ bc)
{
  const int n = blockIdx.x * blockDim.x + threadIdx.x;
  if (n >= GN) return;
  const int row = fused_row(n);
  bc[n] = bih[row] + bhh[row];
}

__global__ void rowmaxf_k(const float* __restrict__ Wf, float* __restrict__ RM,
                          float* __restrict__ SC)
{
  const int n = blockIdx.x, lane = threadIdx.x;
  float m = 1e-20f;
  if (n < XDIM)
    for (int k = lane; k < HIDDEN; k += 64) m = fmaxf(m, fabsf(Wf[(size_t)n * HIDDEN + k]));
  else m = 1.f;
  #pragma unroll
  for (int o = 32; o > 0; o >>= 1) m = fmaxf(m, __shfl_xor(m, o, 64));
  if (lane == 0) { RM[n] = m; SC[n] = m / 16129.f; }
}

__global__ void packfi_k(const float* __restrict__ Wf, const float* __restrict__ RM,
                         signed char* __restrict__ Wfi)
{
  const int t = blockIdx.x * blockDim.x + threadIdx.x;
  if (t >= LGN * HIDDEN) return;
  const int r = t >> 10, k = t & 1023;
  const float v = (r < XDIM) ? Wf[(size_t)r * HIDDEN + k] : 0.f;
  Wfi[t] = qscale(v, 127.f / RM[r]);
}

__global__ void packt_k(const float* __restrict__ Wih0, float* __restrict__ W0T)
{
  const int t = blockIdx.x * blockDim.x + threadIdx.x;
  if (t >= XDIM * GN) return;
  const int e = t >> 12, n = t & 4095;
  W0T[t] = Wih0[(size_t)fused_row(n) * INDIM + e];
}

// ---------------------------------------------------------------- launch
extern "C" void kernel_launch(void* const* d_in, const int* in_sizes, int n_in,
                              void* d_out, int out_size, void* d_ws, size_t ws_size,
                              hipStream_t stream)
{
  const float* z    = (const float*)d_in[0];
  const float* x    = (const float*)d_in[1];
  const float* Wih0 = (const float*)d_in[2];
  const float* Whh0 = (const float*)d_in[3];
  const float* bih0 = (const float*)d_in[4];
  const float* bhh0 = (const float*)d_in[5];
  const float* Wih1 = (const float*)d_in[6];
  const float* Whh1 = (const float*)d_in[7];
  const float* bih1 = (const float*)d_in[8];
  const float* bhh1 = (const float*)d_in[9];
  const float* Wf   = (const float*)d_in[10];
  const float* bfv  = (const float*)d_in[11];
  float* out = (float*)d_out;

  char* ws = (char*)d_ws;
  size_t off = 0;
  auto alloc = [&](size_t bytes) { void* p = ws + off; off += (bytes + 255) & ~(size_t)255; return p; };

  float*       LG   = (float*)      alloc((size_t)BP * LGN * 4);
  signed char* H0a  = (signed char*)alloc((size_t)BP * 1024);
  signed char* H0b  = (signed char*)alloc((size_t)BP * 1024);
  signed char* H0s1 = (signed char*)alloc((size_t)BP * 1024);   // h0'_0 @ s1 (t=0 only)
  signed char* H1a  = (signed char*)alloc((size_t)BP * 1024);
  signed char* H1b  = (signed char*)alloc((size_t)BP * 1024);
  signed char* Y    = (signed char*)alloc((size_t)BP * 64);
  signed char* Bpi0 = (signed char*)alloc((size_t)GN * K0P);
  signed char* Bpi1 = (signed char*)alloc((size_t)GN * K1P);
  signed char* Wfi  = (signed char*)alloc((size_t)LGN * HIDDEN);
  float*       W0T  = (float*)      alloc((size_t)XDIM * GN * 4);
  float*       bc0  = (float*)      alloc((size_t)GN * 4);
  float*       bc1  = (float*)      alloc((size_t)GN * 4);
  float*       RM0  = (float*)      alloc((size_t)GN * 4);
  float*       SC0  = (float*)      alloc((size_t)GN * 4);
  float*       RM1  = (float*)      alloc((size_t)GN * 4);
  float*       SC1  = (float*)      alloc((size_t)GN * 4);
  float*       RMf  = (float*)      alloc((size_t)LGN * 4);
  float*       SCf  = (float*)      alloc((size_t)LGN * 4);
  float*       S0   = (float*)      alloc((size_t)BP * 4);
  float*       S1   = (float*)      alloc((size_t)BP * 4);
  _Float16*    c0T  = (_Float16*)   alloc((size_t)BP * HIDDEN * 2);
  _Float16*    c1T  = (_Float16*)   alloc((size_t)BP * HIDDEN * 2);
  int*         idx  = (int*)        alloc((size_t)BP * 4);
  (void)ws_size; (void)in_sizes; (void)n_in; (void)out_size;

  rowmax0_k<<<GN, 64, 0, stream>>>(Wih0, Whh0, RM0, SC0);
  rowmax1_k<<<GN, 64, 0, stream>>>(Wih1, Whh1, RM1, SC1);
  rowmaxf_k<<<LGN, 64, 0, stream>>>(Wf, RMf, SCf);
  packi0_k<<<(GN * K0P + 255) / 256, 256, 0, stream>>>(Wih0, Whh0, RM0, Bpi0);
  packi1_k<<<(GN * K1P + 255) / 256, 256, 0, stream>>>(Wih1, Whh1, RM1, Bpi1);
  packfi_k<<<(LGN * HIDDEN + 255) / 256, 256, 0, stream>>>(Wf, RMf, Wfi);
  packbias_k<<<(GN + 255) / 256, 256, 0, stream>>>(bih0, bhh0, bc0);
  packbias_k<<<(GN + 255) / 256, 256, 0, stream>>>(bih1, bhh1, bc1);
  packt_k<<<(XDIM * GN + 255) / 256, 256, 0, stream>>>(Wih0, W0T);
  // initq: z@s0 -> H0b (= H0prev at t=0), z@s1 -> H1b (= H1prev at t=0)
  initq_k<<<BP, 64, 0, stream>>>(z, x, c0T, c1T, H0b, H1b, Y, S0, S1, idx);

  for (int t = 0; t < NSTEP; ++t) {
    signed char* H0cur  = (t & 1) ? H0b : H0a;
    signed char* H0prev = (t & 1) ? H0a : H0b;
    signed char* H1cur  = (t & 1) ? H1b : H1a;
    signed char* H1prev = (t & 1) ? H1a : H1b;

    // layer 0: A = [h0_{t-1} | y_t], fused cell -> h0' (written once, scale 1)
    gemm_i8_cell_k<true><<<512, 512, 0, stream>>>(
        H0prev, Y, 64, Bpi0, K0P, bc0, SC0,
        (t == 0) ? S0 : nullptr, W0T, idx, c0T,
        H0cur,
        (t == 0) ? H0s1 : nullptr, S1);     // extra s1-scaled copy at t=0 only
    // layer 1: A = [h0'_t | h1_{t-1}], fused cell -> h1'
    gemm_i8_cell_k<false><<<512, 512, 0, stream>>>(
        (t == 0) ? H0s1 : H0cur, H1prev, 1024, Bpi1, K1P, bc1, SC1,
        (t == 0) ? S1 : nullptr, nullptr, nullptr, c1T,
        H1cur, nullptr, nullptr);
    // logits from int8 h1' (scale 1/127)
    logits_i8_k<<<dim3(LGN / 128, BP / 64), dim3(256), 0, stream>>>(
        H1cur, 1024, Wfi, SCf, LG, LGN);
    smax_k<<<BP, 64, 0, stream>>>(LG, bfv, out, t, x, Y, idx);
  }
}

// Round 21
// 1499.044 us; speedup vs baseline: 1.3006x; 1.0319x over previous
//
#include <hip/hip_runtime.h>
#include <hip/hip_bf16.h>

#define HIDDEN   1024
#define XDIM     130
#define CONDDIM  44
#define INDIM    174      // XDIM + CONDDIM
#define NSTEP    16
#define BP       4096     // effective batch (64*64)
#define K0P      1088     // 1024 (h) + 64 (y pad) ; i8: 17 tiles of 64
#define K1P      2048     // 1024 + 1024           ; i8: 32 tiles of 64
#define GN       4096     // 4*HIDDEN gate dim
#define LGN      256      // padded logits cols (130 -> 256)
#define SPLITK   16       // A-tiles < SPLITK from Alo (stride 1024), else Ahi

typedef float f32x4 __attribute__((ext_vector_type(4)));
typedef int   i32x4 __attribute__((ext_vector_type(4)));

// fused gate column order: n in [0,4096) -> q=(n>>4)&3 (gate), j=((n>>6)<<4)|(n&15)
__device__ __forceinline__ int fused_row(int n) {
  const int q = (n >> 4) & 3;
  const int j = ((n >> 6) << 4) | (n & 15);
  return q * HIDDEN + j;
}

__device__ __forceinline__ void g2lds16(const void* g, void* l) {
  __builtin_amdgcn_global_load_lds(
      (const __attribute__((address_space(1))) void*)g,
      (__attribute__((address_space(3))) void*)l, 16, 0, 0);
}

__device__ __forceinline__ float sigm(float x)  { return 1.f / (1.f + __expf(-x)); }
__device__ __forceinline__ float tanhfast(float x) { return 2.f / (1.f + __expf(-2.f * x)) - 1.f; }

__device__ __forceinline__ signed char qscale(float v, float inv127s) {
  int q = __float2int_rn(v * inv127s);
  q = q > 127 ? 127 : (q < -127 ? -127 : q);
  return (signed char)q;
}

// ================================================================ int8 gate GEMM + fused LSTM cell
// R21: fully compile-time K-loop. R20 showed the gate dispatch is NOT
// byte-bound (bytes -24% -> dur unchanged); VALUBusy 41% was the top pipe:
// runtime buffer rotation (t%3), per-tile LDS address recompute, and the
// t<SPLITK select. NT is now a template parameter and the loop is fully
// unrolled: every buffer index, staging offset and branch constant-folds;
// the compiler schedules across tiles. Everything else identical to R20
// (256m x 128n, 8 waves 4m x 2n, 2 blocks/CU, 3 LDS bufs, fp16 tiled c).
template<bool FB, int NT>
__global__ __launch_bounds__(512, 4)
void gemm_i8_cell_k(const signed char* __restrict__ Alo,   // stride 1024
                    const signed char* __restrict__ Ahi, int ahstr,
                    const signed char* __restrict__ W, int K,
                    const float* __restrict__ bcomb,
                    const float* __restrict__ SC,        // Rmax/127^2, fused order
                    const float* __restrict__ sA,        // per-row A scale (or null)
                    const float* __restrict__ W0T,       // 130 x 4096 fused (FB only)
                    const int*   __restrict__ idx,       // feedback index (FB only)
                    _Float16* __restrict__ cT,           // tiled: [j>>5][b][j&31] fp16
                    signed char* __restrict__ d1,        // stride 1024, scale 1
                    signed char* __restrict__ d2,        // stride 1024, scale sD2 (or null)
                    const float* __restrict__ sD2)
{
  __shared__ __align__(16) signed char lds[3 * 24576];   // 3 buf x (A 16KB + B 8KB)

  const int tid  = threadIdx.x;
  const int w    = tid >> 6;        // wave 0..7
  const int lane = tid & 63;
  const int bid  = blockIdx.x;      // 512 blocks (16 m-tiles x 32 n-tiles)
  // XCD swizzle: each XCD owns an 8m x 8n rectangle, m-major inside
  const int xcd  = bid & 7;
  const int rr   = bid >> 3;        // 0..63
  const int mt   = (xcd & 1) * 8 + (rr & 7);
  const int nt   = (xcd >> 1) * 8 + (rr >> 3);
  const int m0   = mt * 256;
  const int n0   = nt * 128;
  const int wm   = w >> 1;          // 0..3 : 64-row quarter
  const int wn   = w & 1;           // 0..1 : 64-col half
  const int fr   = lane & 15;
  const int kqs  = (((lane >> 4) ^ ((fr >> 1) & 3)) * 16);   // swizzled 16B chunk
  const int sr   = lane >> 2;
  const int sc   = (((lane & 3) ^ ((sr >> 1) & 3)) * 16);    // pre-XORed source chunk

  const int fq = lane >> 4;
  const int cb = n0 + wn * 64;
  const int j  = ((cb >> 6) << 4) | fr;

  i32x4 acc[4][4] = {};

  // hoisted staging source bases (per-lane pre-swizzled chunk folded in)
  const signed char* aLo0 = Alo + (size_t)(m0 + w * 32 +      sr) * 1024  + sc;
  const signed char* aLo1 = Alo + (size_t)(m0 + w * 32 + 16 + sr) * 1024  + sc;
  const signed char* aHi0 = Ahi + (size_t)(m0 + w * 32 +      sr) * ahstr + sc;
  const signed char* aHi1 = Ahi + (size_t)(m0 + w * 32 + 16 + sr) * ahstr + sc;
  const signed char* bB   = W   + (size_t)(n0 + w * 16 +      sr) * K     + sc;

  // hoisted LDS staging dest bases (per-wave)
  signed char* const dA0 = lds + (w * 32) * 64;
  signed char* const dB0 = lds + 16384 + (w * 16) * 64;

  #define STAGE(T, BUF) do {                                                  \
    signed char* dA_ = dA0 + (BUF) * 24576;                                   \
    signed char* dB_ = dB0 + (BUF) * 24576;                                   \
    if ((T) < SPLITK) {                                                       \
      g2lds16(aLo0 + (T) * 64, dA_);                                          \
      g2lds16(aLo1 + (T) * 64, dA_ + 1024);                                   \
    } else {                                                                  \
      g2lds16(aHi0 + ((T) - SPLITK) * 64, dA_);                               \
      g2lds16(aHi1 + ((T) - SPLITK) * 64, dA_ + 1024);                        \
    }                                                                         \
    g2lds16(bB + (T) * 64, dB_);                                              \
  } while (0)

  // prologue: tiles 0,1 into bufs 0,1; wait tile 0 (tile 1's 3 ops in flight)
  STAGE(0, 0);
  STAGE(1, 1);
  asm volatile("s_waitcnt vmcnt(3)" ::: "memory");
  __builtin_amdgcn_s_barrier();

  #pragma unroll
  for (int t = 0; t < NT; ++t) {               // NT compile-time: full unroll,
    const int buf = t % 3;                     // buf / offsets constant-fold
    const signed char* As = lds + buf * 24576;
    const signed char* Bs = As + 16384;

    if (t + 2 < NT) STAGE(t + 2, (t + 2) % 3); // buf (t-1)%3 drained already

    i32x4 afr[4], bfr[4];
    #pragma unroll
    for (int q = 0; q < 4; ++q)
      afr[q] = *reinterpret_cast<const i32x4*>(&As[(wm * 64 + q * 16 + fr) * 64 + kqs]);
    #pragma unroll
    for (int nf = 0; nf < 4; ++nf)
      bfr[nf] = *reinterpret_cast<const i32x4*>(&Bs[(wn * 64 + nf * 16 + fr) * 64 + kqs]);

    __builtin_amdgcn_s_setprio(1);
    #pragma unroll
    for (int q = 0; q < 4; ++q)
      #pragma unroll
      for (int nf = 0; nf < 4; ++nf)
        acc[q][nf] = __builtin_amdgcn_mfma_i32_16x16x64_i8(afr[q], bfr[nf], acc[q][nf], 0, 0, 0);
    __builtin_amdgcn_s_setprio(0);

    if (t + 1 < NT) {
      if (t + 2 < NT) asm volatile("s_waitcnt vmcnt(3)" ::: "memory");  // t+1 landed
      else            asm volatile("s_waitcnt vmcnt(0)" ::: "memory");
      __builtin_amdgcn_s_barrier();
    }
  }
  #undef STAGE

  // ---- fused LSTM cell epilogue ----
  const float bs0 = bcomb[cb + fr],      sc0 = SC[cb + fr];
  const float bs1 = bcomb[cb + 16 + fr], sc1 = SC[cb + 16 + fr];
  const float bs2 = bcomb[cb + 32 + fr], sc2 = SC[cb + 32 + fr];
  const float bs3 = bcomb[cb + 48 + fr], sc3 = SC[cb + 48 + fr];
  const size_t ctbase = (size_t)(j >> 5) * ((size_t)BP * 32) + (j & 31);

  #pragma unroll
  for (int mf = 0; mf < 4; ++mf) {
    #pragma unroll
    for (int r = 0; r < 4; ++r) {
      const int b = m0 + wm * 64 + mf * 16 + fq * 4 + r;
      const float sa = sA ? sA[b] : 1.f;
      float gi = (float)acc[mf][0][r] * (sc0 * sa) + bs0;
      float gf = (float)acc[mf][1][r] * (sc1 * sa) + bs1;
      float gg = (float)acc[mf][2][r] * (sc2 * sa) + bs2;
      float go = (float)acc[mf][3][r] * (sc3 * sa) + bs3;
      if (FB) {
        const float* wr = W0T + (size_t)idx[b] * GN;
        gi += wr[cb + fr];
        gf += wr[cb + 16 + fr];
        gg += wr[cb + 32 + fr];
        go += wr[cb + 48 + fr];
      }
      const size_t ci = ctbase + (size_t)b * 32;
      const float cn = sigm(gf) * (float)cT[ci] + sigm(gi) * tanhfast(gg);
      cT[ci] = (_Float16)cn;
      const float hn = sigm(go) * tanhfast(cn);
      d1[(size_t)b * 1024 + j] = qscale(hn, 127.f);
      if (d2) d2[(size_t)b * 1024 + j] = qscale(hn, 127.f / sD2[b]);
    }
  }
}

// ---------------------------------------------------------------- int8 logits GEMM (64x128 tile, 128 blocks)
__global__ __launch_bounds__(256, 4)
void logits_i8_k(const signed char* __restrict__ A, int lda,   // h1' rows (stride 1024)
                 const signed char* __restrict__ Wfi,          // [256][1024] int8
                 const float* __restrict__ SCf,                // RMf/127^2
                 float* __restrict__ C, int ldc)
{
  __shared__ __align__(16) signed char As[64 * 64];    // 4 KB
  __shared__ __align__(16) signed char Bs[128 * 64];   // 8 KB

  const int tid  = threadIdx.x;
  const int w    = tid >> 6;
  const int lane = tid & 63;
  const int m0 = blockIdx.y * 64;
  const int n0 = blockIdx.x * 128;
  const int wm = w >> 1;
  const int wn = w & 1;
  const int fr = lane & 15;
  const int kqs = (((lane >> 4) ^ ((fr >> 1) & 3)) * 16);
  const int sr  = lane >> 2;
  const int sc  = (((lane & 3) ^ ((sr >> 1) & 3)) * 16);

  i32x4 acc[2][4] = {};

  for (int k0 = 0; k0 < HIDDEN; k0 += 64) {
    __syncthreads();
    g2lds16(A + (size_t)(m0 + w * 16 + sr) * lda + (k0 + sc), (void*)(As + (w * 16) * 64));
    g2lds16(Wfi + (size_t)(n0 + w * 16 + sr) * HIDDEN + (k0 + sc), (void*)(Bs + (w * 16) * 64));
    g2lds16(Wfi + (size_t)(n0 + 64 + w * 16 + sr) * HIDDEN + (k0 + sc), (void*)(Bs + (64 + w * 16) * 64));
    __syncthreads();

    i32x4 af[2], bw[4];
    #pragma unroll
    for (int i = 0; i < 2; ++i)
      af[i] = *reinterpret_cast<const i32x4*>(&As[(wm * 32 + i * 16 + fr) * 64 + kqs]);
    #pragma unroll
    for (int jn = 0; jn < 4; ++jn)
      bw[jn] = *reinterpret_cast<const i32x4*>(&Bs[(wn * 64 + jn * 16 + fr) * 64 + kqs]);
    #pragma unroll
    for (int i = 0; i < 2; ++i)
      #pragma unroll
      for (int jn = 0; jn < 4; ++jn)
        acc[i][jn] = __builtin_amdgcn_mfma_i32_16x16x64_i8(af[i], bw[jn], acc[i][jn], 0, 0, 0);
  }

  const int fq = lane >> 4;
  #pragma unroll
  for (int i = 0; i < 2; ++i)
    #pragma unroll
    for (int jn = 0; jn < 4; ++jn) {
      const int col = n0 + wn * 64 + jn * 16 + fr;
      const float scf = SCf[col];
      #pragma unroll
      for (int r = 0; r < 4; ++r) {
        const int row = m0 + wm * 32 + i * 16 + fq * 4 + r;
        C[(size_t)row * ldc + col] = (float)acc[i][jn][r] * scf;
      }
    }
}

// ---------------------------------------------------------------- log_softmax + argmax + y staging
__global__ void smax_k(const float* __restrict__ LG,
                       const float* __restrict__ bfv,
                       float* __restrict__ out, int t,
                       const float* __restrict__ x,
                       signed char* __restrict__ Y,      // [BP][64], y/4 at scale 1
                       int* __restrict__ idx)
{
  const int b    = blockIdx.x;
  const int lane = threadIdx.x;   // 64
  const float NINF = -__builtin_inff();
  const float* lg = LG + (size_t)b * LGN;

  const int c1 = lane + 64, c2 = lane + 128;
  float v0 = lg[lane] + bfv[lane];
  float v1 = lg[c1] + bfv[c1];
  float v2 = (c2 < XDIM) ? lg[c2] + bfv[c2] : NINF;

  float m = fmaxf(v0, fmaxf(v1, v2));
  #pragma unroll
  for (int o = 32; o > 0; o >>= 1) m = fmaxf(m, __shfl_xor(m, o, 64));

  int bi = 0x7fffffff;
  if (v0 == m) bi = lane;
  if (v1 == m) bi = min(bi, c1);
  if (v2 == m) bi = min(bi, c2);
  #pragma unroll
  for (int o = 32; o > 0; o >>= 1) bi = min(bi, __shfl_xor(bi, o, 64));

  float s = __expf(v0 - m) + __expf(v1 - m) + ((c2 < XDIM) ? __expf(v2 - m) : 0.f);
  #pragma unroll
  for (int o = 32; o > 0; o >>= 1) s += __shfl_xor(s, o, 64);
  const float lse = __logf(s);

  float* orow = out + ((size_t)b * NSTEP + t) * XDIM;
  orow[lane] = v0 - m - lse;
  orow[c1]   = v1 - m - lse;
  if (c2 < XDIM) orow[c2] = v2 - m - lse;
  if (lane == 0) idx[b] = bi;

  if (t + 1 < NSTEP) {
    const float yv = (lane < CONDDIM)
        ? x[((size_t)b * NSTEP + (t + 1)) * INDIM + XDIM + lane] : 0.f;
    Y[(size_t)b * 64 + lane] = qscale(yv * 0.25f, 127.f);
  }
}

// ---------------------------------------------------------------- init: per-row scales + quantized z + zero c
__global__ void initq_k(const float* __restrict__ z, const float* __restrict__ x,
                        _Float16* __restrict__ c0T, _Float16* __restrict__ c1T,
                        signed char* __restrict__ Hz0,   // z @ s0, stride 1024
                        signed char* __restrict__ Hz1,   // z @ s1, stride 1024
                        signed char* __restrict__ Y,
                        float* __restrict__ S0, float* __restrict__ S1,
                        int* __restrict__ idx)
{
  const int b    = blockIdx.x;
  const int lane = threadIdx.x;   // 64
  const float* zr = z + (size_t)b * HIDDEN;

  float mz = 0.f;
  for (int k = lane; k < HIDDEN; k += 64) mz = fmaxf(mz, fabsf(zr[k]));
  #pragma unroll
  for (int o = 32; o > 0; o >>= 1) mz = fmaxf(mz, __shfl_xor(mz, o, 64));

  const float yv = (lane < CONDDIM) ? x[((size_t)b * NSTEP) * INDIM + XDIM + lane] : 0.f;
  float my = fabsf(yv) * 0.25f;
  #pragma unroll
  for (int o = 32; o > 0; o >>= 1) my = fmaxf(my, __shfl_xor(my, o, 64));

  const float s0 = fmaxf(fmaxf(mz, my), 1e-6f);
  const float s1 = fmaxf(mz, 1.f);
  const float i0 = 127.f / s0;
  const float i1 = 127.f / s1;

  for (int k = lane; k < HIDDEN; k += 64) {
    const float zv = zr[k];
    Hz0[(size_t)b * 1024 + k] = qscale(zv, i0);
    Hz1[(size_t)b * 1024 + k] = qscale(zv, i1);
    const size_t ci = (size_t)(k >> 5) * ((size_t)BP * 32) + (size_t)b * 32 + (k & 31);
    c0T[ci] = (_Float16)0.f;
    c1T[ci] = (_Float16)0.f;
  }
  Y[(size_t)b * 64 + lane] = qscale(yv * 0.25f, i0);   // y_0 @ s0 (+ zero pad)
  if (lane == 0) { S0[b] = s0; S1[b] = s1; idx[b] = 1; }
}

// ---------------------------------------------------------------- weight packing
__global__ void rowmax0_k(const float* __restrict__ Wih0, const float* __restrict__ Whh0,
                          float* __restrict__ RM, float* __restrict__ SC)
{
  const int n = blockIdx.x, lane = threadIdx.x;
  const int row = fused_row(n);
  float m = 1e-20f;
  for (int k = lane; k < HIDDEN; k += 64)  m = fmaxf(m, fabsf(Whh0[(size_t)row * HIDDEN + k]));
  for (int k = lane; k < CONDDIM; k += 64) m = fmaxf(m, 4.f * fabsf(Wih0[(size_t)row * INDIM + XDIM + k]));
  #pragma unroll
  for (int o = 32; o > 0; o >>= 1) m = fmaxf(m, __shfl_xor(m, o, 64));
  if (lane == 0) { RM[n] = m; SC[n] = m / 16129.f; }
}

__global__ void rowmax1_k(const float* __restrict__ Wih1, const float* __restrict__ Whh1,
                          float* __restrict__ RM, float* __restrict__ SC)
{
  const int n = blockIdx.x, lane = threadIdx.x;
  const int row = fused_row(n);
  float m = 1e-20f;
  for (int k = lane; k < HIDDEN; k += 64) {
    m = fmaxf(m, fabsf(Wih1[(size_t)row * HIDDEN + k]));
    m = fmaxf(m, fabsf(Whh1[(size_t)row * HIDDEN + k]));
  }
  #pragma unroll
  for (int o = 32; o > 0; o >>= 1) m = fmaxf(m, __shfl_xor(m, o, 64));
  if (lane == 0) { RM[n] = m; SC[n] = m / 16129.f; }
}

__global__ void packi0_k(const float* __restrict__ Wih0, const float* __restrict__ Whh0,
                         const float* __restrict__ RM, signed char* __restrict__ Bp)
{
  const int t = blockIdx.x * blockDim.x + threadIdx.x;
  if (t >= GN * K0P) return;
  const int n = t / K0P, k = t % K0P;
  const int row = fused_row(n);
  float v = 0.f;
  if (k < HIDDEN)                v = Whh0[(size_t)row * HIDDEN + k];
  else if (k < HIDDEN + CONDDIM) v = 4.f * Wih0[(size_t)row * INDIM + XDIM + (k - HIDDEN)];
  Bp[t] = qscale(v, 127.f / RM[n]);
}

__global__ void packi1_k(const float* __restrict__ Wih1, const float* __restrict__ Whh1,
                         const float* __restrict__ RM, signed char* __restrict__ Bp)
{
  const int t = blockIdx.x * blockDim.x + threadIdx.x;
  if (t >= GN * K1P) return;
  const int n = t >> 11, k = t & 2047;
  const int row = fused_row(n);
  const float v = (k < HIDDEN) ? Wih1[(size_t)row * HIDDEN + k]
                               : Whh1[(size_t)row * HIDDEN + (k - HIDDEN)];
  Bp[t] = qscale(v, 127.f / RM[n]);
}

__global__ void packbias_k(const float* __restrict__ bih, const float* __restrict__ bhh,
                           float* __restrict__ bc)
{
  const int n = blockIdx.x * blockDim.x + threadIdx.x;
  if (n >= GN) return;
  const int row = fused_row(n);
  bc[n] = bih[row] + bhh[row];
}

__global__ void rowmaxf_k(const float* __restrict__ Wf, float* __restrict__ RM,
                          float* __restrict__ SC)
{
  const int n = blockIdx.x, lane = threadIdx.x;
  float m = 1e-20f;
  if (n < XDIM)
    for (int k = lane; k < HIDDEN; k += 64) m = fmaxf(m, fabsf(Wf[(size_t)n * HIDDEN + k]));
  else m = 1.f;
  #pragma unroll
  for (int o = 32; o > 0; o >>= 1) m = fmaxf(m, __shfl_xor(m, o, 64));
  if (lane == 0) { RM[n] = m; SC[n] = m / 16129.f; }
}

__global__ void packfi_k(const float* __restrict__ Wf, const float* __restrict__ RM,
                         signed char* __restrict__ Wfi)
{
  const int t = blockIdx.x * blockDim.x + threadIdx.x;
  if (t >= LGN * HIDDEN) return;
  const int r = t >> 10, k = t & 1023;
  const float v = (r < XDIM) ? Wf[(size_t)r * HIDDEN + k] : 0.f;
  Wfi[t] = qscale(v, 127.f / RM[r]);
}

__global__ void packt_k(const float* __restrict__ Wih0, float* __restrict__ W0T)
{
  const int t = blockIdx.x * blockDim.x + threadIdx.x;
  if (t >= XDIM * GN) return;
  const int e = t >> 12, n = t & 4095;
  W0T[t] = Wih0[(size_t)fused_row(n) * INDIM + e];
}

// ---------------------------------------------------------------- launch
extern "C" void kernel_launch(void* const* d_in, const int* in_sizes, int n_in,
                              void* d_out, int out_size, void* d_ws, size_t ws_size,
                              hipStream_t stream)
{
  const float* z    = (const float*)d_in[0];
  const float* x    = (const float*)d_in[1];
  const float* Wih0 = (const float*)d_in[2];
  const float* Whh0 = (const float*)d_in[3];
  const float* bih0 = (const float*)d_in[4];
  const float* bhh0 = (const float*)d_in[5];
  const float* Wih1 = (const float*)d_in[6];
  const float* Whh1 = (const float*)d_in[7];
  const float* bih1 = (const float*)d_in[8];
  const float* bhh1 = (const float*)d_in[9];
  const float* Wf   = (const float*)d_in[10];
  const float* bfv  = (const float*)d_in[11];
  float* out = (float*)d_out;

  char* ws = (char*)d_ws;
  size_t off = 0;
  auto alloc = [&](size_t bytes) { void* p = ws + off; off += (bytes + 255) & ~(size_t)255; return p; };

  float*       LG   = (float*)      alloc((size_t)BP * LGN * 4);
  signed char* H0a  = (signed char*)alloc((size_t)BP * 1024);
  signed char* H0b  = (signed char*)alloc((size_t)BP * 1024);
  signed char* H0s1 = (signed char*)alloc((size_t)BP * 1024);   // h0'_0 @ s1 (t=0 only)
  signed char* H1a  = (signed char*)alloc((size_t)BP * 1024);
  signed char* H1b  = (signed char*)alloc((size_t)BP * 1024);
  signed char* Y    = (signed char*)alloc((size_t)BP * 64);
  signed char* Bpi0 = (signed char*)alloc((size_t)GN * K0P);
  signed char* Bpi1 = (signed char*)alloc((size_t)GN * K1P);
  signed char* Wfi  = (signed char*)alloc((size_t)LGN * HIDDEN);
  float*       W0T  = (float*)      alloc((size_t)XDIM * GN * 4);
  float*       bc0  = (float*)      alloc((size_t)GN * 4);
  float*       bc1  = (float*)      alloc((size_t)GN * 4);
  float*       RM0  = (float*)      alloc((size_t)GN * 4);
  float*       SC0  = (float*)      alloc((size_t)GN * 4);
  float*       RM1  = (float*)      alloc((size_t)GN * 4);
  float*       SC1  = (float*)      alloc((size_t)GN * 4);
  float*       RMf  = (float*)      alloc((size_t)LGN * 4);
  float*       SCf  = (float*)      alloc((size_t)LGN * 4);
  float*       S0   = (float*)      alloc((size_t)BP * 4);
  float*       S1   = (float*)      alloc((size_t)BP * 4);
  _Float16*    c0T  = (_Float16*)   alloc((size_t)BP * HIDDEN * 2);
  _Float16*    c1T  = (_Float16*)   alloc((size_t)BP * HIDDEN * 2);
  int*         idx  = (int*)        alloc((size_t)BP * 4);
  (void)ws_size; (void)in_sizes; (void)n_in; (void)out_size;

  rowmax0_k<<<GN, 64, 0, stream>>>(Wih0, Whh0, RM0, SC0);
  rowmax1_k<<<GN, 64, 0, stream>>>(Wih1, Whh1, RM1, SC1);
  rowmaxf_k<<<LGN, 64, 0, stream>>>(Wf, RMf, SCf);
  packi0_k<<<(GN * K0P + 255) / 256, 256, 0, stream>>>(Wih0, Whh0, RM0, Bpi0);
  packi1_k<<<(GN * K1P + 255) / 256, 256, 0, stream>>>(Wih1, Whh1, RM1, Bpi1);
  packfi_k<<<(LGN * HIDDEN + 255) / 256, 256, 0, stream>>>(Wf, RMf, Wfi);
  packbias_k<<<(GN + 255) / 256, 256, 0, stream>>>(bih0, bhh0, bc0);
  packbias_k<<<(GN + 255) / 256, 256, 0, stream>>>(bih1, bhh1, bc1);
  packt_k<<<(XDIM * GN + 255) / 256, 256, 0, stream>>>(Wih0, W0T);
  // initq: z@s0 -> H0b (= H0prev at t=0), z@s1 -> H1b (= H1prev at t=0)
  initq_k<<<BP, 64, 0, stream>>>(z, x, c0T, c1T, H0b, H1b, Y, S0, S1, idx);

  for (int t = 0; t < NSTEP; ++t) {
    signed char* H0cur  = (t & 1) ? H0b : H0a;
    signed char* H0prev = (t & 1) ? H0a : H0b;
    signed char* H1cur  = (t & 1) ? H1b : H1a;
    signed char* H1prev = (t & 1) ? H1a : H1b;

    // layer 0: A = [h0_{t-1} | y_t], fused cell -> h0' (written once, scale 1)
    gemm_i8_cell_k<true, K0P / 64><<<512, 512, 0, stream>>>(
        H0prev, Y, 64, Bpi0, K0P, bc0, SC0,
        (t == 0) ? S0 : nullptr, W0T, idx, c0T,
        H0cur,
        (t == 0) ? H0s1 : nullptr, S1);     // extra s1-scaled copy at t=0 only
    // layer 1: A = [h0'_t | h1_{t-1}], fused cell -> h1'
    gemm_i8_cell_k<false, K1P / 64><<<512, 512, 0, stream>>>(
        (t == 0) ? H0s1 : H0cur, H1prev, 1024, Bpi1, K1P, bc1, SC1,
        (t == 0) ? S1 : nullptr, nullptr, nullptr, c1T,
        H1cur, nullptr, nullptr);
    // logits from int8 h1' (scale 1/127)
    logits_i8_k<<<dim3(LGN / 128, BP / 64), dim3(256), 0, stream>>>(
        H1cur, 1024, Wfi, SCf, LG, LGN);
    smax_k<<<BP, 64, 0, stream>>>(LG, bfv, out, t, x, Y, idx);
  }
}